// Round 1
// baseline (1204.477 us; speedup 1.0000x reference)
//
#include <hip/hip_runtime.h>
#include <cstdint>
#include <cstddef>

// ---- problem constants ----
#define B_   64
#define S_   256
#define D_   128
#define H_   8
#define DH_  16
#define FF_  512
#define L_   4
#define U_   5000
#define N_   40000
#define E_   160000
#define FEA_ 32
#define HWY_ 16
#define CED_ 16
#define TD_  6

// ===================== GNN =====================

__global__ __launch_bounds__(256) void k_deg(const int* __restrict__ dst, float* __restrict__ deg) {
    int e = blockIdx.x * 256 + threadIdx.x;
    if (e < E_) unsafeAtomicAdd(&deg[dst[e]], 1.0f);
}

// agg[dst] += h[src], F features (F = 1<<logf)
__global__ __launch_bounds__(256) void k_scatter(const int* __restrict__ src, const int* __restrict__ dst,
                                                 const float* __restrict__ h, float* __restrict__ agg,
                                                 int logf_) {
    int t = blockIdx.x * 256 + threadIdx.x;
    int e = t >> logf_;
    int f = t & ((1 << logf_) - 1);
    if (e >= E_) return;
    unsafeAtomicAdd(&agg[(size_t)dst[e] * (1 << logf_) + f], h[(size_t)src[e] * (1 << logf_) + f]);
}

// h1 = relu((nf + agg/(deg+1)) @ W[32,128] + b)
__global__ __launch_bounds__(256) void k_gnn_mm1(const float* __restrict__ nf, const float* __restrict__ agg,
                                                 const float* __restrict__ deg, const float* __restrict__ W,
                                                 const float* __restrict__ bias, float* __restrict__ out) {
    __shared__ float Ws[FEA_ * D_];
    __shared__ float bs[D_];
    __shared__ float ins[2][FEA_];
    int tid = threadIdx.x;
    for (int i = tid; i < FEA_ * D_ / 4; i += 256) ((float4*)Ws)[i] = ((const float4*)W)[i];
    if (tid < D_) bs[tid] = bias[tid];
    __syncthreads();
    int ro = tid >> 7, d = tid & 127;
    int base = blockIdx.x * 32;
    for (int ir = 0; ir < 16; ++ir) {
        int row = base + ir * 2 + ro;
        if (d < FEA_) {
            float rd = 1.0f / (deg[row] + 1.0f);
            ins[ro][d] = nf[(size_t)row * FEA_ + d] + agg[(size_t)row * FEA_ + d] * rd;
        }
        __syncthreads();
        float acc = bs[d];
#pragma unroll
        for (int k = 0; k < FEA_; ++k) acc = fmaf(ins[ro][k], Ws[k * D_ + d], acc);
        out[(size_t)row * D_ + d] = fmaxf(acc, 0.f);
        __syncthreads();
    }
}

// spe = relu((h + agg/(deg+1)) @ W[128,128] + b)
__global__ __launch_bounds__(256) void k_gnn_mm2(const float* __restrict__ hin, const float* __restrict__ agg,
                                                 const float* __restrict__ deg, const float* __restrict__ W,
                                                 const float* __restrict__ bias, float* __restrict__ out) {
    __shared__ float Ws[D_ * D_];  // 64 KiB
    __shared__ float bs[D_];
    __shared__ float ins[2][D_];
    int tid = threadIdx.x;
    for (int i = tid; i < D_ * D_ / 4; i += 256) ((float4*)Ws)[i] = ((const float4*)W)[i];
    if (tid < D_) bs[tid] = bias[tid];
    __syncthreads();
    int ro = tid >> 7, d = tid & 127;
    int base = blockIdx.x * 32;
    for (int ir = 0; ir < 16; ++ir) {
        int row = base + ir * 2 + ro;
        float rd = 1.0f / (deg[row] + 1.0f);
        ins[ro][d] = hin[(size_t)row * D_ + d] + agg[(size_t)row * D_ + d] * rd;
        __syncthreads();
        float acc = bs[d];
#pragma unroll
        for (int k = 0; k < D_; ++k) acc = fmaf(ins[ro][k], Ws[k * D_ + d], acc);
        out[(size_t)row * D_ + d] = fmaxf(acc, 0.f);
        __syncthreads();
    }
}

// ===================== fusion + positional encoding =====================
__global__ __launch_bounds__(256) void k_fusion(const float* __restrict__ spe, const int* __restrict__ traj,
                                                const float* __restrict__ ue_tab, const int* __restrict__ uid,
                                                const float* __restrict__ tempx, const int* __restrict__ hwx,
                                                const float* __restrict__ ce_tab, const float* __restrict__ flw,
                                                const float* __restrict__ flb, float* __restrict__ x) {
    __shared__ float Ws[22 * D_];
    __shared__ float bs[D_];
    __shared__ float ins[2][22];
    int tid = threadIdx.x;
    for (int i = tid; i < 22 * D_; i += 256) Ws[i] = flw[i];
    if (tid < D_) bs[tid] = flb[tid];
    __syncthreads();
    int ro = tid >> 7, d = tid & 127;
    int base = blockIdx.x * 32;
    for (int ir = 0; ir < 16; ++ir) {
        int tok = base + ir * 2 + ro;
        int b = tok >> 8, s = tok & 255;
        if (d < TD_) ins[ro][d] = tempx[(size_t)tok * TD_ + d];
        else if (d < 22) ins[ro][d] = ce_tab[(size_t)hwx[tok] * CED_ + (d - TD_)];
        __syncthreads();
        float acc = bs[d];
#pragma unroll
        for (int k = 0; k < 22; ++k) acc = fmaf(ins[ro][k], Ws[k * D_ + d], acc);
        acc = fmaxf(acc, 0.f);
        // sinusoidal PE: pe[s, 2i]=sin(s*exp(-2i*ln(1e4)/128)), pe[s,2i+1]=cos(...)
        int i2 = d & ~1;
        float ang = (float)s * __expf(-(float)i2 * 0.0719557841560639f);
        float pe = (d & 1) ? cosf(ang) : sinf(ang);
        x[(size_t)tok * D_ + d] = spe[(size_t)traj[tok] * D_ + d] + ue_tab[(size_t)uid[b] * D_ + d] + acc + pe;
        __syncthreads();
    }
}

// ===================== attention bias =====================
__global__ __launch_bounds__(256) void k_bias(const float* __restrict__ tm, const float* __restrict__ dm,
                                              const int* __restrict__ mask, const float* __restrict__ lambda2,
                                              float* __restrict__ bias) {
    int t = blockIdx.x * 256 + threadIdx.x;  // one float4 per thread
    const int total = B_ * S_ * S_ / 4;
    if (t >= total) return;
    float l2 = *lambda2, l2c = 1.f - l2;
    float4 a = ((const float4*)tm)[t];
    float4 b = ((const float4*)dm)[t];
    int base = t * 4;
    int bb = base >> 16;       // b  (S*S = 65536)
    int k0 = base & 255;       // k
    const int* mrow = mask + bb * S_;
    float4 r;
    r.x = (mrow[k0 + 0] > 0 ? 0.f : -1e9f) - (l2 * log1pf(a.x) + l2c * log1pf(b.x));
    r.y = (mrow[k0 + 1] > 0 ? 0.f : -1e9f) - (l2 * log1pf(a.y) + l2c * log1pf(b.y));
    r.z = (mrow[k0 + 2] > 0 ? 0.f : -1e9f) - (l2 * log1pf(a.z) + l2c * log1pf(b.z));
    r.w = (mrow[k0 + 3] > 0 ? 0.f : -1e9f) - (l2 * log1pf(a.w) + l2c * log1pf(b.w));
    ((float4*)bias)[t] = r;
}

// ===================== generic fp32 GEMM =====================
// C[M,N] = act( A[M,K] @ W[K,N] + bias + resid )
__global__ __launch_bounds__(256) void k_gemm(const float* __restrict__ A, const float* __restrict__ W,
                                              const float* __restrict__ bias, const float* __restrict__ resid,
                                              float* __restrict__ C, int M, int N, int K, int act) {
    __shared__ float As[32][64];
    __shared__ float Ws[32][68];
    int tid = threadIdx.x;
    int tx = tid & 15, ty = tid >> 4;
    int row0 = blockIdx.x * 64, col0 = blockIdx.y * 64;
    float acc[4][4] = {};
    for (int k0 = 0; k0 < K; k0 += 32) {
#pragma unroll
        for (int i = 0; i < 2; ++i) {
            int t = tid + i * 256;
            int r = t >> 3;
            int kk = (t & 7) << 2;
            float4 v = make_float4(0.f, 0.f, 0.f, 0.f);
            int row = row0 + r;
            if (row < M) v = *(const float4*)(A + (size_t)row * K + k0 + kk);
            As[kk + 0][r] = v.x; As[kk + 1][r] = v.y; As[kk + 2][r] = v.z; As[kk + 3][r] = v.w;
        }
#pragma unroll
        for (int i = 0; i < 2; ++i) {
            int t = tid + i * 256;
            int kk = t >> 4;
            int nn = (t & 15) << 2;
            int col = col0 + nn;
            float4 v = make_float4(0.f, 0.f, 0.f, 0.f);
            if (col + 3 < N) v = *(const float4*)(W + (size_t)(k0 + kk) * N + col);
            else {
                float tmp[4] = {0.f, 0.f, 0.f, 0.f};
                for (int j = 0; j < 4; ++j) if (col + j < N) tmp[j] = W[(size_t)(k0 + kk) * N + col + j];
                v = make_float4(tmp[0], tmp[1], tmp[2], tmp[3]);
            }
            *(float4*)&Ws[kk][nn] = v;
        }
        __syncthreads();
#pragma unroll
        for (int k = 0; k < 32; ++k) {
            float4 av = *(const float4*)&As[k][ty * 4];
            float4 bv = *(const float4*)&Ws[k][tx * 4];
            float a[4] = {av.x, av.y, av.z, av.w};
            float b[4] = {bv.x, bv.y, bv.z, bv.w};
#pragma unroll
            for (int i = 0; i < 4; ++i)
#pragma unroll
                for (int j = 0; j < 4; ++j) acc[i][j] = fmaf(a[i], b[j], acc[i][j]);
        }
        __syncthreads();
    }
#pragma unroll
    for (int i = 0; i < 4; ++i) {
        int row = row0 + ty * 4 + i;
        if (row >= M) continue;
#pragma unroll
        for (int j = 0; j < 4; ++j) {
            int col = col0 + tx * 4 + j;
            if (col >= N) continue;
            float v = acc[i][j];
            if (bias) v += bias[col];
            if (resid) v += resid[(size_t)row * N + col];
            if (act) v = fmaxf(v, 0.f);
            C[(size_t)row * N + col] = v;
        }
    }
}

// ===================== attention (one block per (b,h)) =====================
__global__ __launch_bounds__(256) void k_attn(const float* __restrict__ qkv, const float* __restrict__ bias,
                                              float* __restrict__ o) {
    __shared__ float Ks[S_][DH_];
    __shared__ float Vs[S_][DH_];
    int b = blockIdx.x >> 3;
    int h = blockIdx.x & 7;
    int tid = threadIdx.x;  // q row
    const float* base = qkv + ((size_t)(b * S_ + tid)) * 384 + h * DH_;
    float4 q4[4];
#pragma unroll
    for (int i = 0; i < 4; ++i) {
        q4[i] = *(const float4*)(base + i * 4);
        *(float4*)&Ks[tid][i * 4] = *(const float4*)(base + 128 + i * 4);
        *(float4*)&Vs[tid][i * 4] = *(const float4*)(base + 256 + i * 4);
    }
    __syncthreads();
    const float* brow = bias + ((size_t)(b * S_ + tid)) * S_;
    float m = -1e30f, l = 0.f;
    float4 a0 = {0, 0, 0, 0}, a1 = {0, 0, 0, 0}, a2 = {0, 0, 0, 0}, a3 = {0, 0, 0, 0};
    for (int s = 0; s < S_; ++s) {
        const float4* kr = (const float4*)Ks[s];
        float4 k0 = kr[0], k1 = kr[1], k2 = kr[2], k3 = kr[3];
        float dt = q4[0].x * k0.x + q4[0].y * k0.y + q4[0].z * k0.z + q4[0].w * k0.w
                 + q4[1].x * k1.x + q4[1].y * k1.y + q4[1].z * k1.z + q4[1].w * k1.w
                 + q4[2].x * k2.x + q4[2].y * k2.y + q4[2].z * k2.z + q4[2].w * k2.w
                 + q4[3].x * k3.x + q4[3].y * k3.y + q4[3].z * k3.z + q4[3].w * k3.w;
        float sc = dt * 0.25f + brow[s];
        float mn = fmaxf(m, sc);
        float c = __expf(m - mn);
        float p = __expf(sc - mn);
        l = l * c + p;
        const float4* vr = (const float4*)Vs[s];
        float4 v0 = vr[0], v1 = vr[1], v2 = vr[2], v3 = vr[3];
        a0.x = a0.x * c + p * v0.x; a0.y = a0.y * c + p * v0.y; a0.z = a0.z * c + p * v0.z; a0.w = a0.w * c + p * v0.w;
        a1.x = a1.x * c + p * v1.x; a1.y = a1.y * c + p * v1.y; a1.z = a1.z * c + p * v1.z; a1.w = a1.w * c + p * v1.w;
        a2.x = a2.x * c + p * v2.x; a2.y = a2.y * c + p * v2.y; a2.z = a2.z * c + p * v2.z; a2.w = a2.w * c + p * v2.w;
        a3.x = a3.x * c + p * v3.x; a3.y = a3.y * c + p * v3.y; a3.z = a3.z * c + p * v3.z; a3.w = a3.w * c + p * v3.w;
        m = mn;
    }
    float inv = 1.f / l;
    float* ob = o + ((size_t)(b * S_ + tid)) * D_ + h * DH_;
    float4 r0 = {a0.x * inv, a0.y * inv, a0.z * inv, a0.w * inv};
    float4 r1 = {a1.x * inv, a1.y * inv, a1.z * inv, a1.w * inv};
    float4 r2 = {a2.x * inv, a2.y * inv, a2.z * inv, a2.w * inv};
    float4 r3 = {a3.x * inv, a3.y * inv, a3.z * inv, a3.w * inv};
    *(float4*)(ob + 0) = r0; *(float4*)(ob + 4) = r1; *(float4*)(ob + 8) = r2; *(float4*)(ob + 12) = r3;
}

// ===================== LayerNorm (one wave per token) =====================
__global__ __launch_bounds__(256) void k_ln(const float* __restrict__ y, const float* __restrict__ g,
                                            const float* __restrict__ be, float* __restrict__ x) {
    int tok = blockIdx.x * 4 + (threadIdx.x >> 6);
    int lane = threadIdx.x & 63;
    const float* yr = y + (size_t)tok * D_;
    float v0 = yr[lane], v1 = yr[lane + 64];
    float s = v0 + v1, s2 = v0 * v0 + v1 * v1;
#pragma unroll
    for (int off = 32; off; off >>= 1) { s += __shfl_xor(s, off, 64); s2 += __shfl_xor(s2, off, 64); }
    float mean = s * (1.f / 128.f);
    float var = s2 * (1.f / 128.f) - mean * mean;
    float rs = rsqrtf(var + 1e-5f);
    float* xr = x + (size_t)tok * D_;
    xr[lane]      = (v0 - mean) * rs * g[lane]      + be[lane];
    xr[lane + 64] = (v1 - mean) * rs * g[lane + 64] + be[lane + 64];
}

// ===================== gather last token =====================
__global__ __launch_bounds__(256) void k_gather(const float* __restrict__ x, const int* __restrict__ endi,
                                                float* __restrict__ te) {
    int t = blockIdx.x * 256 + threadIdx.x;
    if (t >= B_ * D_) return;
    int b = t >> 7, d = t & 127;
    te[t] = x[((size_t)b * S_ + endi[b]) * D_ + d];
}

// ===================== launch =====================
extern "C" void kernel_launch(void* const* d_in, const int* in_sizes, int n_in,
                              void* d_out, int out_size, void* d_ws, size_t ws_size,
                              hipStream_t stream) {
    const float* node_feature = (const float*)d_in[0];
    const int*   edge_index   = (const int*)d_in[1];
    const int*   traj_x       = (const int*)d_in[2];
    const float* temporal_x   = (const float*)d_in[3];
    const int*   user_id_x    = (const int*)d_in[4];
    const int*   mask         = (const int*)d_in[5];
    const int*   end_idx      = (const int*)d_in[6];
    const float* tmat         = (const float*)d_in[8];
    const float* dmat         = (const float*)d_in[9];
    const int*   highway_x    = (const int*)d_in[10];
    const float* lambda2      = (const float*)d_in[11];
    const float* gnn_w1       = (const float*)d_in[12];
    const float* gnn_b1       = (const float*)d_in[13];
    const float* gnn_w2       = (const float*)d_in[14];
    const float* gnn_b2       = (const float*)d_in[15];
    const float* ue_tab       = (const float*)d_in[16];
    const float* ce_tab       = (const float*)d_in[17];
    const float* fl_w         = (const float*)d_in[18];
    const float* fl_b         = (const float*)d_in[19];
    const float* wqkv         = (const float*)d_in[20];
    const float* bqkv         = (const float*)d_in[21];
    const float* wo           = (const float*)d_in[22];
    const float* bo           = (const float*)d_in[23];
    const float* ln1_g        = (const float*)d_in[24];
    const float* ln1_b        = (const float*)d_in[25];
    const float* ln2_g        = (const float*)d_in[26];
    const float* ln2_b        = (const float*)d_in[27];
    const float* ffn_w1       = (const float*)d_in[28];
    const float* ffn_b1       = (const float*)d_in[29];
    const float* ffn_w2       = (const float*)d_in[30];
    const float* ffn_b2       = (const float*)d_in[31];
    const float* head_w       = (const float*)d_in[32];
    const float* head_b       = (const float*)d_in[33];
    float* out = (float*)d_out;

    // ws layout (floats). GNN temporaries are overlapped by transformer buffers.
    float* w    = (float*)d_ws;
    float* deg  = w;                       // 40960
    float* spe  = w + 40960;               // 5,120,000
    float* pool = w + 5160960;
    float* agg  = pool;                    // 5,120,000 (GNN)
    float* h1   = pool + 5120000;          // 5,120,000 (GNN)
    float* x    = pool;                    // 2,097,152 (after GNN)
    float* qkvb = pool + 2097152;          // 6,291,456
    float* atto = pool + 8388608;          // 2,097,152
    float* yb   = pool + 10485760;         // 2,097,152
    float* ffn1 = pool + 12582912;         // 8,388,608
    float* biasb= pool + 20971520;         // 4,194,304   (total ~121.3 MB)

    const int* esrc = edge_index;
    const int* edst = edge_index + E_;

    hipMemsetAsync(deg, 0, N_ * sizeof(float), stream);
    hipMemsetAsync(agg, 0, (size_t)N_ * D_ * sizeof(float), stream);
    k_deg<<<(E_ + 255) / 256, 256, 0, stream>>>(edst, deg);
    k_scatter<<<(E_ * FEA_) / 256, 256, 0, stream>>>(esrc, edst, node_feature, agg, 5);
    k_gnn_mm1<<<N_ / 32, 256, 0, stream>>>(node_feature, agg, deg, gnn_w1, gnn_b1, h1);
    hipMemsetAsync(agg, 0, (size_t)N_ * D_ * sizeof(float), stream);
    k_scatter<<<(E_ * D_) / 256, 256, 0, stream>>>(esrc, edst, h1, agg, 7);
    k_gnn_mm2<<<N_ / 32, 256, 0, stream>>>(h1, agg, deg, gnn_w2, gnn_b2, spe);

    k_fusion<<<(B_ * S_) / 32, 256, 0, stream>>>(spe, traj_x, ue_tab, user_id_x,
                                                 temporal_x, highway_x, ce_tab, fl_w, fl_b, x);
    k_bias<<<(B_ * S_ * S_ / 4) / 256, 256, 0, stream>>>(tmat, dmat, mask, lambda2, biasb);

    auto gemm = [&](const float* A, const float* W_, const float* bi, const float* res,
                    float* C, int M, int Nn, int K, int act) {
        dim3 grid((M + 63) / 64, (Nn + 63) / 64);
        k_gemm<<<grid, 256, 0, stream>>>(A, W_, bi, res, C, M, Nn, K, act);
    };

    const int M = B_ * S_;
    for (int l = 0; l < L_; ++l) {
        gemm(x, wqkv + (size_t)l * D_ * 3 * D_, bqkv + l * 3 * D_, nullptr, qkvb, M, 3 * D_, D_, 0);
        k_attn<<<B_ * H_, 256, 0, stream>>>(qkvb, biasb, atto);
        gemm(atto, wo + (size_t)l * D_ * D_, bo + l * D_, x, yb, M, D_, D_, 0);
        k_ln<<<M / 4, 256, 0, stream>>>(yb, ln1_g + l * D_, ln1_b + l * D_, x);
        gemm(x, ffn_w1 + (size_t)l * D_ * FF_, ffn_b1 + l * FF_, nullptr, ffn1, M, FF_, D_, 1);
        gemm(ffn1, ffn_w2 + (size_t)l * FF_ * D_, ffn_b2 + l * D_, x, yb, M, D_, FF_, 0);
        k_ln<<<M / 4, 256, 0, stream>>>(yb, ln2_g + l * D_, ln2_b + l * D_, x);
    }

    float* te = yb;  // reuse as [B,D] traj_emb
    k_gather<<<(B_ * D_) / 256, 256, 0, stream>>>(x, end_idx, te);
    gemm(te, head_w, head_b, nullptr, out, B_, U_, D_, 0);
}

// Round 2
// 751.688 us; speedup vs baseline: 1.6024x; 1.6024x over previous
//
#include <hip/hip_runtime.h>
#include <cstdint>
#include <cstddef>

typedef unsigned short u16;
typedef __attribute__((ext_vector_type(8))) short short8;
typedef __attribute__((ext_vector_type(4))) float f32x4;

// ---- problem constants ----
#define B_   64
#define S_   256
#define D_   128
#define H_   8
#define DH_  16
#define FF_  512
#define L_   4
#define U_   5000
#define N_   40000
#define NP_  40064   // padded to multiple of 128
#define E_   160000
#define FEA_ 32
#define HWY_ 16
#define CED_ 16
#define TD_  6

static __device__ __forceinline__ u16 f2b(float f) {
    unsigned int u = __float_as_uint(f);
    unsigned int r = (u + 0x7FFFu + ((u >> 16) & 1u)) >> 16;
    return (u16)r;
}

static __device__ __forceinline__ void gload16(const void* g, void* l) {
    __builtin_amdgcn_global_load_lds(
        (const __attribute__((address_space(1))) unsigned int*)g,
        (__attribute__((address_space(3))) unsigned int*)l,
        16, 0, 0);
}

// ===================== GNN scatter =====================
__global__ __launch_bounds__(256) void k_deg(const int* __restrict__ dst, float* __restrict__ deg) {
    int e = blockIdx.x * 256 + threadIdx.x;
    if (e < E_) unsafeAtomicAdd(&deg[dst[e]], 1.0f);
}

__global__ __launch_bounds__(256) void k_scatter(const int* __restrict__ src, const int* __restrict__ dst,
                                                 const float* __restrict__ h, float* __restrict__ agg,
                                                 int logf_) {
    int t = blockIdx.x * 256 + threadIdx.x;
    int e = t >> logf_;
    int f = t & ((1 << logf_) - 1);
    if (e >= E_) return;
    unsafeAtomicAdd(&agg[(size_t)dst[e] * (1 << logf_) + f], h[(size_t)src[e] * (1 << logf_) + f]);
}

// in1b[row][k] (row<NP_, Kp=64): bf16(nf + agg/(deg+1)) for k<32 else 0; rows>=N_ zero
__global__ __launch_bounds__(256) void k_prep1(const float* __restrict__ nf, const float* __restrict__ agg,
                                               const float* __restrict__ deg, u16* __restrict__ out) {
    int t = blockIdx.x * 256 + threadIdx.x;   // one ushort4 (4 k) per thread
    int row = t >> 4;
    int k0 = (t & 15) << 2;
    if (row >= NP_) return;
    u16 r[4] = {0, 0, 0, 0};
    if (row < N_ && k0 < FEA_) {
        float rd = 1.0f / (deg[row] + 1.0f);
        for (int j = 0; j < 4; ++j)
            r[j] = f2b(nf[(size_t)row * FEA_ + k0 + j] + agg[(size_t)row * FEA_ + k0 + j] * rd);
    }
    *(ushort4*)&out[(size_t)row * 64 + k0] = make_ushort4(r[0], r[1], r[2], r[3]);
}

// in2b[row][k] (K=128): bf16(h1 + agg/(deg+1)); rows>=N_ zero
__global__ __launch_bounds__(256) void k_prep2(const float* __restrict__ h1, const float* __restrict__ agg,
                                               const float* __restrict__ deg, u16* __restrict__ out) {
    int t = blockIdx.x * 256 + threadIdx.x;
    int row = t >> 5;
    int k0 = (t & 31) << 2;
    if (row >= NP_) return;
    u16 r[4] = {0, 0, 0, 0};
    if (row < N_) {
        float rd = 1.0f / (deg[row] + 1.0f);
        for (int j = 0; j < 4; ++j)
            r[j] = f2b(h1[(size_t)row * D_ + k0 + j] + agg[(size_t)row * D_ + k0 + j] * rd);
    }
    *(ushort4*)&out[(size_t)row * D_ + k0] = make_ushort4(r[0], r[1], r[2], r[3]);
}

// ===================== weight transpose+convert: out[l][n][k] = bf16(in[l][k][n]), k>=K -> 0
__global__ __launch_bounds__(256) void k_cvtT(const float* __restrict__ in, u16* __restrict__ out,
                                              int K, int N, int Kp, int total) {
    int idx = blockIdx.x * 256 + threadIdx.x;
    if (idx >= total) return;
    int nkp = N * Kp;
    int l = idx / nkp;
    int r = idx - l * nkp;
    int n = r / Kp;
    int k = r - n * Kp;
    float v = (k < K) ? in[(size_t)l * K * N + (size_t)k * N + n] : 0.f;
    out[idx] = f2b(v);
}

// ===================== MFMA GEMM =====================
// C[M,N] = act(A[M,K]bf16 @ BT[N,K]bf16^T + bias + resid), M%128==0, N%128==0, K%64==0
template<int ACT, int OUTB, int RES>
__global__ __launch_bounds__(256) void k_mgemm(const u16* __restrict__ A, const u16* __restrict__ BT,
                                               const float* __restrict__ bias, const float* __restrict__ resid,
                                               void* __restrict__ Cout, int M, int N, int K) {
    __shared__ u16 Al[128 * 64];
    __shared__ u16 Bl[128 * 64];
    int tid = threadIdx.x;
    int wid = tid >> 6, lane = tid & 63;
    int row0 = blockIdx.x * 128;
    int col0 = blockIdx.y * 128;
    int wr = wid >> 1, wc = wid & 1;
    f32x4 acc[4][4] = {};
    int srow = wid * 32 + (lane >> 3);          // staging row base (this lane)
    int ks8 = ((lane & 7) ^ (lane >> 3)) * 8;   // pre-swizzled k-slot (ushort offset)

    for (int k0 = 0; k0 < K; k0 += 64) {
        if (k0) __syncthreads();
#pragma unroll
        for (int i = 0; i < 4; ++i) {
            int row = srow + i * 8;
            gload16(A + (size_t)(row0 + row) * K + k0 + ks8, &Al[(wid * 32 + i * 8) * 64]);
            gload16(BT + (size_t)(col0 + row) * K + k0 + ks8, &Bl[(wid * 32 + i * 8) * 64]);
        }
        __syncthreads();
        int rA = lane & 15, kq = lane >> 4;
#pragma unroll
        for (int ks = 0; ks < 2; ++ks) {
            int sw = ((ks * 4 + kq) ^ (rA & 7)) * 8;
            short8 af[4], bfr[4];
#pragma unroll
            for (int m = 0; m < 4; ++m)
                af[m] = *(const short8*)&Al[(64 * wr + m * 16 + rA) * 64 + sw];
#pragma unroll
            for (int n = 0; n < 4; ++n)
                bfr[n] = *(const short8*)&Bl[(64 * wc + n * 16 + rA) * 64 + sw];
#pragma unroll
            for (int m = 0; m < 4; ++m)
#pragma unroll
                for (int n = 0; n < 4; ++n)
                    acc[m][n] = __builtin_amdgcn_mfma_f32_16x16x32_bf16(af[m], bfr[n], acc[m][n], 0, 0, 0);
        }
    }
    int rA = lane & 15, kq = lane >> 4;
#pragma unroll
    for (int m = 0; m < 4; ++m) {
#pragma unroll
        for (int n = 0; n < 4; ++n) {
            int cc = col0 + 64 * wc + n * 16 + rA;
            float bv = bias[cc];
#pragma unroll
            for (int r = 0; r < 4; ++r) {
                int cr = row0 + 64 * wr + m * 16 + kq * 4 + r;
                float v = acc[m][n][r] + bv;
                if (RES) v += resid[(size_t)cr * N + cc];
                if (ACT) v = fmaxf(v, 0.f);
                if (OUTB) ((u16*)Cout)[(size_t)cr * N + cc] = f2b(v);
                else      ((float*)Cout)[(size_t)cr * N + cc] = v;
            }
        }
    }
}

// ===================== fusion + positional encoding =====================
__global__ __launch_bounds__(256) void k_fusion(const float* __restrict__ spe, const int* __restrict__ traj,
                                                const float* __restrict__ ue_tab, const int* __restrict__ uid,
                                                const float* __restrict__ tempx, const int* __restrict__ hwx,
                                                const float* __restrict__ ce_tab, const float* __restrict__ flw,
                                                const float* __restrict__ flb, float* __restrict__ x,
                                                u16* __restrict__ xb) {
    __shared__ float Ws[22 * D_];
    __shared__ float bs[D_];
    __shared__ float ins[2][22];
    int tid = threadIdx.x;
    for (int i = tid; i < 22 * D_; i += 256) Ws[i] = flw[i];
    if (tid < D_) bs[tid] = flb[tid];
    __syncthreads();
    int ro = tid >> 7, d = tid & 127;
    int base = blockIdx.x * 32;
    for (int ir = 0; ir < 16; ++ir) {
        int tok = base + ir * 2 + ro;
        int b = tok >> 8, s = tok & 255;
        if (d < TD_) ins[ro][d] = tempx[(size_t)tok * TD_ + d];
        else if (d < 22) ins[ro][d] = ce_tab[(size_t)hwx[tok] * CED_ + (d - TD_)];
        __syncthreads();
        float acc = bs[d];
#pragma unroll
        for (int k = 0; k < 22; ++k) acc = fmaf(ins[ro][k], Ws[k * D_ + d], acc);
        acc = fmaxf(acc, 0.f);
        int i2 = d & ~1;
        float ang = (float)s * __expf(-(float)i2 * 0.0719557841560639f);
        float pe = (d & 1) ? cosf(ang) : sinf(ang);
        float v = spe[(size_t)traj[tok] * D_ + d] + ue_tab[(size_t)uid[b] * D_ + d] + acc + pe;
        x[(size_t)tok * D_ + d] = v;
        xb[(size_t)tok * D_ + d] = f2b(v);
        __syncthreads();
    }
}

// ===================== attention bias =====================
__global__ __launch_bounds__(256) void k_bias(const float* __restrict__ tm, const float* __restrict__ dm,
                                              const int* __restrict__ mask, const float* __restrict__ lambda2,
                                              float* __restrict__ bias) {
    int t = blockIdx.x * 256 + threadIdx.x;
    const int total = B_ * S_ * S_ / 4;
    if (t >= total) return;
    float l2 = *lambda2, l2c = 1.f - l2;
    float4 a = ((const float4*)tm)[t];
    float4 b = ((const float4*)dm)[t];
    int base = t * 4;
    int bb = base >> 16;
    int k0 = base & 255;
    const int* mrow = mask + bb * S_;
    float4 r;
    r.x = (mrow[k0 + 0] > 0 ? 0.f : -1e9f) - (l2 * log1pf(a.x) + l2c * log1pf(b.x));
    r.y = (mrow[k0 + 1] > 0 ? 0.f : -1e9f) - (l2 * log1pf(a.y) + l2c * log1pf(b.y));
    r.z = (mrow[k0 + 2] > 0 ? 0.f : -1e9f) - (l2 * log1pf(a.z) + l2c * log1pf(b.z));
    r.w = (mrow[k0 + 3] > 0 ? 0.f : -1e9f) - (l2 * log1pf(a.w) + l2c * log1pf(b.w));
    ((float4*)bias)[t] = r;
}

// ===================== fp32 GEMM (head only) =====================
__global__ __launch_bounds__(256) void k_gemm(const float* __restrict__ A, const float* __restrict__ W,
                                              const float* __restrict__ bias, float* __restrict__ C,
                                              int M, int N, int K) {
    __shared__ float As[32][64];
    __shared__ float Ws[32][68];
    int tid = threadIdx.x;
    int tx = tid & 15, ty = tid >> 4;
    int row0 = blockIdx.x * 64, col0 = blockIdx.y * 64;
    float acc[4][4] = {};
    for (int k0 = 0; k0 < K; k0 += 32) {
#pragma unroll
        for (int i = 0; i < 2; ++i) {
            int t = tid + i * 256;
            int r = t >> 3;
            int kk = (t & 7) << 2;
            float4 v = make_float4(0.f, 0.f, 0.f, 0.f);
            int row = row0 + r;
            if (row < M) v = *(const float4*)(A + (size_t)row * K + k0 + kk);
            As[kk + 0][r] = v.x; As[kk + 1][r] = v.y; As[kk + 2][r] = v.z; As[kk + 3][r] = v.w;
        }
#pragma unroll
        for (int i = 0; i < 2; ++i) {
            int t = tid + i * 256;
            int kk = t >> 4;
            int nn = (t & 15) << 2;
            int col = col0 + nn;
            float4 v = make_float4(0.f, 0.f, 0.f, 0.f);
            if (col + 3 < N) v = *(const float4*)(W + (size_t)(k0 + kk) * N + col);
            else {
                float tmp[4] = {0.f, 0.f, 0.f, 0.f};
                for (int j = 0; j < 4; ++j) if (col + j < N) tmp[j] = W[(size_t)(k0 + kk) * N + col + j];
                v = make_float4(tmp[0], tmp[1], tmp[2], tmp[3]);
            }
            *(float4*)&Ws[kk][nn] = v;
        }
        __syncthreads();
#pragma unroll
        for (int k = 0; k < 32; ++k) {
            float4 av = *(const float4*)&As[k][ty * 4];
            float4 bv = *(const float4*)&Ws[k][tx * 4];
            float a[4] = {av.x, av.y, av.z, av.w};
            float b[4] = {bv.x, bv.y, bv.z, bv.w};
#pragma unroll
            for (int i = 0; i < 4; ++i)
#pragma unroll
                for (int j = 0; j < 4; ++j) acc[i][j] = fmaf(a[i], b[j], acc[i][j]);
        }
        __syncthreads();
    }
#pragma unroll
    for (int i = 0; i < 4; ++i) {
        int row = row0 + ty * 4 + i;
        if (row >= M) continue;
#pragma unroll
        for (int j = 0; j < 4; ++j) {
            int col = col0 + tx * 4 + j;
            if (col >= N) continue;
            C[(size_t)row * N + col] = acc[i][j] + bias[col];
        }
    }
}

// ===================== attention (fp32, one block per (b,h)) =====================
__global__ __launch_bounds__(256) void k_attn(const float* __restrict__ qkv, const float* __restrict__ bias,
                                              u16* __restrict__ o) {
    __shared__ float Ks[S_][DH_];
    __shared__ float Vs[S_][DH_];
    int b = blockIdx.x >> 3;
    int h = blockIdx.x & 7;
    int tid = threadIdx.x;
    const float* base = qkv + ((size_t)(b * S_ + tid)) * 384 + h * DH_;
    float4 q4[4];
#pragma unroll
    for (int i = 0; i < 4; ++i) {
        q4[i] = *(const float4*)(base + i * 4);
        *(float4*)&Ks[tid][i * 4] = *(const float4*)(base + 128 + i * 4);
        *(float4*)&Vs[tid][i * 4] = *(const float4*)(base + 256 + i * 4);
    }
    __syncthreads();
    const float* brow = bias + ((size_t)(b * S_ + tid)) * S_;
    float m = -1e30f, l = 0.f;
    float4 a0 = {0, 0, 0, 0}, a1 = {0, 0, 0, 0}, a2 = {0, 0, 0, 0}, a3 = {0, 0, 0, 0};
    for (int s0 = 0; s0 < S_; s0 += 4) {
        float4 bb4 = *(const float4*)(brow + s0);
        float bbv[4] = {bb4.x, bb4.y, bb4.z, bb4.w};
#pragma unroll
        for (int j = 0; j < 4; ++j) {
            int s = s0 + j;
            const float4* kr = (const float4*)Ks[s];
            float4 k0 = kr[0], k1 = kr[1], k2 = kr[2], k3 = kr[3];
            float dt = q4[0].x * k0.x + q4[0].y * k0.y + q4[0].z * k0.z + q4[0].w * k0.w
                     + q4[1].x * k1.x + q4[1].y * k1.y + q4[1].z * k1.z + q4[1].w * k1.w
                     + q4[2].x * k2.x + q4[2].y * k2.y + q4[2].z * k2.z + q4[2].w * k2.w
                     + q4[3].x * k3.x + q4[3].y * k3.y + q4[3].z * k3.z + q4[3].w * k3.w;
            float sc = dt * 0.25f + bbv[j];
            float mn = fmaxf(m, sc);
            float c = __expf(m - mn);
            float p = __expf(sc - mn);
            l = l * c + p;
            const float4* vr = (const float4*)Vs[s];
            float4 v0 = vr[0], v1 = vr[1], v2 = vr[2], v3 = vr[3];
            a0.x = a0.x * c + p * v0.x; a0.y = a0.y * c + p * v0.y; a0.z = a0.z * c + p * v0.z; a0.w = a0.w * c + p * v0.w;
            a1.x = a1.x * c + p * v1.x; a1.y = a1.y * c + p * v1.y; a1.z = a1.z * c + p * v1.z; a1.w = a1.w * c + p * v1.w;
            a2.x = a2.x * c + p * v2.x; a2.y = a2.y * c + p * v2.y; a2.z = a2.z * c + p * v2.z; a2.w = a2.w * c + p * v2.w;
            a3.x = a3.x * c + p * v3.x; a3.y = a3.y * c + p * v3.y; a3.z = a3.z * c + p * v3.z; a3.w = a3.w * c + p * v3.w;
            m = mn;
        }
    }
    float inv = 1.f / l;
    u16* ob = o + ((size_t)(b * S_ + tid)) * D_ + h * DH_;
    float av[16] = {a0.x, a0.y, a0.z, a0.w, a1.x, a1.y, a1.z, a1.w,
                    a2.x, a2.y, a2.z, a2.w, a3.x, a3.y, a3.z, a3.w};
#pragma unroll
    for (int i = 0; i < 16; ++i) ob[i] = f2b(av[i] * inv);
}

// ===================== LayerNorm (one wave per token), fp32 + bf16 out =====================
__global__ __launch_bounds__(256) void k_ln(const float* __restrict__ y, const float* __restrict__ g,
                                            const float* __restrict__ be, float* __restrict__ x,
                                            u16* __restrict__ xb) {
    int tok = blockIdx.x * 4 + (threadIdx.x >> 6);
    int lane = threadIdx.x & 63;
    const float* yr = y + (size_t)tok * D_;
    float v0 = yr[lane], v1 = yr[lane + 64];
    float s = v0 + v1, s2 = v0 * v0 + v1 * v1;
#pragma unroll
    for (int off = 32; off; off >>= 1) { s += __shfl_xor(s, off, 64); s2 += __shfl_xor(s2, off, 64); }
    float mean = s * (1.f / 128.f);
    float var = s2 * (1.f / 128.f) - mean * mean;
    float rs = rsqrtf(var + 1e-5f);
    float o0 = (v0 - mean) * rs * g[lane] + be[lane];
    float o1 = (v1 - mean) * rs * g[lane + 64] + be[lane + 64];
    float* xr = x + (size_t)tok * D_;
    u16* xbr = xb + (size_t)tok * D_;
    xr[lane] = o0; xr[lane + 64] = o1;
    xbr[lane] = f2b(o0); xbr[lane + 64] = f2b(o1);
}

// ===================== gather last token =====================
__global__ __launch_bounds__(256) void k_gather(const float* __restrict__ x, const int* __restrict__ endi,
                                                float* __restrict__ te) {
    int t = blockIdx.x * 256 + threadIdx.x;
    if (t >= B_ * D_) return;
    int b = t >> 7, d = t & 127;
    te[t] = x[((size_t)b * S_ + endi[b]) * D_ + d];
}

// ===================== launch =====================
extern "C" void kernel_launch(void* const* d_in, const int* in_sizes, int n_in,
                              void* d_out, int out_size, void* d_ws, size_t ws_size,
                              hipStream_t stream) {
    const float* node_feature = (const float*)d_in[0];
    const int*   edge_index   = (const int*)d_in[1];
    const int*   traj_x       = (const int*)d_in[2];
    const float* temporal_x   = (const float*)d_in[3];
    const int*   user_id_x    = (const int*)d_in[4];
    const int*   mask         = (const int*)d_in[5];
    const int*   end_idx      = (const int*)d_in[6];
    const float* tmat         = (const float*)d_in[8];
    const float* dmat         = (const float*)d_in[9];
    const int*   highway_x    = (const int*)d_in[10];
    const float* lambda2      = (const float*)d_in[11];
    const float* gnn_w1       = (const float*)d_in[12];
    const float* gnn_b1       = (const float*)d_in[13];
    const float* gnn_w2       = (const float*)d_in[14];
    const float* gnn_b2       = (const float*)d_in[15];
    const float* ue_tab       = (const float*)d_in[16];
    const float* ce_tab       = (const float*)d_in[17];
    const float* fl_w         = (const float*)d_in[18];
    const float* fl_b         = (const float*)d_in[19];
    const float* wqkv         = (const float*)d_in[20];
    const float* bqkv         = (const float*)d_in[21];
    const float* wo           = (const float*)d_in[22];
    const float* bo           = (const float*)d_in[23];
    const float* ln1_g        = (const float*)d_in[24];
    const float* ln1_b        = (const float*)d_in[25];
    const float* ln2_g        = (const float*)d_in[26];
    const float* ln2_b        = (const float*)d_in[27];
    const float* ffn_w1       = (const float*)d_in[28];
    const float* ffn_b1       = (const float*)d_in[29];
    const float* ffn_w2       = (const float*)d_in[30];
    const float* ffn_b2       = (const float*)d_in[31];
    const float* head_w       = (const float*)d_in[32];
    const float* head_b       = (const float*)d_in[33];
    float* out = (float*)d_out;

    // ---- workspace layout (float units) ----
    float* w     = (float*)d_ws;
    float* deg   = w;                        // 40,960
    float* spe   = w + 40960;                // NP_*128 = 5,128,192
    float* biasb = w + 5169152;              // 4,194,304
    float* wreg  = w + 9363456;              // weights bf16: 405,504 f
    u16* wqkvT = (u16*)wreg;                 // 4*384*128 us
    u16* woT   = wqkvT + 4 * 384 * 128;      // 4*128*128
    u16* w1T   = woT + 4 * 128 * 128;        // 4*512*128
    u16* w2T   = w1T + 4 * 512 * 128;        // 4*128*512
    u16* gw1T  = w2T + 4 * 128 * 512;        // 128*64
    u16* gw2T  = gw1T + 128 * 64;            // 128*128
    float* pool  = w + 9768960;
    // GNN phase
    float* agg  = pool;                      // 5,120,000
    float* h1   = pool + 5120000;            // NP_*128 = 5,128,192
    u16*   in1b = (u16*)(pool + 10248192);   // NP_*64 us
    u16*   in2b = (u16*)(pool + 11530240);   // NP_*128 us
    // transformer phase (overlaps GNN)
    float* x    = pool;                      // 2,097,152
    u16*   xb   = (u16*)(pool + 2097152);    // 2,097,152 us
    float* qkv  = pool + 3145728;            // 6,291,456
    u16*  attob = (u16*)(pool + 9437184);    // 2,097,152 us
    float* y    = pool + 10485760;           // 2,097,152
    u16*   f1b  = (u16*)(pool + 12582912);   // 8,388,608 us
    float* te   = pool + 16777216;           // 8,192

    const int* esrc = edge_index;
    const int* edst = edge_index + E_;

    // weight convert+transpose (independent, upfront)
    auto cvt = [&](const float* in, u16* outp, int K, int N, int Kp, int L) {
        int total = L * N * Kp;
        k_cvtT<<<(total + 255) / 256, 256, 0, stream>>>(in, outp, K, N, Kp, total);
    };
    cvt(wqkv,   wqkvT, 128, 384, 128, 4);
    cvt(wo,     woT,   128, 128, 128, 4);
    cvt(ffn_w1, w1T,   128, 512, 128, 4);
    cvt(ffn_w2, w2T,   512, 128, 512, 4);
    cvt(gnn_w1, gw1T,   32, 128,  64, 1);
    cvt(gnn_w2, gw2T,  128, 128, 128, 1);

    // ---- GNN ----
    hipMemsetAsync(deg, 0, N_ * sizeof(float), stream);
    hipMemsetAsync(agg, 0, (size_t)N_ * FEA_ * sizeof(float), stream);
    k_deg<<<(E_ + 255) / 256, 256, 0, stream>>>(edst, deg);
    k_scatter<<<(E_ * FEA_) / 256, 256, 0, stream>>>(esrc, edst, node_feature, agg, 5);
    k_prep1<<<(NP_ * 16 + 255) / 256, 256, 0, stream>>>(node_feature, agg, deg, in1b);
    k_mgemm<1, 0, 0><<<dim3(NP_ / 128, 1), 256, 0, stream>>>(in1b, gw1T, gnn_b1, nullptr, h1, NP_, D_, 64);
    hipMemsetAsync(agg, 0, (size_t)N_ * D_ * sizeof(float), stream);
    k_scatter<<<(E_ * D_) / 256, 256, 0, stream>>>(esrc, edst, h1, agg, 7);
    k_prep2<<<(NP_ * 32 + 255) / 256, 256, 0, stream>>>(h1, agg, deg, in2b);
    k_mgemm<1, 0, 0><<<dim3(NP_ / 128, 1), 256, 0, stream>>>(in2b, gw2T, gnn_b2, nullptr, spe, NP_, D_, D_);

    // ---- fusion, bias ----
    k_bias<<<(B_ * S_ * S_ / 4) / 256, 256, 0, stream>>>(tmat, dmat, mask, lambda2, biasb);
    k_fusion<<<(B_ * S_) / 32, 256, 0, stream>>>(spe, traj_x, ue_tab, user_id_x,
                                                 temporal_x, highway_x, ce_tab, fl_w, fl_b, x, xb);

    // ---- transformer ----
    const int M = B_ * S_;
    for (int l = 0; l < L_; ++l) {
        k_mgemm<0, 0, 0><<<dim3(M / 128, 3), 256, 0, stream>>>(xb, wqkvT + (size_t)l * 384 * 128,
                                                               bqkv + l * 384, nullptr, qkv, M, 384, D_);
        k_attn<<<B_ * H_, 256, 0, stream>>>(qkv, biasb, attob);
        k_mgemm<0, 0, 1><<<dim3(M / 128, 1), 256, 0, stream>>>(attob, woT + (size_t)l * 128 * 128,
                                                               bo + l * D_, x, y, M, D_, D_);
        k_ln<<<M / 4, 256, 0, stream>>>(y, ln1_g + l * D_, ln1_b + l * D_, x, xb);
        k_mgemm<1, 1, 0><<<dim3(M / 128, 4), 256, 0, stream>>>(xb, w1T + (size_t)l * 512 * 128,
                                                               ffn_b1 + l * FF_, nullptr, f1b, M, FF_, D_);
        k_mgemm<0, 0, 1><<<dim3(M / 128, 1), 256, 0, stream>>>(f1b, w2T + (size_t)l * 128 * 512,
                                                               ffn_b2 + l * D_, x, y, M, D_, FF_);
        k_ln<<<M / 4, 256, 0, stream>>>(y, ln2_g + l * D_, ln2_b + l * D_, x, xb);
    }

    k_gather<<<(B_ * D_ + 255) / 256, 256, 0, stream>>>(x, end_idx, te);
    k_gemm<<<dim3(1, (U_ + 63) / 64), 256, 0, stream>>>(te, head_w, head_b, out, B_, U_, D_);
}

// Round 3
// 679.826 us; speedup vs baseline: 1.7717x; 1.1057x over previous
//
#include <hip/hip_runtime.h>
#include <cstdint>
#include <cstddef>

typedef unsigned short u16;
typedef __attribute__((ext_vector_type(8))) short short8;
typedef __attribute__((ext_vector_type(4))) float f32x4;

// ---- problem constants ----
#define B_   64
#define S_   256
#define D_   128
#define H_   8
#define DH_  16
#define FF_  512
#define L_   4
#define U_   5000
#define UP_  5120    // U padded to multiple of 128
#define N_   40000
#define NP_  40064   // padded to multiple of 128
#define E_   160000
#define FEA_ 32
#define HWY_ 16
#define CED_ 16
#define TD_  6

static __device__ __forceinline__ u16 f2b(float f) {
    unsigned int u = __float_as_uint(f);
    unsigned int r = (u + 0x7FFFu + ((u >> 16) & 1u)) >> 16;
    return (u16)r;
}

static __device__ __forceinline__ void gload16(const void* g, void* l) {
    __builtin_amdgcn_global_load_lds(
        (const __attribute__((address_space(1))) unsigned int*)g,
        (__attribute__((address_space(3))) unsigned int*)l,
        16, 0, 0);
}

// ===================== GNN scatter =====================
__global__ __launch_bounds__(256) void k_deg(const int* __restrict__ dst, float* __restrict__ deg) {
    int e = blockIdx.x * 256 + threadIdx.x;
    if (e < E_) unsafeAtomicAdd(&deg[dst[e]], 1.0f);
}

__global__ __launch_bounds__(256) void k_scatter(const int* __restrict__ src, const int* __restrict__ dst,
                                                 const float* __restrict__ h, float* __restrict__ agg,
                                                 int logf_) {
    int t = blockIdx.x * 256 + threadIdx.x;
    int e = t >> logf_;
    int f = t & ((1 << logf_) - 1);
    if (e >= E_) return;
    unsafeAtomicAdd(&agg[(size_t)dst[e] * (1 << logf_) + f], h[(size_t)src[e] * (1 << logf_) + f]);
}

__global__ __launch_bounds__(256) void k_prep1(const float* __restrict__ nf, const float* __restrict__ agg,
                                               const float* __restrict__ deg, u16* __restrict__ out) {
    int t = blockIdx.x * 256 + threadIdx.x;
    int row = t >> 4;
    int k0 = (t & 15) << 2;
    if (row >= NP_) return;
    u16 r[4] = {0, 0, 0, 0};
    if (row < N_ && k0 < FEA_) {
        float rd = 1.0f / (deg[row] + 1.0f);
        for (int j = 0; j < 4; ++j)
            r[j] = f2b(nf[(size_t)row * FEA_ + k0 + j] + agg[(size_t)row * FEA_ + k0 + j] * rd);
    }
    *(ushort4*)&out[(size_t)row * 64 + k0] = make_ushort4(r[0], r[1], r[2], r[3]);
}

__global__ __launch_bounds__(256) void k_prep2(const float* __restrict__ h1, const float* __restrict__ agg,
                                               const float* __restrict__ deg, u16* __restrict__ out) {
    int t = blockIdx.x * 256 + threadIdx.x;
    int row = t >> 5;
    int k0 = (t & 31) << 2;
    if (row >= NP_) return;
    u16 r[4] = {0, 0, 0, 0};
    if (row < N_) {
        float rd = 1.0f / (deg[row] + 1.0f);
        for (int j = 0; j < 4; ++j)
            r[j] = f2b(h1[(size_t)row * D_ + k0 + j] + agg[(size_t)row * D_ + k0 + j] * rd);
    }
    *(ushort4*)&out[(size_t)row * D_ + k0] = make_ushort4(r[0], r[1], r[2], r[3]);
}

// ===================== weight transpose+convert: out[l][n][k] = bf16(in[l][k][n])
// k>=K -> 0, n>=Nsrc -> 0 (N may be padded)
__global__ __launch_bounds__(256) void k_cvtT(const float* __restrict__ in, u16* __restrict__ out,
                                              int K, int N, int Nsrc, int Kp, int total) {
    int idx = blockIdx.x * 256 + threadIdx.x;
    if (idx >= total) return;
    int nkp = N * Kp;
    int l = idx / nkp;
    int r = idx - l * nkp;
    int n = r / Kp;
    int k = r - n * Kp;
    float v = (k < K && n < Nsrc) ? in[(size_t)l * K * Nsrc + (size_t)k * Nsrc + n] : 0.f;
    out[idx] = f2b(v);
}

// ===================== MFMA GEMM =====================
// C[M,N] = act(A bf16 @ BT bf16^T + bias + resid); grid covers padded M,N; epilogue bounds by real M,N
template<int ACT, int OUTB, int RES>
__global__ __launch_bounds__(256) void k_mgemm(const u16* __restrict__ A, const u16* __restrict__ BT,
                                               const float* __restrict__ bias, const float* __restrict__ resid,
                                               void* __restrict__ Cout, int M, int N, int K) {
    __shared__ u16 Al[128 * 64];
    __shared__ u16 Bl[128 * 64];
    int tid = threadIdx.x;
    int wid = tid >> 6, lane = tid & 63;
    int row0 = blockIdx.x * 128;
    int col0 = blockIdx.y * 128;
    int wr = wid >> 1, wc = wid & 1;
    f32x4 acc[4][4] = {};
    int srow = wid * 32 + (lane >> 3);
    int ks8 = ((lane & 7) ^ (lane >> 3)) * 8;

    for (int k0 = 0; k0 < K; k0 += 64) {
        if (k0) __syncthreads();
#pragma unroll
        for (int i = 0; i < 4; ++i) {
            int row = srow + i * 8;
            gload16(A + (size_t)(row0 + row) * K + k0 + ks8, &Al[(wid * 32 + i * 8) * 64]);
            gload16(BT + (size_t)(col0 + row) * K + k0 + ks8, &Bl[(wid * 32 + i * 8) * 64]);
        }
        __syncthreads();
        int rA = lane & 15, kq = lane >> 4;
#pragma unroll
        for (int ks = 0; ks < 2; ++ks) {
            int sw = ((ks * 4 + kq) ^ (rA & 7)) * 8;
            short8 af[4], bfr[4];
#pragma unroll
            for (int m = 0; m < 4; ++m)
                af[m] = *(const short8*)&Al[(64 * wr + m * 16 + rA) * 64 + sw];
#pragma unroll
            for (int n = 0; n < 4; ++n)
                bfr[n] = *(const short8*)&Bl[(64 * wc + n * 16 + rA) * 64 + sw];
#pragma unroll
            for (int m = 0; m < 4; ++m)
#pragma unroll
                for (int n = 0; n < 4; ++n)
                    acc[m][n] = __builtin_amdgcn_mfma_f32_16x16x32_bf16(af[m], bfr[n], acc[m][n], 0, 0, 0);
        }
    }
    int rA = lane & 15, kq = lane >> 4;
#pragma unroll
    for (int m = 0; m < 4; ++m) {
#pragma unroll
        for (int n = 0; n < 4; ++n) {
            int cc = col0 + 64 * wc + n * 16 + rA;
            if (cc >= N) continue;
            float bv = bias[cc];
#pragma unroll
            for (int r = 0; r < 4; ++r) {
                int cr = row0 + 64 * wr + m * 16 + kq * 4 + r;
                if (cr >= M) continue;
                float v = acc[m][n][r] + bv;
                if (RES) v += resid[(size_t)cr * N + cc];
                if (ACT) v = fmaxf(v, 0.f);
                if (OUTB) ((u16*)Cout)[(size_t)cr * N + cc] = f2b(v);
                else      ((float*)Cout)[(size_t)cr * N + cc] = v;
            }
        }
    }
}

// ===================== fusion + positional encoding =====================
__global__ __launch_bounds__(256) void k_fusion(const float* __restrict__ spe, const int* __restrict__ traj,
                                                const float* __restrict__ ue_tab, const int* __restrict__ uid,
                                                const float* __restrict__ tempx, const int* __restrict__ hwx,
                                                const float* __restrict__ ce_tab, const float* __restrict__ flw,
                                                const float* __restrict__ flb, float* __restrict__ x,
                                                u16* __restrict__ xb) {
    __shared__ float Ws[22 * D_];
    __shared__ float bs[D_];
    __shared__ float ins[2][22];
    int tid = threadIdx.x;
    for (int i = tid; i < 22 * D_; i += 256) Ws[i] = flw[i];
    if (tid < D_) bs[tid] = flb[tid];
    __syncthreads();
    int ro = tid >> 7, d = tid & 127;
    int base = blockIdx.x * 32;
    for (int ir = 0; ir < 16; ++ir) {
        int tok = base + ir * 2 + ro;
        int b = tok >> 8, s = tok & 255;
        if (d < TD_) ins[ro][d] = tempx[(size_t)tok * TD_ + d];
        else if (d < 22) ins[ro][d] = ce_tab[(size_t)hwx[tok] * CED_ + (d - TD_)];
        __syncthreads();
        float acc = bs[d];
#pragma unroll
        for (int k = 0; k < 22; ++k) acc = fmaf(ins[ro][k], Ws[k * D_ + d], acc);
        acc = fmaxf(acc, 0.f);
        int i2 = d & ~1;
        float ang = (float)s * __expf(-(float)i2 * 0.0719557841560639f);
        float pe = (d & 1) ? cosf(ang) : sinf(ang);
        float v = spe[(size_t)traj[tok] * D_ + d] + ue_tab[(size_t)uid[b] * D_ + d] + acc + pe;
        x[(size_t)tok * D_ + d] = v;
        xb[(size_t)tok * D_ + d] = f2b(v);
        __syncthreads();
    }
}

// ===================== attention bias =====================
__global__ __launch_bounds__(256) void k_bias(const float* __restrict__ tm, const float* __restrict__ dm,
                                              const int* __restrict__ mask, const float* __restrict__ lambda2,
                                              float* __restrict__ bias) {
    int t = blockIdx.x * 256 + threadIdx.x;
    const int total = B_ * S_ * S_ / 4;
    if (t >= total) return;
    float l2 = *lambda2, l2c = 1.f - l2;
    float4 a = ((const float4*)tm)[t];
    float4 b = ((const float4*)dm)[t];
    int base = t * 4;
    int bb = base >> 16;
    int k0 = base & 255;
    const int* mrow = mask + bb * S_;
    float4 r;
    r.x = (mrow[k0 + 0] > 0 ? 0.f : -1e9f) - (l2 * log1pf(a.x) + l2c * log1pf(b.x));
    r.y = (mrow[k0 + 1] > 0 ? 0.f : -1e9f) - (l2 * log1pf(a.y) + l2c * log1pf(b.y));
    r.z = (mrow[k0 + 2] > 0 ? 0.f : -1e9f) - (l2 * log1pf(a.z) + l2c * log1pf(b.z));
    r.w = (mrow[k0 + 3] > 0 ? 0.f : -1e9f) - (l2 * log1pf(a.w) + l2c * log1pf(b.w));
    ((float4*)bias)[t] = r;
}

// ===================== MFMA flash attention =====================
// qkv bf16 [B*S][384], bias f32 [B][S][S], out bf16 [B*S][128]
// block = (b,h) via XCD-chunked swizzle; 4 waves, wave handles 64 q rows (4 tiles of 16)
#define KLS 40    // K lds row stride (u16): dh 0..15 data, 16..31 zeros, 32..39 pad
#define VTS 272   // V^T / P row stride (u16)
__global__ __launch_bounds__(256) void k_attn(const u16* __restrict__ qkv, const float* __restrict__ bias,
                                              u16* __restrict__ o) {
    __shared__ u16 Kl[256 * KLS];       // 20480 B
    __shared__ u16 Vt[16 * VTS];        //  8704 B
    __shared__ u16 Pl[4 * 16 * VTS];    // 34816 B   (per-wave P^T tile)
    int idx = blockIdx.x;
    int b = (idx & 7) * 8 + ((idx >> 3) >> 3);   // same-b heads land on same XCD
    int h = (idx >> 3) & 7;
    int tid = threadIdx.x, wid = tid >> 6, lane = tid & 63;

    // ---- stage K (row-major, dh-padded) and V (transposed) ----
    {
        const u16* kr = qkv + ((size_t)(b * S_ + tid)) * 384 + 128 + h * 16;
        short8 k0v = *(const short8*)kr;
        short8 k1v = *(const short8*)(kr + 8);
        short8 z = {};
        *(short8*)&Kl[tid * KLS + 0]  = k0v;
        *(short8*)&Kl[tid * KLS + 8]  = k1v;
        *(short8*)&Kl[tid * KLS + 16] = z;
        *(short8*)&Kl[tid * KLS + 24] = z;
        const u16* vr = qkv + ((size_t)(b * S_ + tid)) * 384 + 256 + h * 16;
        short8 v0 = *(const short8*)vr;
        short8 v1 = *(const short8*)(vr + 8);
#pragma unroll
        for (int d = 0; d < 8; ++d) Vt[d * VTS + tid] = (u16)v0[d];
#pragma unroll
        for (int d = 0; d < 8; ++d) Vt[(d + 8) * VTS + tid] = (u16)v1[d];
    }
    __syncthreads();

    u16* pl = Pl + wid * 16 * VTS;
    int qi = lane & 15, kq = lane >> 4;

    for (int qt = 0; qt < 4; ++qt) {
        int q0 = wid * 64 + qt * 16;
        int q = q0 + qi;
        // bias loads (issued early; consumed after MFMAs)
        float4 bb[16];
        const float* bp = bias + (size_t)b * (S_ * S_) + (size_t)q * S_ + kq * 4;
#pragma unroll
        for (int t = 0; t < 16; ++t) bb[t] = *(const float4*)(bp + t * 16);
        // Q fragment (B-operand): col=q, kk=dh=(lane>>4)*8+j ; lanes>=32 zero
        short8 qf = {};
        if (lane < 32)
            qf = *(const short8*)(qkv + ((size_t)(b * S_ + q)) * 384 + h * 16 + kq * 8);
        // QK^T (swapped): D[k,q], 16 k-tiles
        f32x4 sc[16];
#pragma unroll
        for (int t = 0; t < 16; ++t) {
            short8 kf = *(const short8*)&Kl[(t * 16 + qi) * KLS + kq * 8];
            f32x4 zz = {0.f, 0.f, 0.f, 0.f};
            sc[t] = __builtin_amdgcn_mfma_f32_16x16x32_bf16(kf, qf, zz, 0, 0, 0);
        }
        // softmax over k (lane-local 64 values + 2 shfl)
        float m = -1e30f;
#pragma unroll
        for (int t = 0; t < 16; ++t) {
            sc[t][0] = sc[t][0] * 0.25f + bb[t].x;
            sc[t][1] = sc[t][1] * 0.25f + bb[t].y;
            sc[t][2] = sc[t][2] * 0.25f + bb[t].z;
            sc[t][3] = sc[t][3] * 0.25f + bb[t].w;
            m = fmaxf(m, fmaxf(fmaxf(sc[t][0], sc[t][1]), fmaxf(sc[t][2], sc[t][3])));
        }
        m = fmaxf(m, __shfl_xor(m, 16, 64));
        m = fmaxf(m, __shfl_xor(m, 32, 64));
        float l = 0.f;
#pragma unroll
        for (int t = 0; t < 16; ++t) {
            sc[t][0] = __expf(sc[t][0] - m);
            sc[t][1] = __expf(sc[t][1] - m);
            sc[t][2] = __expf(sc[t][2] - m);
            sc[t][3] = __expf(sc[t][3] - m);
            l += (sc[t][0] + sc[t][1]) + (sc[t][2] + sc[t][3]);
        }
        l += __shfl_xor(l, 16, 64);
        l += __shfl_xor(l, 32, 64);
        float inv = 1.f / l;
        // write normalized P^T (as P[q][k]) to per-wave LDS
#pragma unroll
        for (int t = 0; t < 16; ++t) {
            ushort4 pw = make_ushort4(f2b(sc[t][0] * inv), f2b(sc[t][1] * inv),
                                      f2b(sc[t][2] * inv), f2b(sc[t][3] * inv));
            *(ushort4*)&pl[qi * VTS + t * 16 + kq * 4] = pw;
        }
        // PV: O^T[dh,q] = V^T · P^T, 8 k-windows of 32
        f32x4 oa = {0.f, 0.f, 0.f, 0.f};
#pragma unroll
        for (int w8 = 0; w8 < 8; ++w8) {
            short8 vf = *(const short8*)&Vt[qi * VTS + w8 * 32 + kq * 8];
            short8 pf = *(const short8*)&pl[qi * VTS + w8 * 32 + kq * 8];
            oa = __builtin_amdgcn_mfma_f32_16x16x32_bf16(vf, pf, oa, 0, 0, 0);
        }
        // write O: row=b*S+q, cols h*16 + kq*4 .. +4
        ushort4 ow = make_ushort4(f2b(oa[0]), f2b(oa[1]), f2b(oa[2]), f2b(oa[3]));
        *(ushort4*)&o[((size_t)(b * S_ + q)) * D_ + h * 16 + kq * 4] = ow;
    }
}

// ===================== LayerNorm =====================
__global__ __launch_bounds__(256) void k_ln(const float* __restrict__ y, const float* __restrict__ g,
                                            const float* __restrict__ be, float* __restrict__ x,
                                            u16* __restrict__ xb) {
    int tok = blockIdx.x * 4 + (threadIdx.x >> 6);
    int lane = threadIdx.x & 63;
    const float* yr = y + (size_t)tok * D_;
    float v0 = yr[lane], v1 = yr[lane + 64];
    float s = v0 + v1, s2 = v0 * v0 + v1 * v1;
#pragma unroll
    for (int off = 32; off; off >>= 1) { s += __shfl_xor(s, off, 64); s2 += __shfl_xor(s2, off, 64); }
    float mean = s * (1.f / 128.f);
    float var = s2 * (1.f / 128.f) - mean * mean;
    float rs = rsqrtf(var + 1e-5f);
    float o0 = (v0 - mean) * rs * g[lane] + be[lane];
    float o1 = (v1 - mean) * rs * g[lane + 64] + be[lane + 64];
    float* xr = x + (size_t)tok * D_;
    u16* xbr = xb + (size_t)tok * D_;
    xr[lane] = o0; xr[lane + 64] = o1;
    xbr[lane] = f2b(o0); xbr[lane + 64] = f2b(o1);
}

// ===================== gather last token (bf16) =====================
__global__ __launch_bounds__(256) void k_gather(const float* __restrict__ x, const int* __restrict__ endi,
                                                u16* __restrict__ te) {
    int t = blockIdx.x * 256 + threadIdx.x;
    if (t >= B_ * D_) return;
    int b = t >> 7, d = t & 127;
    te[t] = f2b(x[((size_t)b * S_ + endi[b]) * D_ + d]);
}

// ===================== launch =====================
extern "C" void kernel_launch(void* const* d_in, const int* in_sizes, int n_in,
                              void* d_out, int out_size, void* d_ws, size_t ws_size,
                              hipStream_t stream) {
    const float* node_feature = (const float*)d_in[0];
    const int*   edge_index   = (const int*)d_in[1];
    const int*   traj_x       = (const int*)d_in[2];
    const float* temporal_x   = (const float*)d_in[3];
    const int*   user_id_x    = (const int*)d_in[4];
    const int*   mask         = (const int*)d_in[5];
    const int*   end_idx      = (const int*)d_in[6];
    const float* tmat         = (const float*)d_in[8];
    const float* dmat         = (const float*)d_in[9];
    const int*   highway_x    = (const int*)d_in[10];
    const float* lambda2      = (const float*)d_in[11];
    const float* gnn_w1       = (const float*)d_in[12];
    const float* gnn_b1       = (const float*)d_in[13];
    const float* gnn_w2       = (const float*)d_in[14];
    const float* gnn_b2       = (const float*)d_in[15];
    const float* ue_tab       = (const float*)d_in[16];
    const float* ce_tab       = (const float*)d_in[17];
    const float* fl_w         = (const float*)d_in[18];
    const float* fl_b         = (const float*)d_in[19];
    const float* wqkv         = (const float*)d_in[20];
    const float* bqkv         = (const float*)d_in[21];
    const float* wo           = (const float*)d_in[22];
    const float* bo           = (const float*)d_in[23];
    const float* ln1_g        = (const float*)d_in[24];
    const float* ln1_b        = (const float*)d_in[25];
    const float* ln2_g        = (const float*)d_in[26];
    const float* ln2_b        = (const float*)d_in[27];
    const float* ffn_w1       = (const float*)d_in[28];
    const float* ffn_b1       = (const float*)d_in[29];
    const float* ffn_w2       = (const float*)d_in[30];
    const float* ffn_b2       = (const float*)d_in[31];
    const float* head_w       = (const float*)d_in[32];
    const float* head_b       = (const float*)d_in[33];
    float* out = (float*)d_out;

    // ---- workspace layout (float units) ----
    float* w     = (float*)d_ws;
    float* deg   = w;                        // 40,960
    float* spe   = w + 40960;                // NP_*128 = 5,128,192
    float* biasb = w + 5169152;              // 4,194,304
    float* wreg  = w + 9363456;              // bf16 weights
    u16* wqkvT = (u16*)wreg;                 // 4*384*128   = 196,608 us
    u16* woT   = wqkvT + 4 * 384 * 128;      // 4*128*128   =  65,536
    u16* w1T   = woT + 4 * 128 * 128;        // 4*512*128   = 262,144
    u16* w2T   = w1T + 4 * 512 * 128;        // 4*128*512   = 262,144
    u16* gw1T  = w2T + 4 * 128 * 512;        // 128*64      =   8,192
    u16* gw2T  = gw1T + 128 * 64;            // 128*128     =  16,384
    u16* hwT   = gw2T + 128 * 128;           // UP_*128     = 655,360
    float* pool  = w + 10096640;             // after weights (1,466,368 us = 733,184 f)
    // GNN phase
    float* agg  = pool;                      // 5,120,000
    float* h1   = pool + 5120000;            // 5,128,192
    u16*   in1b = (u16*)(pool + 10248192);   // NP_*64 us = 1,282,048 f
    u16*   in2b = (u16*)(pool + 11530240);   // NP_*128 us = 2,564,096 f (ends 14,094,336)
    // transformer phase (overlaps GNN)
    float* x     = pool;                     // 2,097,152
    u16*   xb    = (u16*)(pool + 2097152);   // 1,048,576 f
    u16*   qkvb  = (u16*)(pool + 3145728);   // 8192*384 us = 1,572,864 f
    u16*   attob = (u16*)(pool + 4718592);   // 1,048,576 f
    float* y     = pool + 5767168;           // 2,097,152
    u16*   f1b   = (u16*)(pool + 7864320);   // 8192*512 us = 2,097,152 f
    u16*   te    = (u16*)(pool + 9961472);   // 128*128 us = 8,192 f

    const int* esrc = edge_index;
    const int* edst = edge_index + E_;

    // weight convert+transpose
    auto cvt = [&](const float* in, u16* outp, int K, int Npad, int Nsrc, int Kp, int L) {
        int total = L * Npad * Kp;
        k_cvtT<<<(total + 255) / 256, 256, 0, stream>>>(in, outp, K, Npad, Nsrc, Kp, total);
    };
    cvt(wqkv,   wqkvT, 128, 384, 384, 128, 4);
    cvt(wo,     woT,   128, 128, 128, 128, 4);
    cvt(ffn_w1, w1T,   128, 512, 512, 128, 4);
    cvt(ffn_w2, w2T,   512, 128, 128, 512, 4);
    cvt(gnn_w1, gw1T,   32, 128, 128,  64, 1);
    cvt(gnn_w2, gw2T,  128, 128, 128, 128, 1);
    cvt(head_w, hwT,   128, UP_, U_,  128, 1);

    // ---- GNN ----
    hipMemsetAsync(deg, 0, N_ * sizeof(float), stream);
    hipMemsetAsync(agg, 0, (size_t)N_ * FEA_ * sizeof(float), stream);
    k_deg<<<(E_ + 255) / 256, 256, 0, stream>>>(edst, deg);
    k_scatter<<<(E_ * FEA_) / 256, 256, 0, stream>>>(esrc, edst, node_feature, agg, 5);
    k_prep1<<<(NP_ * 16 + 255) / 256, 256, 0, stream>>>(node_feature, agg, deg, in1b);
    k_mgemm<1, 0, 0><<<dim3(NP_ / 128, 1), 256, 0, stream>>>(in1b, gw1T, gnn_b1, nullptr, h1, NP_, D_, 64);
    hipMemsetAsync(agg, 0, (size_t)N_ * D_ * sizeof(float), stream);
    k_scatter<<<(E_ * D_) / 256, 256, 0, stream>>>(esrc, edst, h1, agg, 7);
    k_prep2<<<(NP_ * 32 + 255) / 256, 256, 0, stream>>>(h1, agg, deg, in2b);
    k_mgemm<1, 0, 0><<<dim3(NP_ / 128, 1), 256, 0, stream>>>(in2b, gw2T, gnn_b2, nullptr, spe, NP_, D_, D_);

    // ---- fusion, bias ----
    k_bias<<<(B_ * S_ * S_ / 4) / 256, 256, 0, stream>>>(tmat, dmat, mask, lambda2, biasb);
    k_fusion<<<(B_ * S_) / 32, 256, 0, stream>>>(spe, traj_x, ue_tab, user_id_x,
                                                 temporal_x, highway_x, ce_tab, fl_w, fl_b, x, xb);

    // ---- transformer ----
    const int M = B_ * S_;
    for (int l = 0; l < L_; ++l) {
        k_mgemm<0, 1, 0><<<dim3(M / 128, 3), 256, 0, stream>>>(xb, wqkvT + (size_t)l * 384 * 128,
                                                               bqkv + l * 384, nullptr, qkvb, M, 384, D_);
        k_attn<<<B_ * H_, 256, 0, stream>>>(qkvb, biasb, attob);
        k_mgemm<0, 0, 1><<<dim3(M / 128, 1), 256, 0, stream>>>(attob, woT + (size_t)l * 128 * 128,
                                                               bo + l * D_, x, y, M, D_, D_);
        k_ln<<<M / 4, 256, 0, stream>>>(y, ln1_g + l * D_, ln1_b + l * D_, x, xb);
        k_mgemm<1, 1, 0><<<dim3(M / 128, 4), 256, 0, stream>>>(xb, w1T + (size_t)l * 512 * 128,
                                                               ffn_b1 + l * FF_, nullptr, f1b, M, FF_, D_);
        k_mgemm<0, 0, 1><<<dim3(M / 128, 1), 256, 0, stream>>>(f1b, w2T + (size_t)l * 128 * 512,
                                                               ffn_b2 + l * D_, x, y, M, D_, FF_);
        k_ln<<<M / 4, 256, 0, stream>>>(y, ln2_g + l * D_, ln2_b + l * D_, x, xb);
    }

    k_gather<<<(B_ * D_ + 255) / 256, 256, 0, stream>>>(x, end_idx, te);
    k_mgemm<0, 0, 0><<<dim3(1, UP_ / 128), 256, 0, stream>>>(te, hwT, head_b, nullptr, out, B_, U_, D_);
}

// Round 5
// 544.898 us; speedup vs baseline: 2.2105x; 1.2476x over previous
//
#include <hip/hip_runtime.h>
#include <cstdint>
#include <cstddef>

typedef unsigned short u16;
typedef __attribute__((ext_vector_type(8))) short short8;
typedef __attribute__((ext_vector_type(4))) float f32x4;

// ---- problem constants ----
#define B_   64
#define S_   256
#define D_   128
#define H_   8
#define DH_  16
#define FF_  512
#define L_   4
#define U_   5000
#define UP_  5120    // U padded to multiple of 128
#define N_   40000
#define NP_  40064   // padded to multiple of 128
#define E_   160000
#define FEA_ 32
#define HWY_ 16
#define CED_ 16
#define TD_  6
#define NSCB 157     // ceil(NP_/256)

static __device__ __forceinline__ u16 f2b(float f) {
    unsigned int u = __float_as_uint(f);
    unsigned int r = (u + 0x7FFFu + ((u >> 16) & 1u)) >> 16;
    return (u16)r;
}

static __device__ __forceinline__ void gload16(const void* g, void* l) {
    __builtin_amdgcn_global_load_lds(
        (const __attribute__((address_space(1))) unsigned int*)g,
        (__attribute__((address_space(3))) unsigned int*)l,
        16, 0, 0);
}

// ===================== CSR build =====================
__global__ __launch_bounds__(256) void k_count(const int* __restrict__ dst, int* __restrict__ cnt) {
    int e = blockIdx.x * 256 + threadIdx.x;
    if (e < E_) atomicAdd(&cnt[dst[e]], 1);
}

__global__ __launch_bounds__(256) void k_scan1(const int* __restrict__ cnt, int* __restrict__ part) {
    __shared__ int sh[256];
    int idx = blockIdx.x * 256 + threadIdx.x;
    sh[threadIdx.x] = (idx < NP_) ? cnt[idx] : 0;
    __syncthreads();
    for (int o = 128; o > 0; o >>= 1) {
        if (threadIdx.x < o) sh[threadIdx.x] += sh[threadIdx.x + o];
        __syncthreads();
    }
    if (threadIdx.x == 0) part[blockIdx.x] = sh[0];
}

__global__ __launch_bounds__(64) void k_scan2(int* __restrict__ part) {
    if (threadIdx.x == 0) {
        int run = 0;
        for (int i = 0; i < NSCB; ++i) { int t = part[i]; part[i] = run; run += t; }
    }
}

__global__ __launch_bounds__(256) void k_scan3(const int* __restrict__ cnt, const int* __restrict__ part,
                                               int* __restrict__ off, int* __restrict__ cursor) {
    __shared__ int sh[256];
    int idx = blockIdx.x * 256 + threadIdx.x;
    int v = (idx < NP_) ? cnt[idx] : 0;
    sh[threadIdx.x] = v;
    __syncthreads();
    for (int o = 1; o < 256; o <<= 1) {
        int t = (threadIdx.x >= o) ? sh[threadIdx.x - o] : 0;
        __syncthreads();
        sh[threadIdx.x] += t;
        __syncthreads();
    }
    if (idx < NP_) {
        int res = sh[threadIdx.x] - v + part[blockIdx.x];
        off[idx] = res;
        cursor[idx] = res;
    }
}

__global__ __launch_bounds__(256) void k_fill(const int* __restrict__ src, const int* __restrict__ dst,
                                              int* __restrict__ cursor, int* __restrict__ ebuf) {
    int e = blockIdx.x * 256 + threadIdx.x;
    if (e >= E_) return;
    int p = atomicAdd(&cursor[dst[e]], 1);
    ebuf[p] = src[e];
}

// ===================== GNN gather+prep (fused) =====================
// out1b[n][0..31] = bf16(nf[n] + sum_nbr/(cnt+1)); cols 32..63 = 0
__global__ __launch_bounds__(256) void k_gprep1(const float* __restrict__ nf, const int* __restrict__ off,
                                                const int* __restrict__ cnt, const int* __restrict__ ebuf,
                                                u16* __restrict__ out) {
    int n = blockIdx.x * 8 + (threadIdx.x >> 5);
    int f = threadIdx.x & 31;
    u16 r = 0;
    if (n < N_) {
        int start = off[n], c = cnt[n];
        float acc = 0.f;
        for (int i = 0; i < c; ++i) {
            int s = ebuf[start + i];
            acc += nf[(size_t)s * FEA_ + f];
        }
        r = f2b(nf[(size_t)n * FEA_ + f] + acc / (float)(c + 1));
    }
    out[(size_t)n * 64 + f] = r;
    out[(size_t)n * 64 + 32 + f] = 0;
}

// in2b[n][d] = bf16(h1[n][d] + sum_nbr/(cnt+1))
__global__ __launch_bounds__(256) void k_gprep2(const float* __restrict__ h1, const int* __restrict__ off,
                                                const int* __restrict__ cnt, const int* __restrict__ ebuf,
                                                u16* __restrict__ out) {
    int n = blockIdx.x * 2 + (threadIdx.x >> 7);
    int d = threadIdx.x & 127;
    u16 r = 0;
    if (n < N_) {
        int start = off[n], c = cnt[n];
        float acc = 0.f;
        for (int i = 0; i < c; ++i) {
            int s = ebuf[start + i];
            acc += h1[(size_t)s * D_ + d];
        }
        r = f2b(h1[(size_t)n * D_ + d] + acc / (float)(c + 1));
    }
    out[(size_t)n * D_ + d] = r;
}

// ===================== tiled weight transpose+convert =====================
// out[l][n][k] = bf16(in[l][k][n]); k>=K -> 0, n>=Nsrc -> 0
__global__ __launch_bounds__(256) void k_cvtT(const float* __restrict__ in, u16* __restrict__ out,
                                              int K, int Npad, int Nsrc, int Kp) {
    __shared__ float tile[32][33];
    int l = blockIdx.z;
    int n0 = blockIdx.x * 32, k0 = blockIdx.y * 32;
    int j = threadIdx.x & 31, i = threadIdx.x >> 5;
#pragma unroll
    for (int r = 0; r < 4; ++r) {
        int k = k0 + i + r * 8, n = n0 + j;
        tile[i + r * 8][j] = (k < K && n < Nsrc) ? in[(size_t)l * K * Nsrc + (size_t)k * Nsrc + n] : 0.f;
    }
    __syncthreads();
#pragma unroll
    for (int r = 0; r < 4; ++r) {
        int n = n0 + i + r * 8, k = k0 + j;
        if (n < Npad && k < Kp)
            out[(size_t)l * Npad * Kp + (size_t)n * Kp + k] = f2b(tile[j][i + r * 8]);
    }
}

// ===================== MFMA GEMM (optionally fused LayerNorm) =====================
// C[M,N] = act(A bf16 @ BT^T + bias + resid); LN=1 requires N==128, col0==0:
// writes x=LN(v) to Cout (f32) and xb (bf16)
template<int ACT, int OUTB, int RES, int LN>
__global__ __launch_bounds__(256) void k_mgemm(const u16* __restrict__ A, const u16* __restrict__ BT,
                                               const float* __restrict__ bias, const float* __restrict__ resid,
                                               void* __restrict__ Cout,
                                               const float* __restrict__ g, const float* __restrict__ be,
                                               u16* __restrict__ xbout, int M, int N, int K) {
    constexpr int SMEMB = LN ? (128 * 133 * 4) : (128 * 64 * 4);
    __shared__ __align__(16) char smem[SMEMB];
    u16* Al = (u16*)smem;
    u16* Bl = Al + 128 * 64;
    int tid = threadIdx.x;
    int wid = tid >> 6, lane = tid & 63;
    int row0 = blockIdx.x * 128;
    int col0 = blockIdx.y * 128;
    int wr = wid >> 1, wc = wid & 1;
    f32x4 acc[4][4] = {};
    int srow = wid * 32 + (lane >> 3);
    int ks8 = ((lane & 7) ^ (lane >> 3)) * 8;

    for (int k0 = 0; k0 < K; k0 += 64) {
        if (k0) __syncthreads();
#pragma unroll
        for (int i = 0; i < 4; ++i) {
            int row = srow + i * 8;
            gload16(A + (size_t)(row0 + row) * K + k0 + ks8, &Al[(wid * 32 + i * 8) * 64]);
            gload16(BT + (size_t)(col0 + row) * K + k0 + ks8, &Bl[(wid * 32 + i * 8) * 64]);
        }
        __syncthreads();
        int rA = lane & 15, kq = lane >> 4;
#pragma unroll
        for (int ks = 0; ks < 2; ++ks) {
            int sw = ((ks * 4 + kq) ^ (rA & 7)) * 8;
            short8 af[4], bfr[4];
#pragma unroll
            for (int m = 0; m < 4; ++m)
                af[m] = *(const short8*)&Al[(64 * wr + m * 16 + rA) * 64 + sw];
#pragma unroll
            for (int n = 0; n < 4; ++n)
                bfr[n] = *(const short8*)&Bl[(64 * wc + n * 16 + rA) * 64 + sw];
#pragma unroll
            for (int m = 0; m < 4; ++m)
#pragma unroll
                for (int n = 0; n < 4; ++n)
                    acc[m][n] = __builtin_amdgcn_mfma_f32_16x16x32_bf16(af[m], bfr[n], acc[m][n], 0, 0, 0);
        }
    }
    int rA = lane & 15, kq = lane >> 4;
    if (LN) {
        float* vbuf = (float*)smem;
        __syncthreads();   // all LDS reads done; reuse as vbuf
#pragma unroll
        for (int m = 0; m < 4; ++m) {
#pragma unroll
            for (int n = 0; n < 4; ++n) {
                int cc = 64 * wc + n * 16 + rA;
                float bv = bias[cc];
#pragma unroll
                for (int r = 0; r < 4; ++r) {
                    int rl = 64 * wr + m * 16 + kq * 4 + r;
                    float v = acc[m][n][r] + bv + resid[(size_t)(row0 + rl) * 128 + cc];
                    vbuf[rl * 133 + cc] = v;
                }
            }
        }
        __syncthreads();
        int rl = tid >> 1, half = tid & 1;
        const float* vrow = vbuf + rl * 133 + half * 64;
        float4 vv[16];
        float s = 0.f, s2 = 0.f;
#pragma unroll
        for (int j = 0; j < 16; ++j) {
            vv[j] = *(const float4*)(vrow + j * 4);
            s += (vv[j].x + vv[j].y) + (vv[j].z + vv[j].w);
            s2 += (vv[j].x * vv[j].x + vv[j].y * vv[j].y) + (vv[j].z * vv[j].z + vv[j].w * vv[j].w);
        }
        s += __shfl_xor(s, 1, 64);
        s2 += __shfl_xor(s2, 1, 64);
        float mean = s * (1.f / 128.f);
        float var = s2 * (1.f / 128.f) - mean * mean;
        float rs = rsqrtf(var + 1e-5f);
        int grow = row0 + rl;
        float* xrow = (float*)Cout + (size_t)grow * 128 + half * 64;
        u16* xbrow = xbout + (size_t)grow * 128 + half * 64;
#pragma unroll
        for (int j = 0; j < 16; ++j) {
            float4 gv = *(const float4*)(g + half * 64 + j * 4);
            float4 bv = *(const float4*)(be + half * 64 + j * 4);
            float o0 = (vv[j].x - mean) * rs * gv.x + bv.x;
            float o1 = (vv[j].y - mean) * rs * gv.y + bv.y;
            float o2 = (vv[j].z - mean) * rs * gv.z + bv.z;
            float o3 = (vv[j].w - mean) * rs * gv.w + bv.w;
            *(float4*)(xrow + j * 4) = make_float4(o0, o1, o2, o3);
            *(ushort4*)(xbrow + j * 4) = make_ushort4(f2b(o0), f2b(o1), f2b(o2), f2b(o3));
        }
    } else {
#pragma unroll
        for (int m = 0; m < 4; ++m) {
#pragma unroll
            for (int n = 0; n < 4; ++n) {
                int cc = col0 + 64 * wc + n * 16 + rA;
                if (cc >= N) continue;
                float bv = bias[cc];
#pragma unroll
                for (int r = 0; r < 4; ++r) {
                    int cr = row0 + 64 * wr + m * 16 + kq * 4 + r;
                    if (cr >= M) continue;
                    float v = acc[m][n][r] + bv;
                    if (RES) v += resid[(size_t)cr * N + cc];
                    if (ACT) v = fmaxf(v, 0.f);
                    if (OUTB) ((u16*)Cout)[(size_t)cr * N + cc] = f2b(v);
                    else      ((float*)Cout)[(size_t)cr * N + cc] = v;
                }
            }
        }
    }
}

// ===================== fusion + positional encoding =====================
__global__ __launch_bounds__(256) void k_fusion(const float* __restrict__ spe, const int* __restrict__ traj,
                                                const float* __restrict__ ue_tab, const int* __restrict__ uid,
                                                const float* __restrict__ tempx, const int* __restrict__ hwx,
                                                const float* __restrict__ ce_tab, const float* __restrict__ flw,
                                                const float* __restrict__ flb, float* __restrict__ x,
                                                u16* __restrict__ xb) {
    __shared__ float Ws[22 * D_];
    __shared__ float bs[D_];
    __shared__ float ins[2][22];
    int tid = threadIdx.x;
    for (int i = tid; i < 22 * D_; i += 256) Ws[i] = flw[i];
    if (tid < D_) bs[tid] = flb[tid];
    __syncthreads();
    int ro = tid >> 7, d = tid & 127;
    int base = blockIdx.x * 32;
    for (int ir = 0; ir < 16; ++ir) {
        int tok = base + ir * 2 + ro;
        int b = tok >> 8, s = tok & 255;
        if (d < TD_) ins[ro][d] = tempx[(size_t)tok * TD_ + d];
        else if (d < 22) ins[ro][d] = ce_tab[(size_t)hwx[tok] * CED_ + (d - TD_)];
        __syncthreads();
        float acc = bs[d];
#pragma unroll
        for (int k = 0; k < 22; ++k) acc = fmaf(ins[ro][k], Ws[k * D_ + d], acc);
        acc = fmaxf(acc, 0.f);
        int i2 = d & ~1;
        float ang = (float)s * __expf(-(float)i2 * 0.0719557841560639f);
        float pe = (d & 1) ? cosf(ang) : sinf(ang);
        float v = spe[(size_t)traj[tok] * D_ + d] + ue_tab[(size_t)uid[b] * D_ + d] + acc + pe;
        x[(size_t)tok * D_ + d] = v;
        xb[(size_t)tok * D_ + d] = f2b(v);
        __syncthreads();
    }
}

// ===================== attention bias =====================
__global__ __launch_bounds__(256) void k_bias(const float* __restrict__ tm, const float* __restrict__ dm,
                                              const int* __restrict__ mask, const float* __restrict__ lambda2,
                                              float* __restrict__ bias) {
    int t = blockIdx.x * 256 + threadIdx.x;
    const int total = B_ * S_ * S_ / 4;
    if (t >= total) return;
    float l2 = *lambda2, l2c = 1.f - l2;
    float4 a = ((const float4*)tm)[t];
    float4 b = ((const float4*)dm)[t];
    int base = t * 4;
    int bb = base >> 16;
    int k0 = base & 255;
    const int* mrow = mask + bb * S_;
    float4 r;
    r.x = (mrow[k0 + 0] > 0 ? 0.f : -1e9f) - (l2 * log1pf(a.x) + l2c * log1pf(b.x));
    r.y = (mrow[k0 + 1] > 0 ? 0.f : -1e9f) - (l2 * log1pf(a.y) + l2c * log1pf(b.y));
    r.z = (mrow[k0 + 2] > 0 ? 0.f : -1e9f) - (l2 * log1pf(a.z) + l2c * log1pf(b.z));
    r.w = (mrow[k0 + 3] > 0 ? 0.f : -1e9f) - (l2 * log1pf(a.w) + l2c * log1pf(b.w));
    ((float4*)bias)[t] = r;
}

// ===================== MFMA flash attention =====================
#define KLS 40
#define VTS 272
__global__ __launch_bounds__(256) void k_attn(const u16* __restrict__ qkv, const float* __restrict__ bias,
                                              u16* __restrict__ o) {
    __shared__ u16 Kl[256 * KLS];
    __shared__ u16 Vt[16 * VTS];
    __shared__ u16 Pl[4 * 16 * VTS];
    int idx = blockIdx.x;
    int b = (idx & 7) * 8 + ((idx >> 3) >> 3);
    int h = (idx >> 3) & 7;
    int tid = threadIdx.x, wid = tid >> 6, lane = tid & 63;

    {
        const u16* kr = qkv + ((size_t)(b * S_ + tid)) * 384 + 128 + h * 16;
        short8 k0v = *(const short8*)kr;
        short8 k1v = *(const short8*)(kr + 8);
        short8 z = {};
        *(short8*)&Kl[tid * KLS + 0]  = k0v;
        *(short8*)&Kl[tid * KLS + 8]  = k1v;
        *(short8*)&Kl[tid * KLS + 16] = z;
        *(short8*)&Kl[tid * KLS + 24] = z;
        const u16* vr = qkv + ((size_t)(b * S_ + tid)) * 384 + 256 + h * 16;
        short8 v0 = *(const short8*)vr;
        short8 v1 = *(const short8*)(vr + 8);
#pragma unroll
        for (int d = 0; d < 8; ++d) Vt[d * VTS + tid] = (u16)v0[d];
#pragma unroll
        for (int d = 0; d < 8; ++d) Vt[(d + 8) * VTS + tid] = (u16)v1[d];
    }
    __syncthreads();

    u16* pl = Pl + wid * 16 * VTS;
    int qi = lane & 15, kq = lane >> 4;

    for (int qt = 0; qt < 4; ++qt) {
        int q0 = wid * 64 + qt * 16;
        int q = q0 + qi;
        float4 bb[16];
        const float* bp = bias + (size_t)b * (S_ * S_) + (size_t)q * S_ + kq * 4;
#pragma unroll
        for (int t = 0; t < 16; ++t) bb[t] = *(const float4*)(bp + t * 16);
        short8 qf = {};
        if (lane < 32)
            qf = *(const short8*)(qkv + ((size_t)(b * S_ + q)) * 384 + h * 16 + kq * 8);
        f32x4 sc[16];
#pragma unroll
        for (int t = 0; t < 16; ++t) {
            short8 kf = *(const short8*)&Kl[(t * 16 + qi) * KLS + kq * 8];
            f32x4 zz = {0.f, 0.f, 0.f, 0.f};
            sc[t] = __builtin_amdgcn_mfma_f32_16x16x32_bf16(kf, qf, zz, 0, 0, 0);
        }
        float m = -1e30f;
#pragma unroll
        for (int t = 0; t < 16; ++t) {
            sc[t][0] = sc[t][0] * 0.25f + bb[t].x;
            sc[t][1] = sc[t][1] * 0.25f + bb[t].y;
            sc[t][2] = sc[t][2] * 0.25f + bb[t].z;
            sc[t][3] = sc[t][3] * 0.25f + bb[t].w;
            m = fmaxf(m, fmaxf(fmaxf(sc[t][0], sc[t][1]), fmaxf(sc[t][2], sc[t][3])));
        }
        m = fmaxf(m, __shfl_xor(m, 16, 64));
        m = fmaxf(m, __shfl_xor(m, 32, 64));
        float l = 0.f;
#pragma unroll
        for (int t = 0; t < 16; ++t) {
            sc[t][0] = __expf(sc[t][0] - m);
            sc[t][1] = __expf(sc[t][1] - m);
            sc[t][2] = __expf(sc[t][2] - m);
            sc[t][3] = __expf(sc[t][3] - m);
            l += (sc[t][0] + sc[t][1]) + (sc[t][2] + sc[t][3]);
        }
        l += __shfl_xor(l, 16, 64);
        l += __shfl_xor(l, 32, 64);
        float inv = 1.f / l;
#pragma unroll
        for (int t = 0; t < 16; ++t) {
            ushort4 pw = make_ushort4(f2b(sc[t][0] * inv), f2b(sc[t][1] * inv),
                                      f2b(sc[t][2] * inv), f2b(sc[t][3] * inv));
            *(ushort4*)&pl[qi * VTS + t * 16 + kq * 4] = pw;
        }
        f32x4 oa = {0.f, 0.f, 0.f, 0.f};
#pragma unroll
        for (int w8 = 0; w8 < 8; ++w8) {
            short8 vf = *(const short8*)&Vt[qi * VTS + w8 * 32 + kq * 8];
            short8 pf = *(const short8*)&pl[qi * VTS + w8 * 32 + kq * 8];
            oa = __builtin_amdgcn_mfma_f32_16x16x32_bf16(vf, pf, oa, 0, 0, 0);
        }
        ushort4 ow = make_ushort4(f2b(oa[0]), f2b(oa[1]), f2b(oa[2]), f2b(oa[3]));
        *(ushort4*)&o[((size_t)(b * S_ + q)) * D_ + h * 16 + kq * 4] = ow;
    }
}

// ===================== gather last token (bf16) =====================
__global__ __launch_bounds__(256) void k_gather(const float* __restrict__ x, const int* __restrict__ endi,
                                                u16* __restrict__ te) {
    int t = blockIdx.x * 256 + threadIdx.x;
    if (t >= B_ * D_) return;
    int b = t >> 7, d = t & 127;
    te[t] = f2b(x[((size_t)b * S_ + endi[b]) * D_ + d]);
}

// ===================== launch =====================
extern "C" void kernel_launch(void* const* d_in, const int* in_sizes, int n_in,
                              void* d_out, int out_size, void* d_ws, size_t ws_size,
                              hipStream_t stream) {
    const float* node_feature = (const float*)d_in[0];
    const int*   edge_index   = (const int*)d_in[1];
    const int*   traj_x       = (const int*)d_in[2];
    const float* temporal_x   = (const float*)d_in[3];
    const int*   user_id_x    = (const int*)d_in[4];
    const int*   mask         = (const int*)d_in[5];
    const int*   end_idx      = (const int*)d_in[6];
    const float* tmat         = (const float*)d_in[8];
    const float* dmat         = (const float*)d_in[9];
    const int*   highway_x    = (const int*)d_in[10];
    const float* lambda2      = (const float*)d_in[11];
    const float* gnn_w1       = (const float*)d_in[12];
    const float* gnn_b1       = (const float*)d_in[13];
    const float* gnn_w2       = (const float*)d_in[14];
    const float* gnn_b2       = (const float*)d_in[15];
    const float* ue_tab       = (const float*)d_in[16];
    const float* ce_tab       = (const float*)d_in[17];
    const float* fl_w         = (const float*)d_in[18];
    const float* fl_b         = (const float*)d_in[19];
    const float* wqkv         = (const float*)d_in[20];
    const float* bqkv         = (const float*)d_in[21];
    const float* wo           = (const float*)d_in[22];
    const float* bo           = (const float*)d_in[23];
    const float* ln1_g        = (const float*)d_in[24];
    const float* ln1_b        = (const float*)d_in[25];
    const float* ln2_g        = (const float*)d_in[26];
    const float* ln2_b        = (const float*)d_in[27];
    const float* ffn_w1       = (const float*)d_in[28];
    const float* ffn_b1       = (const float*)d_in[29];
    const float* ffn_w2       = (const float*)d_in[30];
    const float* ffn_b2       = (const float*)d_in[31];
    const float* head_w       = (const float*)d_in[32];
    const float* head_b       = (const float*)d_in[33];
    float* out = (float*)d_out;

    // ---- workspace layout (float units) ----
    float* w     = (float*)d_ws;
    int*   cnt   = (int*)w;                  // [0, 40,960)
    float* spe   = w + 40960;                // [40,960, 5,169,152)  NP_*128
    float* biasb = w + 5169152;              // [5,169,152, 9,363,456)  B*S*S
    float* wreg  = w + 9363456;              // bf16 weights, 733,184 f total
    u16* wqkvT = (u16*)wreg;                 // 4*384*128 u16
    u16* woT   = wqkvT + 4 * 384 * 128;      // 4*128*128
    u16* w1T   = woT + 4 * 128 * 128;        // 4*512*128
    u16* w2T   = w1T + 4 * 512 * 128;        // 4*128*512
    u16* gw1T  = w2T + 4 * 128 * 512;        // 128*64
    u16* gw2T  = gw1T + 128 * 64;            // 128*128
    u16* hwT   = gw2T + 128 * 128;           // UP_*128
    float* pool  = w + 10096640;
    // GNN phase (float-unit offsets; u16 buffers counted as count/2 floats)
    float* h1    = pool;                     // [0, 5,128,192)          NP_*128 f
    u16*   in1b  = (u16*)(pool + 5128192);   // NP_*64 u16  = 1,282,048 f -> [5,128,192, 6,410,240)
    u16*   in2b  = (u16*)(pool + 6410240);   // NP_*128 u16 = 2,564,096 f -> [6,410,240, 8,974,336)
    int*   off   = (int*)(pool + 8974336);   // 40,064 ints -> [8,974,336, 9,014,400)
    int*   cursor= (int*)(pool + 9014400);   // [9,014,400, 9,054,464)
    int*   ebuf  = (int*)(pool + 9054464);   // 160,000 ints -> [9,054,464, 9,214,464)
    int*   part  = (int*)(pool + 9214464);   // 160 ints
    // transformer phase (overlaps GNN pool; GNN fully done first)
    float* x     = pool;                     // [0, 2,097,152)
    u16*   xb    = (u16*)(pool + 2097152);   // 8192*128 u16 -> [2,097,152, 2,621,440); slot to 3,145,728
    u16*   qkvb  = (u16*)(pool + 3145728);   // 8192*384 u16 = 1,572,864 f -> [3,145,728, 4,718,592)
    u16*   attob = (u16*)(pool + 4718592);   // 8192*128 u16 = 524,288 f -> [4,718,592, 5,242,880)
    u16*   f1b   = (u16*)(pool + 5767168);   // 8192*512 u16 = 2,097,152 f -> [5,767,168, 7,864,320)
    u16*   te    = (u16*)(pool + 7864320);   // 128*128 u16 = 8,192 f
    // total ws used: 10,096,640 + 9,214,624 = 19,311,264 f ~= 77.2 MB

    const int* esrc = edge_index;
    const int* edst = edge_index + E_;

    // weight convert+transpose (coalesced tiles)
    auto cvt = [&](const float* in, u16* outp, int K, int Npad, int Nsrc, int Kp, int L) {
        dim3 grid((Npad + 31) / 32, (Kp + 31) / 32, L);
        k_cvtT<<<grid, 256, 0, stream>>>(in, outp, K, Npad, Nsrc, Kp);
    };
    cvt(wqkv,   wqkvT, 128, 384, 384, 128, 4);
    cvt(wo,     woT,   128, 128, 128, 128, 4);
    cvt(ffn_w1, w1T,   128, 512, 512, 128, 4);
    cvt(ffn_w2, w2T,   512, 128, 128, 512, 4);
    cvt(gnn_w1, gw1T,   32, 128, 128,  64, 1);
    cvt(gnn_w2, gw2T,  128, 128, 128, 128, 1);
    cvt(head_w, hwT,   128, UP_, U_,  128, 1);

    // ---- GNN: CSR build + gather ----
    hipMemsetAsync(cnt, 0, NP_ * sizeof(int), stream);
    k_count<<<(E_ + 255) / 256, 256, 0, stream>>>(edst, cnt);
    k_scan1<<<NSCB, 256, 0, stream>>>(cnt, part);
    k_scan2<<<1, 64, 0, stream>>>(part);
    k_scan3<<<NSCB, 256, 0, stream>>>(cnt, part, off, cursor);
    k_fill<<<(E_ + 255) / 256, 256, 0, stream>>>(esrc, edst, cursor, ebuf);
    k_gprep1<<<NP_ / 8, 256, 0, stream>>>(node_feature, off, cnt, ebuf, in1b);
    k_mgemm<1, 0, 0, 0><<<dim3(NP_ / 128, 1), 256, 0, stream>>>(in1b, gw1T, gnn_b1, nullptr, h1,
                                                                nullptr, nullptr, nullptr, NP_, D_, 64);
    k_gprep2<<<NP_ / 2, 256, 0, stream>>>(h1, off, cnt, ebuf, in2b);
    k_mgemm<1, 0, 0, 0><<<dim3(NP_ / 128, 1), 256, 0, stream>>>(in2b, gw2T, gnn_b2, nullptr, spe,
                                                                nullptr, nullptr, nullptr, NP_, D_, D_);

    // ---- fusion, bias ----
    k_bias<<<(B_ * S_ * S_ / 4) / 256, 256, 0, stream>>>(tmat, dmat, mask, lambda2, biasb);
    k_fusion<<<(B_ * S_) / 32, 256, 0, stream>>>(spe, traj_x, ue_tab, user_id_x,
                                                 temporal_x, highway_x, ce_tab, fl_w, fl_b, x, xb);

    // ---- transformer ----
    const int M = B_ * S_;
    for (int l = 0; l < L_; ++l) {
        k_mgemm<0, 1, 0, 0><<<dim3(M / 128, 3), 256, 0, stream>>>(xb, wqkvT + (size_t)l * 384 * 128,
                                                                  bqkv + l * 384, nullptr, qkvb,
                                                                  nullptr, nullptr, nullptr, M, 384, D_);
        k_attn<<<B_ * H_, 256, 0, stream>>>(qkvb, biasb, attob);
        k_mgemm<0, 0, 1, 1><<<dim3(M / 128, 1), 256, 0, stream>>>(attob, woT + (size_t)l * 128 * 128,
                                                                  bo + l * D_, x, x,
                                                                  ln1_g + l * D_, ln1_b + l * D_, xb, M, D_, D_);
        k_mgemm<1, 1, 0, 0><<<dim3(M / 128, 4), 256, 0, stream>>>(xb, w1T + (size_t)l * 512 * 128,
                                                                  ffn_b1 + l * FF_, nullptr, f1b,
                                                                  nullptr, nullptr, nullptr, M, FF_, D_);
        k_mgemm<0, 0, 1, 1><<<dim3(M / 128, 1), 256, 0, stream>>>(f1b, w2T + (size_t)l * 128 * 512,
                                                                  ffn_b2 + l * D_, x, x,
                                                                  ln2_g + l * D_, ln2_b + l * D_, xb, M, D_, FF_);
    }

    k_gather<<<(B_ * D_ + 255) / 256, 256, 0, stream>>>(x, end_idx, te);
    k_mgemm<0, 0, 0, 0><<<dim3(1, UP_ / 128), 256, 0, stream>>>(te, hwT, head_b, nullptr, out,
                                                                nullptr, nullptr, nullptr, B_, U_, D_);
}

// Round 7
// 505.867 us; speedup vs baseline: 2.3810x; 1.0772x over previous
//
#include <hip/hip_runtime.h>
#include <hip/hip_fp16.h>
#include <cstdint>
#include <cstddef>

typedef unsigned short u16;
typedef __attribute__((ext_vector_type(8))) short short8;
typedef __attribute__((ext_vector_type(4))) float f32x4;

// ---- problem constants ----
#define B_   64
#define S_   256
#define D_   128
#define H_   8
#define DH_  16
#define FF_  512
#define L_   4
#define U_   5000
#define UP_  5120    // U padded to multiple of 128
#define N_   40000
#define NP_  40064   // padded to multiple of 128
#define E_   160000
#define FEA_ 32
#define HWY_ 16
#define CED_ 16
#define TD_  6
#define NSCB 157     // ceil(NP_/256)

static __device__ __forceinline__ u16 f2b(float f) {
    unsigned int u = __float_as_uint(f);
    unsigned int r = (u + 0x7FFFu + ((u >> 16) & 1u)) >> 16;
    return (u16)r;
}
static __device__ __forceinline__ float b2f(u16 u) {
    return __uint_as_float(((unsigned int)u) << 16);
}
static __device__ __forceinline__ u16 f2h(float f) {
    return __half_as_ushort(__float2half(f));
}
static __device__ __forceinline__ float h2f(u16 u) {
    return __half2float(__ushort_as_half(u));
}

static __device__ __forceinline__ void gload16(const void* g, void* l) {
    __builtin_amdgcn_global_load_lds(
        (const __attribute__((address_space(1))) unsigned int*)g,
        (__attribute__((address_space(3))) unsigned int*)l,
        16, 0, 0);
}

// ===================== CSR build =====================
__global__ __launch_bounds__(256) void k_count(const int* __restrict__ dst, int* __restrict__ cnt) {
    int e = blockIdx.x * 256 + threadIdx.x;
    if (e < E_) atomicAdd(&cnt[dst[e]], 1);
}

__global__ __launch_bounds__(256) void k_scan1(const int* __restrict__ cnt, int* __restrict__ part) {
    __shared__ int sh[256];
    int idx = blockIdx.x * 256 + threadIdx.x;
    sh[threadIdx.x] = (idx < NP_) ? cnt[idx] : 0;
    __syncthreads();
    for (int o = 128; o > 0; o >>= 1) {
        if (threadIdx.x < o) sh[threadIdx.x] += sh[threadIdx.x + o];
        __syncthreads();
    }
    if (threadIdx.x == 0) part[blockIdx.x] = sh[0];
}

__global__ __launch_bounds__(64) void k_scan2(int* __restrict__ part) {
    if (threadIdx.x == 0) {
        int run = 0;
        for (int i = 0; i < NSCB; ++i) { int t = part[i]; part[i] = run; run += t; }
    }
}

__global__ __launch_bounds__(256) void k_scan3(const int* __restrict__ cnt, const int* __restrict__ part,
                                               int* __restrict__ off, int* __restrict__ cursor) {
    __shared__ int sh[256];
    int idx = blockIdx.x * 256 + threadIdx.x;
    int v = (idx < NP_) ? cnt[idx] : 0;
    sh[threadIdx.x] = v;
    __syncthreads();
    for (int o = 1; o < 256; o <<= 1) {
        int t = (threadIdx.x >= o) ? sh[threadIdx.x - o] : 0;
        __syncthreads();
        sh[threadIdx.x] += t;
        __syncthreads();
    }
    if (idx < NP_) {
        int res = sh[threadIdx.x] - v + part[blockIdx.x];
        off[idx] = res;
        cursor[idx] = res;
    }
}

__global__ __launch_bounds__(256) void k_fill(const int* __restrict__ src, const int* __restrict__ dst,
                                              int* __restrict__ cursor, int* __restrict__ ebuf) {
    int e = blockIdx.x * 256 + threadIdx.x;
    if (e >= E_) return;
    int p = atomicAdd(&cursor[dst[e]], 1);
    ebuf[p] = src[e];
}

// ===================== GNN gather+prep (fused, ILP-unrolled) =====================
// out1b[n][0..31] = bf16(nf[n] + sum_nbr/(cnt+1)); cols 32..63 = 0
__global__ __launch_bounds__(256) void k_gprep1(const float* __restrict__ nf, const int* __restrict__ off,
                                                const int* __restrict__ cnt, const int* __restrict__ ebuf,
                                                u16* __restrict__ out) {
    int n = blockIdx.x * 8 + (threadIdx.x >> 5);
    int f = threadIdx.x & 31;
    u16 r = 0;
    if (n < N_) {
        int start = off[n], c = cnt[n];
        float acc = 0.f;
        int i = 0;
        for (; i + 4 <= c; i += 4) {
            int s0 = ebuf[start + i], s1 = ebuf[start + i + 1];
            int s2 = ebuf[start + i + 2], s3 = ebuf[start + i + 3];
            float v0 = nf[(size_t)s0 * FEA_ + f];
            float v1 = nf[(size_t)s1 * FEA_ + f];
            float v2 = nf[(size_t)s2 * FEA_ + f];
            float v3 = nf[(size_t)s3 * FEA_ + f];
            acc += (v0 + v1) + (v2 + v3);
        }
        for (; i < c; ++i) {
            int s = ebuf[start + i];
            acc += nf[(size_t)s * FEA_ + f];
        }
        r = f2b(nf[(size_t)n * FEA_ + f] + acc / (float)(c + 1));
    }
    if (n < NP_) {
        out[(size_t)n * 64 + f] = r;
        out[(size_t)n * 64 + 32 + f] = 0;
    }
}

// in2b[n][d] = bf16(h1b[n][d] + sum_nbr/(cnt+1)), h1b bf16
__global__ __launch_bounds__(256) void k_gprep2(const u16* __restrict__ h1b, const int* __restrict__ off,
                                                const int* __restrict__ cnt, const int* __restrict__ ebuf,
                                                u16* __restrict__ out) {
    int n = blockIdx.x * 4 + (threadIdx.x >> 6);
    int d2 = (threadIdx.x & 63) * 2;
    if (n >= NP_) return;
    u16 r0 = 0, r1 = 0;
    if (n < N_) {
        int start = off[n], c = cnt[n];
        float a0 = 0.f, a1 = 0.f;
        int i = 0;
        for (; i + 4 <= c; i += 4) {
            int s0 = ebuf[start + i], s1 = ebuf[start + i + 1];
            int s2 = ebuf[start + i + 2], s3 = ebuf[start + i + 3];
            ushort2 v0 = *(const ushort2*)&h1b[(size_t)s0 * D_ + d2];
            ushort2 v1 = *(const ushort2*)&h1b[(size_t)s1 * D_ + d2];
            ushort2 v2 = *(const ushort2*)&h1b[(size_t)s2 * D_ + d2];
            ushort2 v3 = *(const ushort2*)&h1b[(size_t)s3 * D_ + d2];
            a0 += (b2f(v0.x) + b2f(v1.x)) + (b2f(v2.x) + b2f(v3.x));
            a1 += (b2f(v0.y) + b2f(v1.y)) + (b2f(v2.y) + b2f(v3.y));
        }
        for (; i < c; ++i) {
            int s = ebuf[start + i];
            ushort2 v = *(const ushort2*)&h1b[(size_t)s * D_ + d2];
            a0 += b2f(v.x); a1 += b2f(v.y);
        }
        float rinv = 1.f / (float)(c + 1);
        ushort2 sv = *(const ushort2*)&h1b[(size_t)n * D_ + d2];
        r0 = f2b(b2f(sv.x) + a0 * rinv);
        r1 = f2b(b2f(sv.y) + a1 * rinv);
    }
    *(ushort2*)&out[(size_t)n * D_ + d2] = make_ushort2(r0, r1);
}

// ===================== tiled weight transpose+convert =====================
__global__ __launch_bounds__(256) void k_cvtT(const float* __restrict__ in, u16* __restrict__ out,
                                              int K, int Npad, int Nsrc, int Kp) {
    __shared__ float tile[32][33];
    int l = blockIdx.z;
    int n0 = blockIdx.x * 32, k0 = blockIdx.y * 32;
    int j = threadIdx.x & 31, i = threadIdx.x >> 5;
#pragma unroll
    for (int r = 0; r < 4; ++r) {
        int k = k0 + i + r * 8, n = n0 + j;
        tile[i + r * 8][j] = (k < K && n < Nsrc) ? in[(size_t)l * K * Nsrc + (size_t)k * Nsrc + n] : 0.f;
    }
    __syncthreads();
#pragma unroll
    for (int r = 0; r < 4; ++r) {
        int n = n0 + i + r * 8, k = k0 + j;
        if (n < Npad && k < Kp)
            out[(size_t)l * Npad * Kp + (size_t)n * Kp + k] = f2b(tile[j][i + r * 8]);
    }
}

// ===================== MFMA GEMM (optionally fused LayerNorm) =====================
template<int ACT, int OUTB, int RES, int LN>
__global__ __launch_bounds__(256) void k_mgemm(const u16* __restrict__ A, const u16* __restrict__ BT,
                                               const float* __restrict__ bias, const float* __restrict__ resid,
                                               void* __restrict__ Cout,
                                               const float* __restrict__ g, const float* __restrict__ be,
                                               u16* __restrict__ xbout, int M, int N, int K) {
    constexpr int SMEMB = LN ? (128 * 133 * 4) : (128 * 64 * 4);
    __shared__ __align__(16) char smem[SMEMB];
    u16* Al = (u16*)smem;
    u16* Bl = Al + 128 * 64;
    int tid = threadIdx.x;
    int wid = tid >> 6, lane = tid & 63;
    int row0 = blockIdx.x * 128;
    int col0 = blockIdx.y * 128;
    int wr = wid >> 1, wc = wid & 1;
    f32x4 acc[4][4] = {};
    int srow = wid * 32 + (lane >> 3);
    int ks8 = ((lane & 7) ^ (lane >> 3)) * 8;

    for (int k0 = 0; k0 < K; k0 += 64) {
        if (k0) __syncthreads();
#pragma unroll
        for (int i = 0; i < 4; ++i) {
            int row = srow + i * 8;
            gload16(A + (size_t)(row0 + row) * K + k0 + ks8, &Al[(wid * 32 + i * 8) * 64]);
            gload16(BT + (size_t)(col0 + row) * K + k0 + ks8, &Bl[(wid * 32 + i * 8) * 64]);
        }
        __syncthreads();
        int rA = lane & 15, kq = lane >> 4;
#pragma unroll
        for (int ks = 0; ks < 2; ++ks) {
            int sw = ((ks * 4 + kq) ^ (rA & 7)) * 8;
            short8 af[4], bfr[4];
#pragma unroll
            for (int m = 0; m < 4; ++m)
                af[m] = *(const short8*)&Al[(64 * wr + m * 16 + rA) * 64 + sw];
#pragma unroll
            for (int n = 0; n < 4; ++n)
                bfr[n] = *(const short8*)&Bl[(64 * wc + n * 16 + rA) * 64 + sw];
#pragma unroll
            for (int m = 0; m < 4; ++m)
#pragma unroll
                for (int n = 0; n < 4; ++n)
                    acc[m][n] = __builtin_amdgcn_mfma_f32_16x16x32_bf16(af[m], bfr[n], acc[m][n], 0, 0, 0);
        }
    }
    int rA = lane & 15, kq = lane >> 4;
    if (LN) {
        float* vbuf = (float*)smem;
        __syncthreads();
#pragma unroll
        for (int m = 0; m < 4; ++m) {
#pragma unroll
            for (int n = 0; n < 4; ++n) {
                int cc = 64 * wc + n * 16 + rA;
                float bv = bias[cc];
#pragma unroll
                for (int r = 0; r < 4; ++r) {
                    int rl = 64 * wr + m * 16 + kq * 4 + r;
                    float v = acc[m][n][r] + bv + resid[(size_t)(row0 + rl) * 128 + cc];
                    vbuf[rl * 133 + cc] = v;
                }
            }
        }
        __syncthreads();
        int rl = tid >> 1, half = tid & 1;
        const float* vrow = vbuf + rl * 133 + half * 64;
        float4 vv[16];
        float s = 0.f, s2 = 0.f;
#pragma unroll
        for (int j = 0; j < 16; ++j) {
            vv[j] = *(const float4*)(vrow + j * 4);
            s += (vv[j].x + vv[j].y) + (vv[j].z + vv[j].w);
            s2 += (vv[j].x * vv[j].x + vv[j].y * vv[j].y) + (vv[j].z * vv[j].z + vv[j].w * vv[j].w);
        }
        s += __shfl_xor(s, 1, 64);
        s2 += __shfl_xor(s2, 1, 64);
        float mean = s * (1.f / 128.f);
        float var = s2 * (1.f / 128.f) - mean * mean;
        float rs = rsqrtf(var + 1e-5f);
        int grow = row0 + rl;
        float* xrow = (float*)Cout + (size_t)grow * 128 + half * 64;
        u16* xbrow = xbout + (size_t)grow * 128 + half * 64;
#pragma unroll
        for (int j = 0; j < 16; ++j) {
            float4 gv = *(const float4*)(g + half * 64 + j * 4);
            float4 bv = *(const float4*)(be + half * 64 + j * 4);
            float o0 = (vv[j].x - mean) * rs * gv.x + bv.x;
            float o1 = (vv[j].y - mean) * rs * gv.y + bv.y;
            float o2 = (vv[j].z - mean) * rs * gv.z + bv.z;
            float o3 = (vv[j].w - mean) * rs * gv.w + bv.w;
            *(float4*)(xrow + j * 4) = make_float4(o0, o1, o2, o3);
            *(ushort4*)(xbrow + j * 4) = make_ushort4(f2b(o0), f2b(o1), f2b(o2), f2b(o3));
        }
    } else {
#pragma unroll
        for (int m = 0; m < 4; ++m) {
#pragma unroll
            for (int n = 0; n < 4; ++n) {
                int cc = col0 + 64 * wc + n * 16 + rA;
                if (cc >= N) continue;
                float bv = bias[cc];
#pragma unroll
                for (int r = 0; r < 4; ++r) {
                    int cr = row0 + 64 * wr + m * 16 + kq * 4 + r;
                    if (cr >= M) continue;
                    float v = acc[m][n][r] + bv;
                    if (RES) v += resid[(size_t)cr * N + cc];
                    if (ACT) v = fmaxf(v, 0.f);
                    if (OUTB) ((u16*)Cout)[(size_t)cr * N + cc] = f2b(v);
                    else      ((float*)Cout)[(size_t)cr * N + cc] = v;
                }
            }
        }
    }
}

// ===================== fusion + positional encoding =====================
__global__ __launch_bounds__(256) void k_fusion(const float* __restrict__ spe, const int* __restrict__ traj,
                                                const float* __restrict__ ue_tab, const int* __restrict__ uid,
                                                const float* __restrict__ tempx, const int* __restrict__ hwx,
                                                const float* __restrict__ ce_tab, const float* __restrict__ flw,
                                                const float* __restrict__ flb, float* __restrict__ x,
                                                u16* __restrict__ xb) {
    __shared__ float Ws[22 * D_];
    __shared__ float bs[D_];
    __shared__ float ins[2][22];
    int tid = threadIdx.x;
    for (int i = tid; i < 22 * D_; i += 256) Ws[i] = flw[i];
    if (tid < D_) bs[tid] = flb[tid];
    __syncthreads();
    int ro = tid >> 7, d = tid & 127;
    int base = blockIdx.x * 32;
    for (int ir = 0; ir < 16; ++ir) {
        int tok = base + ir * 2 + ro;
        int b = tok >> 8, s = tok & 255;
        if (d < TD_) ins[ro][d] = tempx[(size_t)tok * TD_ + d];
        else if (d < 22) ins[ro][d] = ce_tab[(size_t)hwx[tok] * CED_ + (d - TD_)];
        __syncthreads();
        float acc = bs[d];
#pragma unroll
        for (int k = 0; k < 22; ++k) acc = fmaf(ins[ro][k], Ws[k * D_ + d], acc);
        acc = fmaxf(acc, 0.f);
        int i2 = d & ~1;
        float ang = (float)s * __expf(-(float)i2 * 0.0719557841560639f);
        float pe = (d & 1) ? cosf(ang) : sinf(ang);
        float v = spe[(size_t)traj[tok] * D_ + d] + ue_tab[(size_t)uid[b] * D_ + d] + acc + pe;
        x[(size_t)tok * D_ + d] = v;
        xb[(size_t)tok * D_ + d] = f2b(v);
        __syncthreads();
    }
}

// ===================== attention bias (fp16 out) =====================
__global__ __launch_bounds__(256) void k_bias(const float* __restrict__ tm, const float* __restrict__ dm,
                                              const int* __restrict__ mask, const float* __restrict__ lambda2,
                                              u16* __restrict__ bias) {
    int t = blockIdx.x * 256 + threadIdx.x;
    const int total = B_ * S_ * S_ / 4;
    if (t >= total) return;
    float l2 = *lambda2, l2c = 1.f - l2;
    float4 a = ((const float4*)tm)[t];
    float4 b = ((const float4*)dm)[t];
    int base = t * 4;
    int bb = base >> 16;
    int k0 = base & 255;
    const int* mrow = mask + bb * S_;
    float r0 = (mrow[k0 + 0] > 0 ? 0.f : -30000.f) - (l2 * __logf(1.f + a.x) + l2c * __logf(1.f + b.x));
    float r1 = (mrow[k0 + 1] > 0 ? 0.f : -30000.f) - (l2 * __logf(1.f + a.y) + l2c * __logf(1.f + b.y));
    float r2 = (mrow[k0 + 2] > 0 ? 0.f : -30000.f) - (l2 * __logf(1.f + a.z) + l2c * __logf(1.f + b.z));
    float r3 = (mrow[k0 + 3] > 0 ? 0.f : -30000.f) - (l2 * __logf(1.f + a.w) + l2c * __logf(1.f + b.w));
    *(ushort4*)&bias[(size_t)t * 4] = make_ushort4(f2h(r0), f2h(r1), f2h(r2), f2h(r3));
}

// ===================== MFMA flash attention (fp16 bias) =====================
#define KLS 40
#define VTS 272
__global__ __launch_bounds__(256) void k_attn(const u16* __restrict__ qkv, const u16* __restrict__ bias,
                                              u16* __restrict__ o) {
    __shared__ u16 Kl[256 * KLS];
    __shared__ u16 Vt[16 * VTS];
    __shared__ u16 Pl[4 * 16 * VTS];
    int idx = blockIdx.x;
    int b = (idx & 7) * 8 + ((idx >> 3) >> 3);
    int h = (idx >> 3) & 7;
    int tid = threadIdx.x, wid = tid >> 6, lane = tid & 63;

    {
        const u16* kr = qkv + ((size_t)(b * S_ + tid)) * 384 + 128 + h * 16;
        short8 k0v = *(const short8*)kr;
        short8 k1v = *(const short8*)(kr + 8);
        short8 z = {};
        *(short8*)&Kl[tid * KLS + 0]  = k0v;
        *(short8*)&Kl[tid * KLS + 8]  = k1v;
        *(short8*)&Kl[tid * KLS + 16] = z;
        *(short8*)&Kl[tid * KLS + 24] = z;
        const u16* vr = qkv + ((size_t)(b * S_ + tid)) * 384 + 256 + h * 16;
        short8 v0 = *(const short8*)vr;
        short8 v1 = *(const short8*)(vr + 8);
#pragma unroll
        for (int d = 0; d < 8; ++d) Vt[d * VTS + tid] = (u16)v0[d];
#pragma unroll
        for (int d = 0; d < 8; ++d) Vt[(d + 8) * VTS + tid] = (u16)v1[d];
    }
    __syncthreads();

    u16* pl = Pl + wid * 16 * VTS;
    int qi = lane & 15, kq = lane >> 4;

    for (int qt = 0; qt < 4; ++qt) {
        int q0 = wid * 64 + qt * 16;
        int q = q0 + qi;
        ushort4 bb[16];
        const u16* bp = bias + (size_t)b * (S_ * S_) + (size_t)q * S_ + kq * 4;
#pragma unroll
        for (int t = 0; t < 16; ++t) bb[t] = *(const ushort4*)(bp + t * 16);
        short8 qf = {};
        if (lane < 32)
            qf = *(const short8*)(qkv + ((size_t)(b * S_ + q)) * 384 + h * 16 + kq * 8);
        f32x4 sc[16];
#pragma unroll
        for (int t = 0; t < 16; ++t) {
            short8 kf = *(const short8*)&Kl[(t * 16 + qi) * KLS + kq * 8];
            f32x4 zz = {0.f, 0.f, 0.f, 0.f};
            sc[t] = __builtin_amdgcn_mfma_f32_16x16x32_bf16(kf, qf, zz, 0, 0, 0);
        }
        float m = -1e30f;
#pragma unroll
        for (int t = 0; t < 16; ++t) {
            sc[t][0] = sc[t][0] * 0.25f + h2f(bb[t].x);
            sc[t][1] = sc[t][1] * 0.25f + h2f(bb[t].y);
            sc[t][2] = sc[t][2] * 0.25f + h2f(bb[t].z);
            sc[t][3] = sc[t][3] * 0.25f + h2f(bb[t].w);
            m = fmaxf(m, fmaxf(fmaxf(sc[t][0], sc[t][1]), fmaxf(sc[t][2], sc[t][3])));
        }
        m = fmaxf(m, __shfl_xor(m, 16, 64));
        m = fmaxf(m, __shfl_xor(m, 32, 64));
        float l = 0.f;
#pragma unroll
        for (int t = 0; t < 16; ++t) {
            sc[t][0] = __expf(sc[t][0] - m);
            sc[t][1] = __expf(sc[t][1] - m);
            sc[t][2] = __expf(sc[t][2] - m);
            sc[t][3] = __expf(sc[t][3] - m);
            l += (sc[t][0] + sc[t][1]) + (sc[t][2] + sc[t][3]);
        }
        l += __shfl_xor(l, 16, 64);
        l += __shfl_xor(l, 32, 64);
        float inv = 1.f / l;
#pragma unroll
        for (int t = 0; t < 16; ++t) {
            ushort4 pw = make_ushort4(f2b(sc[t][0] * inv), f2b(sc[t][1] * inv),
                                      f2b(sc[t][2] * inv), f2b(sc[t][3] * inv));
            *(ushort4*)&pl[qi * VTS + t * 16 + kq * 4] = pw;
        }
        f32x4 oa = {0.f, 0.f, 0.f, 0.f};
#pragma unroll
        for (int w8 = 0; w8 < 8; ++w8) {
            short8 vf = *(const short8*)&Vt[qi * VTS + w8 * 32 + kq * 8];
            short8 pf = *(const short8*)&pl[qi * VTS + w8 * 32 + kq * 8];
            oa = __builtin_amdgcn_mfma_f32_16x16x32_bf16(vf, pf, oa, 0, 0, 0);
        }
        ushort4 ow = make_ushort4(f2b(oa[0]), f2b(oa[1]), f2b(oa[2]), f2b(oa[3]));
        *(ushort4*)&o[((size_t)(b * S_ + q)) * D_ + h * 16 + kq * 4] = ow;
    }
}

// ===================== gather last token (bf16) =====================
__global__ __launch_bounds__(256) void k_gather(const float* __restrict__ x, const int* __restrict__ endi,
                                                u16* __restrict__ te) {
    int t = blockIdx.x * 256 + threadIdx.x;
    if (t >= B_ * D_) return;
    int b = t >> 7, d = t & 127;
    te[t] = f2b(x[((size_t)b * S_ + endi[b]) * D_ + d]);
}

// ===================== launch =====================
extern "C" void kernel_launch(void* const* d_in, const int* in_sizes, int n_in,
                              void* d_out, int out_size, void* d_ws, size_t ws_size,
                              hipStream_t stream) {
    const float* node_feature = (const float*)d_in[0];
    const int*   edge_index   = (const int*)d_in[1];
    const int*   traj_x       = (const int*)d_in[2];
    const float* temporal_x   = (const float*)d_in[3];
    const int*   user_id_x    = (const int*)d_in[4];
    const int*   mask         = (const int*)d_in[5];
    const int*   end_idx      = (const int*)d_in[6];
    const float* tmat         = (const float*)d_in[8];
    const float* dmat         = (const float*)d_in[9];
    const int*   highway_x    = (const int*)d_in[10];
    const float* lambda2      = (const float*)d_in[11];
    const float* gnn_w1       = (const float*)d_in[12];
    const float* gnn_b1       = (const float*)d_in[13];
    const float* gnn_w2       = (const float*)d_in[14];
    const float* gnn_b2       = (const float*)d_in[15];
    const float* ue_tab       = (const float*)d_in[16];
    const float* ce_tab       = (const float*)d_in[17];
    const float* fl_w         = (const float*)d_in[18];
    const float* fl_b         = (const float*)d_in[19];
    const float* wqkv         = (const float*)d_in[20];
    const float* bqkv         = (const float*)d_in[21];
    const float* wo           = (const float*)d_in[22];
    const float* bo           = (const float*)d_in[23];
    const float* ln1_g        = (const float*)d_in[24];
    const float* ln1_b        = (const float*)d_in[25];
    const float* ln2_g        = (const float*)d_in[26];
    const float* ln2_b        = (const float*)d_in[27];
    const float* ffn_w1       = (const float*)d_in[28];
    const float* ffn_b1       = (const float*)d_in[29];
    const float* ffn_w2       = (const float*)d_in[30];
    const float* ffn_b2       = (const float*)d_in[31];
    const float* head_w       = (const float*)d_in[32];
    const float* head_b       = (const float*)d_in[33];
    float* out = (float*)d_out;

    // ---- workspace layout (float units; u16 buffers sized as u16_count/2 floats) ----
    float* w     = (float*)d_ws;
    int*   cnt   = (int*)w;                  // [0, 40,960)
    float* spe   = w + 40960;                // [40,960, 5,169,152)  NP_*128 f32
    u16*   biasb = (u16*)(w + 5169152);      // B*S*S = 4,194,304 u16 = 2,097,152 f -> [5,169,152, 7,266,304)
    float* wreg  = w + 7266304;              // bf16 weights: 1,466,368 u16 = 733,184 f -> ends 7,999,488
    u16* wqkvT = (u16*)wreg;                 // 196,608 u16
    u16* woT   = wqkvT + 4 * 384 * 128;      //  65,536
    u16* w1T   = woT + 4 * 128 * 128;        // 262,144
    u16* w2T   = w1T + 4 * 512 * 128;        // 262,144
    u16* gw1T  = w2T + 4 * 128 * 512;        //   8,192
    u16* gw2T  = gw1T + 128 * 64;            //  16,384
    u16* hwT   = gw2T + 128 * 128;           // 655,360
    float* pool  = w + 8000000;
    // GNN phase (sizes: NP_*128 u16 = 5,128,192 u16 = 2,564,096 f; NP_*64 u16 = 1,282,048 f)
    u16*   h1b   = (u16*)pool;               // [0, 2,564,096) f
    u16*   in1b  = (u16*)(pool + 2564096);   // [2,564,096, 3,846,144) f
    u16*   in2b  = (u16*)(pool + 3846144);   // [3,846,144, 6,410,240) f
    int*   off   = (int*)(pool + 6410240);   // [6,410,240, 6,450,304)
    int*   cursor= (int*)(pool + 6450304);   // [6,450,304, 6,490,368)
    int*   ebuf  = (int*)(pool + 6490368);   // [6,490,368, 6,650,368)
    int*   part  = (int*)(pool + 6650368);   // 160 ints
    // transformer phase (overlaps GNN pool; GNN fully done before fusion)
    float* x     = pool;                     // [0, 2,097,152)
    u16*   xb    = (u16*)(pool + 2097152);   // 1,048,576 u16 -> [2,097,152, 2,621,440)
    u16*   qkvb  = (u16*)(pool + 3145728);   // 3,145,728 u16 = 1,572,864 f -> [3,145,728, 4,718,592)
    u16*   attob = (u16*)(pool + 4718592);   // 1,048,576 u16 -> [4,718,592, 5,242,880)
    u16*   f1b   = (u16*)(pool + 5767168);   // 4,194,304 u16 = 2,097,152 f -> [5,767,168, 7,864,320)
    u16*   te    = (u16*)(pool + 7864320);   // 16,384 u16 -> [7,864,320, 7,872,512)
    // total: 8,000,000 + 7,872,512 = 15,872,512 f ~= 63.5 MB

    const int* esrc = edge_index;
    const int* edst = edge_index + E_;

    auto cvt = [&](const float* in, u16* outp, int K, int Npad, int Nsrc, int Kp, int L) {
        dim3 grid((Npad + 31) / 32, (Kp + 31) / 32, L);
        k_cvtT<<<grid, 256, 0, stream>>>(in, outp, K, Npad, Nsrc, Kp);
    };
    cvt(wqkv,   wqkvT, 128, 384, 384, 128, 4);
    cvt(wo,     woT,   128, 128, 128, 128, 4);
    cvt(ffn_w1, w1T,   128, 512, 512, 128, 4);
    cvt(ffn_w2, w2T,   512, 128, 128, 512, 4);
    cvt(gnn_w1, gw1T,   32, 128, 128,  64, 1);
    cvt(gnn_w2, gw2T,  128, 128, 128, 128, 1);
    cvt(head_w, hwT,   128, UP_, U_,  128, 1);

    // ---- GNN: CSR build + gather ----
    hipMemsetAsync(cnt, 0, NP_ * sizeof(int), stream);
    k_count<<<(E_ + 255) / 256, 256, 0, stream>>>(edst, cnt);
    k_scan1<<<NSCB, 256, 0, stream>>>(cnt, part);
    k_scan2<<<1, 64, 0, stream>>>(part);
    k_scan3<<<NSCB, 256, 0, stream>>>(cnt, part, off, cursor);
    k_fill<<<(E_ + 255) / 256, 256, 0, stream>>>(esrc, edst, cursor, ebuf);
    k_gprep1<<<NP_ / 8, 256, 0, stream>>>(node_feature, off, cnt, ebuf, in1b);
    k_mgemm<1, 1, 0, 0><<<dim3(NP_ / 128, 1), 256, 0, stream>>>(in1b, gw1T, gnn_b1, nullptr, h1b,
                                                                nullptr, nullptr, nullptr, NP_, D_, 64);
    k_gprep2<<<NP_ / 4, 256, 0, stream>>>(h1b, off, cnt, ebuf, in2b);
    k_mgemm<1, 0, 0, 0><<<dim3(NP_ / 128, 1), 256, 0, stream>>>(in2b, gw2T, gnn_b2, nullptr, spe,
                                                                nullptr, nullptr, nullptr, NP_, D_, D_);

    // ---- fusion, bias ----
    k_bias<<<(B_ * S_ * S_ / 4) / 256, 256, 0, stream>>>(tmat, dmat, mask, lambda2, biasb);
    k_fusion<<<(B_ * S_) / 32, 256, 0, stream>>>(spe, traj_x, ue_tab, user_id_x,
                                                 temporal_x, highway_x, ce_tab, fl_w, fl_b, x, xb);

    // ---- transformer ----
    const int M = B_ * S_;
    for (int l = 0; l < L_; ++l) {
        k_mgemm<0, 1, 0, 0><<<dim3(M / 128, 3), 256, 0, stream>>>(xb, wqkvT + (size_t)l * 384 * 128,
                                                                  bqkv + l * 384, nullptr, qkvb,
                                                                  nullptr, nullptr, nullptr, M, 384, D_);
        k_attn<<<B_ * H_, 256, 0, stream>>>(qkvb, biasb, attob);
        k_mgemm<0, 0, 1, 1><<<dim3(M / 128, 1), 256, 0, stream>>>(attob, woT + (size_t)l * 128 * 128,
                                                                  bo + l * D_, x, x,
                                                                  ln1_g + l * D_, ln1_b + l * D_, xb, M, D_, D_);
        k_mgemm<1, 1, 0, 0><<<dim3(M / 128, 4), 256, 0, stream>>>(xb, w1T + (size_t)l * 512 * 128,
                                                                  ffn_b1 + l * FF_, nullptr, f1b,
                                                                  nullptr, nullptr, nullptr, M, FF_, D_);
        k_mgemm<0, 0, 1, 1><<<dim3(M / 128, 1), 256, 0, stream>>>(f1b, w2T + (size_t)l * 128 * 512,
                                                                  ffn_b2 + l * D_, x, x,
                                                                  ln2_g + l * D_, ln2_b + l * D_, xb, M, D_, FF_);
    }

    k_gather<<<(B_ * D_ + 255) / 256, 256, 0, stream>>>(x, end_idx, te);
    k_mgemm<0, 0, 0, 0><<<dim3(1, UP_ / 128), 256, 0, stream>>>(te, hwT, head_b, nullptr, out,
                                                                nullptr, nullptr, nullptr, B_, U_, D_);
}

// Round 8
// 422.695 us; speedup vs baseline: 2.8495x; 1.1968x over previous
//
#include <hip/hip_runtime.h>
#include <hip/hip_fp16.h>
#include <cstdint>
#include <cstddef>

typedef unsigned short u16;
typedef __attribute__((ext_vector_type(8))) short short8;
typedef __attribute__((ext_vector_type(4))) float f32x4;

// ---- problem constants ----
#define B_   64
#define S_   256
#define D_   128
#define H_   8
#define DH_  16
#define FF_  512
#define L_   4
#define U_   5000
#define UP_  5120
#define N_   40000
#define NP_  40064
#define E_   160000
#define FEA_ 32
#define HWY_ 16
#define CED_ 16
#define TD_  6
#define NSCB 157     // ceil(NP_/256)
// uber kernel block ranges
#define UB_CNT_END 160
#define UB_CVT_END 1592
#define UB_TOTAL   5688

static __device__ __forceinline__ u16 f2b(float f) {
    unsigned int u = __float_as_uint(f);
    unsigned int r = (u + 0x7FFFu + ((u >> 16) & 1u)) >> 16;
    return (u16)r;
}
static __device__ __forceinline__ float b2f(u16 u) {
    return __uint_as_float(((unsigned int)u) << 16);
}
static __device__ __forceinline__ u16 f2h(float f) {
    return __half_as_ushort(__float2half(f));
}
static __device__ __forceinline__ float h2f(u16 u) {
    return __half2float(__ushort_as_half(u));
}

static __device__ __forceinline__ void gload16(const void* g, void* l) {
    __builtin_amdgcn_global_load_lds(
        (const __attribute__((address_space(1))) unsigned int*)g,
        (__attribute__((address_space(3))) unsigned int*)l,
        16, 0, 0);
}

// ===================== uber prep: cnt-zero + 7 weight transposes + attn bias =====================
struct UberArgs {
    const float* csrc[7];
    u16* cdst[7];
    int K[7], Npad[7], Nsrc[7], Kp[7], base[7];
    const float* tm; const float* dm; const int* maskp; const float* lambda2;
    u16* bias; int* cnt;
};

__global__ __launch_bounds__(256) void k_uber(UberArgs a) {
    __shared__ float tile[32][33];
    int bid = blockIdx.x, tid = threadIdx.x;
    if (bid < UB_CNT_END) {
        int idx = bid * 256 + tid;
        if (idx < NP_) a.cnt[idx] = 0;
        return;
    }
    if (bid < UB_CVT_END) {
        int t = 0;
#pragma unroll
        for (int i = 1; i < 7; ++i) t += (bid >= a.base[i]);
        int rb = bid - a.base[t];
        int K = a.K[t], Npad = a.Npad[t], Nsrc = a.Nsrc[t], Kp = a.Kp[t];
        int nbn = Npad >> 5, nbk = Kp >> 5;
        int per = nbn * nbk;
        int l = rb / per, rem = rb - l * per;
        int n0 = (rem % nbn) * 32, k0 = (rem / nbn) * 32;
        const float* in = a.csrc[t];
        u16* outp = a.cdst[t];
        int j = tid & 31, i2 = tid >> 5;
#pragma unroll
        for (int r = 0; r < 4; ++r) {
            int k = k0 + i2 + r * 8, n = n0 + j;
            tile[i2 + r * 8][j] = (k < K && n < Nsrc) ? in[(size_t)l * K * Nsrc + (size_t)k * Nsrc + n] : 0.f;
        }
        __syncthreads();
#pragma unroll
        for (int r = 0; r < 4; ++r) {
            int n = n0 + i2 + r * 8, k = k0 + j;
            if (n < Npad && k < Kp)
                outp[(size_t)l * Npad * Kp + (size_t)n * Kp + k] = f2b(tile[j][i2 + r * 8]);
        }
        return;
    }
    // attention bias (fp16)
    int t4 = (bid - UB_CVT_END) * 256 + tid;
    const int total = B_ * S_ * S_ / 4;
    if (t4 >= total) return;
    float l2 = *a.lambda2, l2c = 1.f - l2;
    float4 av = ((const float4*)a.tm)[t4];
    float4 bv = ((const float4*)a.dm)[t4];
    int basei = t4 * 4;
    int bb = basei >> 16;
    int k0 = basei & 255;
    const int* mrow = a.maskp + bb * S_;
    float r0 = (mrow[k0 + 0] > 0 ? 0.f : -30000.f) - (l2 * __logf(1.f + av.x) + l2c * __logf(1.f + bv.x));
    float r1 = (mrow[k0 + 1] > 0 ? 0.f : -30000.f) - (l2 * __logf(1.f + av.y) + l2c * __logf(1.f + bv.y));
    float r2 = (mrow[k0 + 2] > 0 ? 0.f : -30000.f) - (l2 * __logf(1.f + av.z) + l2c * __logf(1.f + bv.z));
    float r3 = (mrow[k0 + 3] > 0 ? 0.f : -30000.f) - (l2 * __logf(1.f + av.w) + l2c * __logf(1.f + bv.w));
    *(ushort4*)&a.bias[(size_t)t4 * 4] = make_ushort4(f2h(r0), f2h(r1), f2h(r2), f2h(r3));
}

// ===================== CSR build =====================
__global__ __launch_bounds__(256) void k_count(const int* __restrict__ dst, int* __restrict__ cnt) {
    int e = blockIdx.x * 256 + threadIdx.x;
    if (e < E_) atomicAdd(&cnt[dst[e]], 1);
}

__global__ __launch_bounds__(256) void k_scanA(const int* __restrict__ cnt, int* __restrict__ part) {
    __shared__ int sh[256];
    int idx = blockIdx.x * 256 + threadIdx.x;
    sh[threadIdx.x] = (idx < NP_) ? cnt[idx] : 0;
    __syncthreads();
    for (int o = 128; o > 0; o >>= 1) {
        if (threadIdx.x < o) sh[threadIdx.x] += sh[threadIdx.x + o];
        __syncthreads();
    }
    if (threadIdx.x == 0) part[blockIdx.x] = sh[0];
}

// fused: exclusive base over partials + intra-block scan
__global__ __launch_bounds__(256) void k_scanB(const int* __restrict__ cnt, const int* __restrict__ part,
                                               int* __restrict__ off, int* __restrict__ cursor) {
    __shared__ int sh[256];
    __shared__ int bsum;
    int tid = threadIdx.x;
    int pv = (tid < blockIdx.x) ? part[tid] : 0;   // blockIdx.x <= 156 < 256
    sh[tid] = pv;
    __syncthreads();
    for (int o = 128; o > 0; o >>= 1) {
        if (tid < o) sh[tid] += sh[tid + o];
        __syncthreads();
    }
    if (tid == 0) bsum = sh[0];
    __syncthreads();
    int basev = bsum;
    __syncthreads();
    int idx = blockIdx.x * 256 + tid;
    int v = (idx < NP_) ? cnt[idx] : 0;
    sh[tid] = v;
    __syncthreads();
    for (int o = 1; o < 256; o <<= 1) {
        int t2 = (tid >= o) ? sh[tid - o] : 0;
        __syncthreads();
        sh[tid] += t2;
        __syncthreads();
    }
    if (idx < NP_) {
        int res = sh[tid] - v + basev;
        off[idx] = res;
        cursor[idx] = res;
    }
}

__global__ __launch_bounds__(256) void k_fill(const int* __restrict__ src, const int* __restrict__ dst,
                                              int* __restrict__ cursor, int* __restrict__ ebuf) {
    int e = blockIdx.x * 256 + threadIdx.x;
    if (e >= E_) return;
    int p = atomicAdd(&cursor[dst[e]], 1);
    ebuf[p] = src[e];
}

// ===================== GNN gather+prep =====================
__global__ __launch_bounds__(256) void k_gprep1(const float* __restrict__ nf, const int* __restrict__ off,
                                                const int* __restrict__ cnt, const int* __restrict__ ebuf,
                                                u16* __restrict__ out) {
    int n = blockIdx.x * 8 + (threadIdx.x >> 5);
    int f = threadIdx.x & 31;
    u16 r = 0;
    if (n < N_) {
        int start = off[n], c = cnt[n];
        float acc = 0.f;
        int i = 0;
        for (; i + 4 <= c; i += 4) {
            int s0 = ebuf[start + i], s1 = ebuf[start + i + 1];
            int s2 = ebuf[start + i + 2], s3 = ebuf[start + i + 3];
            float v0 = nf[(size_t)s0 * FEA_ + f];
            float v1 = nf[(size_t)s1 * FEA_ + f];
            float v2 = nf[(size_t)s2 * FEA_ + f];
            float v3 = nf[(size_t)s3 * FEA_ + f];
            acc += (v0 + v1) + (v2 + v3);
        }
        for (; i < c; ++i) {
            int s = ebuf[start + i];
            acc += nf[(size_t)s * FEA_ + f];
        }
        r = f2b(nf[(size_t)n * FEA_ + f] + acc / (float)(c + 1));
    }
    if (n < NP_) {
        out[(size_t)n * 64 + f] = r;
        out[(size_t)n * 64 + 32 + f] = 0;
    }
}

__global__ __launch_bounds__(256) void k_gprep2(const u16* __restrict__ h1b, const int* __restrict__ off,
                                                const int* __restrict__ cnt, const int* __restrict__ ebuf,
                                                u16* __restrict__ out) {
    int n = blockIdx.x * 4 + (threadIdx.x >> 6);
    int d2 = (threadIdx.x & 63) * 2;
    if (n >= NP_) return;
    u16 r0 = 0, r1 = 0;
    if (n < N_) {
        int start = off[n], c = cnt[n];
        float a0 = 0.f, a1 = 0.f;
        int i = 0;
        for (; i + 4 <= c; i += 4) {
            int s0 = ebuf[start + i], s1 = ebuf[start + i + 1];
            int s2 = ebuf[start + i + 2], s3 = ebuf[start + i + 3];
            ushort2 v0 = *(const ushort2*)&h1b[(size_t)s0 * D_ + d2];
            ushort2 v1 = *(const ushort2*)&h1b[(size_t)s1 * D_ + d2];
            ushort2 v2 = *(const ushort2*)&h1b[(size_t)s2 * D_ + d2];
            ushort2 v3 = *(const ushort2*)&h1b[(size_t)s3 * D_ + d2];
            a0 += (b2f(v0.x) + b2f(v1.x)) + (b2f(v2.x) + b2f(v3.x));
            a1 += (b2f(v0.y) + b2f(v1.y)) + (b2f(v2.y) + b2f(v3.y));
        }
        for (; i < c; ++i) {
            int s = ebuf[start + i];
            ushort2 v = *(const ushort2*)&h1b[(size_t)s * D_ + d2];
            a0 += b2f(v.x); a1 += b2f(v.y);
        }
        float rinv = 1.f / (float)(c + 1);
        ushort2 sv = *(const ushort2*)&h1b[(size_t)n * D_ + d2];
        r0 = f2b(b2f(sv.x) + a0 * rinv);
        r1 = f2b(b2f(sv.y) + a1 * rinv);
    }
    *(ushort2*)&out[(size_t)n * D_ + d2] = make_ushort2(r0, r1);
}

// ===================== MFMA GEMM (opt. fused LayerNorm / gathered A rows) =====================
template<int ACT, int OUTB, int RES, int LN, int GAT>
__global__ __launch_bounds__(256) void k_mgemm(const u16* __restrict__ A, const u16* __restrict__ BT,
                                               const float* __restrict__ bias, const float* __restrict__ resid,
                                               void* __restrict__ Cout,
                                               const float* __restrict__ g, const float* __restrict__ be,
                                               u16* __restrict__ xbout, const int* __restrict__ endi,
                                               int M, int N, int K) {
    constexpr int SMEMB = LN ? (128 * 133 * 4) : (128 * 64 * 4);
    __shared__ __align__(16) char smem[SMEMB];
    u16* Al = (u16*)smem;
    u16* Bl = Al + 128 * 64;
    int tid = threadIdx.x;
    int wid = tid >> 6, lane = tid & 63;
    int row0 = blockIdx.x * 128;
    int col0 = blockIdx.y * 128;
    int wr = wid >> 1, wc = wid & 1;
    f32x4 acc[4][4] = {};
    int srow = wid * 32 + (lane >> 3);
    int ks8 = ((lane & 7) ^ (lane >> 3)) * 8;

    for (int k0 = 0; k0 < K; k0 += 64) {
        if (k0) __syncthreads();
#pragma unroll
        for (int i = 0; i < 4; ++i) {
            int row = srow + i * 8;
            size_t arow = (size_t)(row0 + row);
            if (GAT) {
                int bb2 = row0 + row;
                arow = (bb2 < B_) ? ((size_t)bb2 * S_ + endi[bb2]) : 0;
            }
            gload16(A + arow * K + k0 + ks8, &Al[(wid * 32 + i * 8) * 64]);
            gload16(BT + (size_t)(col0 + row) * K + k0 + ks8, &Bl[(wid * 32 + i * 8) * 64]);
        }
        __syncthreads();
        int rA = lane & 15, kq = lane >> 4;
#pragma unroll
        for (int ks = 0; ks < 2; ++ks) {
            int sw = ((ks * 4 + kq) ^ (rA & 7)) * 8;
            short8 af[4], bfr[4];
#pragma unroll
            for (int m = 0; m < 4; ++m)
                af[m] = *(const short8*)&Al[(64 * wr + m * 16 + rA) * 64 + sw];
#pragma unroll
            for (int n = 0; n < 4; ++n)
                bfr[n] = *(const short8*)&Bl[(64 * wc + n * 16 + rA) * 64 + sw];
#pragma unroll
            for (int m = 0; m < 4; ++m)
#pragma unroll
                for (int n = 0; n < 4; ++n)
                    acc[m][n] = __builtin_amdgcn_mfma_f32_16x16x32_bf16(af[m], bfr[n], acc[m][n], 0, 0, 0);
        }
    }
    int rA = lane & 15, kq = lane >> 4;
    if (LN) {
        float* vbuf = (float*)smem;
        __syncthreads();
#pragma unroll
        for (int m = 0; m < 4; ++m) {
#pragma unroll
            for (int n = 0; n < 4; ++n) {
                int cc = 64 * wc + n * 16 + rA;
                float bv = bias[cc];
#pragma unroll
                for (int r = 0; r < 4; ++r) {
                    int rl = 64 * wr + m * 16 + kq * 4 + r;
                    float v = acc[m][n][r] + bv + resid[(size_t)(row0 + rl) * 128 + cc];
                    vbuf[rl * 133 + cc] = v;
                }
            }
        }
        __syncthreads();
        int rl = tid >> 1, half = tid & 1;
        const float* vrow = vbuf + rl * 133 + half * 64;
        float4 vv[16];
        float s = 0.f, s2 = 0.f;
#pragma unroll
        for (int j = 0; j < 16; ++j) {
            vv[j] = *(const float4*)(vrow + j * 4);
            s += (vv[j].x + vv[j].y) + (vv[j].z + vv[j].w);
            s2 += (vv[j].x * vv[j].x + vv[j].y * vv[j].y) + (vv[j].z * vv[j].z + vv[j].w * vv[j].w);
        }
        s += __shfl_xor(s, 1, 64);
        s2 += __shfl_xor(s2, 1, 64);
        float mean = s * (1.f / 128.f);
        float var = s2 * (1.f / 128.f) - mean * mean;
        float rs = rsqrtf(var + 1e-5f);
        int grow = row0 + rl;
        float* xrow = (float*)Cout + (size_t)grow * 128 + half * 64;
        u16* xbrow = xbout + (size_t)grow * 128 + half * 64;
#pragma unroll
        for (int j = 0; j < 16; ++j) {
            float4 gv = *(const float4*)(g + half * 64 + j * 4);
            float4 bv = *(const float4*)(be + half * 64 + j * 4);
            float o0 = (vv[j].x - mean) * rs * gv.x + bv.x;
            float o1 = (vv[j].y - mean) * rs * gv.y + bv.y;
            float o2 = (vv[j].z - mean) * rs * gv.z + bv.z;
            float o3 = (vv[j].w - mean) * rs * gv.w + bv.w;
            *(float4*)(xrow + j * 4) = make_float4(o0, o1, o2, o3);
            *(ushort4*)(xbrow + j * 4) = make_ushort4(f2b(o0), f2b(o1), f2b(o2), f2b(o3));
        }
    } else {
#pragma unroll
        for (int m = 0; m < 4; ++m) {
#pragma unroll
            for (int n = 0; n < 4; ++n) {
                int cc = col0 + 64 * wc + n * 16 + rA;
                if (cc >= N) continue;
                float bv = bias[cc];
#pragma unroll
                for (int r = 0; r < 4; ++r) {
                    int cr = row0 + 64 * wr + m * 16 + kq * 4 + r;
                    if (cr >= M) continue;
                    float v = acc[m][n][r] + bv;
                    if (RES) v += resid[(size_t)cr * N + cc];
                    if (ACT) v = fmaxf(v, 0.f);
                    if (OUTB) ((u16*)Cout)[(size_t)cr * N + cc] = f2b(v);
                    else      ((float*)Cout)[(size_t)cr * N + cc] = v;
                }
            }
        }
    }
}

// ===================== fused FFN: x' = LN(x + relu(xb@W1+b1)@W2 + b2) =====================
// block = 32 rows, 256 threads / 4 waves; grid = M/32 = 256
__global__ __launch_bounds__(256) void k_ffn(const u16* __restrict__ xbin,
                                             const u16* __restrict__ w1T, const float* __restrict__ b1,
                                             const u16* __restrict__ w2T, const float* __restrict__ b2,
                                             const float* __restrict__ g, const float* __restrict__ be,
                                             float* __restrict__ x, u16* __restrict__ xbout) {
    __shared__ __align__(16) char smem[73728];
    u16* Alds = (u16*)smem;                 // [32][128]  8KB
    u16* Wlds = (u16*)(smem + 8192);        // [256][64] 32KB (reused for W2 [128][64])
    u16* f1   = (u16*)(smem + 40960);       // [32][512] 32KB (swizzled)
    float* vbuf = (float*)smem;             // 17KB overlay in epilogue
    int tid = threadIdx.x, wid = tid >> 6, lane = tid & 63;
    int rows0 = blockIdx.x * 32;
    int rA = lane & 15, kq = lane >> 4;

    // stage A (32x128, swizzled source, linear dest)
#pragma unroll
    for (int j = 0; j < 2; ++j) {
        int row = wid * 8 + j * 4 + (lane >> 4);
        int win = (lane >> 3) & 1, slot = lane & 7;
        gload16(xbin + (size_t)(rows0 + row) * 128 + win * 64 + ((slot ^ (row & 7)) << 3),
                Alds + (wid * 8 + j * 4) * 128);
    }

    // ---------- phase 1: f1 = relu(A @ W1 + b1), two N-halves of 256 ----------
    for (int nh = 0; nh < 2; ++nh) {
        f32x4 acc1[2][4] = {};
        for (int k0 = 0; k0 < 128; k0 += 64) {
            __syncthreads();
#pragma unroll
            for (int i = 0; i < 8; ++i) {
                int rl2 = i * 32 + wid * 8 + (lane >> 3);
                gload16(w1T + (size_t)(nh * 256 + rl2) * 128 + k0 + (((lane & 7) ^ (rl2 & 7)) << 3),
                        Wlds + (i * 32 + wid * 8) * 64);
            }
            __syncthreads();
#pragma unroll
            for (int ks = 0; ks < 2; ++ks) {
                int sw = ((ks * 4 + kq) ^ (rA & 7)) << 3;
                short8 af[2], bf4[4];
                af[0] = *(const short8*)&Alds[rA * 128 + k0 + sw];
                af[1] = *(const short8*)&Alds[(16 + rA) * 128 + k0 + sw];
#pragma unroll
                for (int n = 0; n < 4; ++n)
                    bf4[n] = *(const short8*)&Wlds[(wid * 64 + n * 16 + rA) * 64 + sw];
#pragma unroll
                for (int m = 0; m < 2; ++m)
#pragma unroll
                    for (int n = 0; n < 4; ++n)
                        acc1[m][n] = __builtin_amdgcn_mfma_f32_16x16x32_bf16(af[m], bf4[n], acc1[m][n], 0, 0, 0);
            }
        }
        // epilogue -> f1 (swizzled)
#pragma unroll
        for (int m = 0; m < 2; ++m)
#pragma unroll
            for (int n = 0; n < 4; ++n) {
                int cc = nh * 256 + wid * 64 + n * 16 + rA;
                float bv = b1[cc];
#pragma unroll
                for (int r = 0; r < 4; ++r) {
                    int rl = m * 16 + kq * 4 + r;
                    float v = fmaxf(acc1[m][n][r] + bv, 0.f);
                    int scol = (cc & ~63) | (((((cc >> 3) & 7) ^ (rl & 7)) & 7) << 3) | (cc & 7);
                    f1[rl * 512 + scol] = f2b(v);
                }
            }
    }
    __syncthreads();   // f1 complete; Wlds free

    // ---------- phase 2: acc2 = f1 @ W2 ----------
    f32x4 acc2[2][2] = {};
    for (int k0 = 0; k0 < 512; k0 += 64) {
        if (k0) __syncthreads();
#pragma unroll
        for (int i = 0; i < 4; ++i) {
            int rl2 = i * 32 + wid * 8 + (lane >> 3);
            gload16(w2T + (size_t)rl2 * 512 + k0 + (((lane & 7) ^ (rl2 & 7)) << 3),
                    Wlds + (i * 32 + wid * 8) * 64);
        }
        __syncthreads();
#pragma unroll
        for (int ks = 0; ks < 2; ++ks) {
            int sw = ((ks * 4 + kq) ^ (rA & 7)) << 3;
            short8 af0 = *(const short8*)&f1[rA * 512 + k0 + sw];
            short8 af1 = *(const short8*)&f1[(16 + rA) * 512 + k0 + sw];
            short8 bf0 = *(const short8*)&Wlds[(wid * 32 + rA) * 64 + sw];
            short8 bf1 = *(const short8*)&Wlds[(wid * 32 + 16 + rA) * 64 + sw];
            acc2[0][0] = __builtin_amdgcn_mfma_f32_16x16x32_bf16(af0, bf0, acc2[0][0], 0, 0, 0);
            acc2[0][1] = __builtin_amdgcn_mfma_f32_16x16x32_bf16(af0, bf1, acc2[0][1], 0, 0, 0);
            acc2[1][0] = __builtin_amdgcn_mfma_f32_16x16x32_bf16(af1, bf0, acc2[1][0], 0, 0, 0);
            acc2[1][1] = __builtin_amdgcn_mfma_f32_16x16x32_bf16(af1, bf1, acc2[1][1], 0, 0, 0);
        }
    }

    // ---------- epilogue: bias + resid + LN ----------
    __syncthreads();   // Alds/Wlds/f1 reads done; overlay vbuf
#pragma unroll
    for (int m = 0; m < 2; ++m)
#pragma unroll
        for (int n = 0; n < 2; ++n) {
            int cc = wid * 32 + n * 16 + rA;
            float bv = b2[cc];
#pragma unroll
            for (int r = 0; r < 4; ++r) {
                int rl = m * 16 + kq * 4 + r;
                float v = acc2[m][n][r] + bv + x[(size_t)(rows0 + rl) * 128 + cc];
                vbuf[rl * 133 + cc] = v;
            }
        }
    __syncthreads();
    int row = tid >> 3, sub = tid & 7;   // 8 threads per row, 16 cols each
    const float* vr = vbuf + row * 133 + sub * 16;
    float vv[16];
    float s = 0.f, s2 = 0.f;
#pragma unroll
    for (int j = 0; j < 16; ++j) {
        vv[j] = vr[j];
        s += vv[j];
        s2 += vv[j] * vv[j];
    }
    s += __shfl_xor(s, 1, 64);  s2 += __shfl_xor(s2, 1, 64);
    s += __shfl_xor(s, 2, 64);  s2 += __shfl_xor(s2, 2, 64);
    s += __shfl_xor(s, 4, 64);  s2 += __shfl_xor(s2, 4, 64);
    float mean = s * (1.f / 128.f);
    float var = s2 * (1.f / 128.f) - mean * mean;
    float rs = rsqrtf(var + 1e-5f);
    int grow = rows0 + row;
    float* xrow = x + (size_t)grow * 128 + sub * 16;
    u16* xbrow = xbout + (size_t)grow * 128 + sub * 16;
#pragma unroll
    for (int j = 0; j < 4; ++j) {
        float4 gv = *(const float4*)(g + sub * 16 + j * 4);
        float4 bv = *(const float4*)(be + sub * 16 + j * 4);
        float o0 = (vv[j * 4 + 0] - mean) * rs * gv.x + bv.x;
        float o1 = (vv[j * 4 + 1] - mean) * rs * gv.y + bv.y;
        float o2 = (vv[j * 4 + 2] - mean) * rs * gv.z + bv.z;
        float o3 = (vv[j * 4 + 3] - mean) * rs * gv.w + bv.w;
        *(float4*)(xrow + j * 4) = make_float4(o0, o1, o2, o3);
        *(ushort4*)(xbrow + j * 4) = make_ushort4(f2b(o0), f2b(o1), f2b(o2), f2b(o3));
    }
}

// ===================== fusion + positional encoding =====================
__global__ __launch_bounds__(256) void k_fusion(const float* __restrict__ spe, const int* __restrict__ traj,
                                                const float* __restrict__ ue_tab, const int* __restrict__ uid,
                                                const float* __restrict__ tempx, const int* __restrict__ hwx,
                                                const float* __restrict__ ce_tab, const float* __restrict__ flw,
                                                const float* __restrict__ flb, float* __restrict__ x,
                                                u16* __restrict__ xb) {
    __shared__ float Ws[22 * D_];
    __shared__ float bs[D_];
    __shared__ float ins[2][22];
    int tid = threadIdx.x;
    for (int i = tid; i < 22 * D_; i += 256) Ws[i] = flw[i];
    if (tid < D_) bs[tid] = flb[tid];
    __syncthreads();
    int ro = tid >> 7, d = tid & 127;
    int base = blockIdx.x * 32;
    for (int ir = 0; ir < 16; ++ir) {
        int tok = base + ir * 2 + ro;
        int b = tok >> 8, s = tok & 255;
        if (d < TD_) ins[ro][d] = tempx[(size_t)tok * TD_ + d];
        else if (d < 22) ins[ro][d] = ce_tab[(size_t)hwx[tok] * CED_ + (d - TD_)];
        __syncthreads();
        float acc = bs[d];
#pragma unroll
        for (int k = 0; k < 22; ++k) acc = fmaf(ins[ro][k], Ws[k * D_ + d], acc);
        acc = fmaxf(acc, 0.f);
        int i2 = d & ~1;
        float ang = (float)s * __expf(-(float)i2 * 0.0719557841560639f);
        float pe = (d & 1) ? cosf(ang) : sinf(ang);
        float v = spe[(size_t)traj[tok] * D_ + d] + ue_tab[(size_t)uid[b] * D_ + d] + acc + pe;
        x[(size_t)tok * D_ + d] = v;
        xb[(size_t)tok * D_ + d] = f2b(v);
        __syncthreads();
    }
}

// ===================== MFMA flash attention (fp16 bias) =====================
#define KLS 40
#define VTS 272
__global__ __launch_bounds__(256) void k_attn(const u16* __restrict__ qkv, const u16* __restrict__ bias,
                                              u16* __restrict__ o) {
    __shared__ u16 Kl[256 * KLS];
    __shared__ u16 Vt[16 * VTS];
    __shared__ u16 Pl[4 * 16 * VTS];
    int idx = blockIdx.x;
    int b = (idx & 7) * 8 + ((idx >> 3) >> 3);
    int h = (idx >> 3) & 7;
    int tid = threadIdx.x, wid = tid >> 6, lane = tid & 63;

    {
        const u16* kr = qkv + ((size_t)(b * S_ + tid)) * 384 + 128 + h * 16;
        short8 k0v = *(const short8*)kr;
        short8 k1v = *(const short8*)(kr + 8);
        short8 z = {};
        *(short8*)&Kl[tid * KLS + 0]  = k0v;
        *(short8*)&Kl[tid * KLS + 8]  = k1v;
        *(short8*)&Kl[tid * KLS + 16] = z;
        *(short8*)&Kl[tid * KLS + 24] = z;
        const u16* vr = qkv + ((size_t)(b * S_ + tid)) * 384 + 256 + h * 16;
        short8 v0 = *(const short8*)vr;
        short8 v1 = *(const short8*)(vr + 8);
#pragma unroll
        for (int d = 0; d < 8; ++d) Vt[d * VTS + tid] = (u16)v0[d];
#pragma unroll
        for (int d = 0; d < 8; ++d) Vt[(d + 8) * VTS + tid] = (u16)v1[d];
    }
    __syncthreads();

    u16* pl = Pl + wid * 16 * VTS;
    int qi = lane & 15, kq = lane >> 4;

    for (int qt = 0; qt < 4; ++qt) {
        int q0 = wid * 64 + qt * 16;
        int q = q0 + qi;
        ushort4 bb[16];
        const u16* bp = bias + (size_t)b * (S_ * S_) + (size_t)q * S_ + kq * 4;
#pragma unroll
        for (int t = 0; t < 16; ++t) bb[t] = *(const ushort4*)(bp + t * 16);
        short8 qf = {};
        if (lane < 32)
            qf = *(const short8*)(qkv + ((size_t)(b * S_ + q)) * 384 + h * 16 + kq * 8);
        f32x4 sc[16];
#pragma unroll
        for (int t = 0; t < 16; ++t) {
            short8 kf = *(const short8*)&Kl[(t * 16 + qi) * KLS + kq * 8];
            f32x4 zz = {0.f, 0.f, 0.f, 0.f};
            sc[t] = __builtin_amdgcn_mfma_f32_16x16x32_bf16(kf, qf, zz, 0, 0, 0);
        }
        float m = -1e30f;
#pragma unroll
        for (int t = 0; t < 16; ++t) {
            sc[t][0] = sc[t][0] * 0.25f + h2f(bb[t].x);
            sc[t][1] = sc[t][1] * 0.25f + h2f(bb[t].y);
            sc[t][2] = sc[t][2] * 0.25f + h2f(bb[t].z);
            sc[t][3] = sc[t][3] * 0.25f + h2f(bb[t].w);
            m = fmaxf(m, fmaxf(fmaxf(sc[t][0], sc[t][1]), fmaxf(sc[t][2], sc[t][3])));
        }
        m = fmaxf(m, __shfl_xor(m, 16, 64));
        m = fmaxf(m, __shfl_xor(m, 32, 64));
        float l = 0.f;
#pragma unroll
        for (int t = 0; t < 16; ++t) {
            sc[t][0] = __expf(sc[t][0] - m);
            sc[t][1] = __expf(sc[t][1] - m);
            sc[t][2] = __expf(sc[t][2] - m);
            sc[t][3] = __expf(sc[t][3] - m);
            l += (sc[t][0] + sc[t][1]) + (sc[t][2] + sc[t][3]);
        }
        l += __shfl_xor(l, 16, 64);
        l += __shfl_xor(l, 32, 64);
        float inv = 1.f / l;
#pragma unroll
        for (int t = 0; t < 16; ++t) {
            ushort4 pw = make_ushort4(f2b(sc[t][0] * inv), f2b(sc[t][1] * inv),
                                      f2b(sc[t][2] * inv), f2b(sc[t][3] * inv));
            *(ushort4*)&pl[qi * VTS + t * 16 + kq * 4] = pw;
        }
        f32x4 oa = {0.f, 0.f, 0.f, 0.f};
#pragma unroll
        for (int w8 = 0; w8 < 8; ++w8) {
            short8 vf = *(const short8*)&Vt[qi * VTS + w8 * 32 + kq * 8];
            short8 pf = *(const short8*)&pl[qi * VTS + w8 * 32 + kq * 8];
            oa = __builtin_amdgcn_mfma_f32_16x16x32_bf16(vf, pf, oa, 0, 0, 0);
        }
        ushort4 ow = make_ushort4(f2b(oa[0]), f2b(oa[1]), f2b(oa[2]), f2b(oa[3]));
        *(ushort4*)&o[((size_t)(b * S_ + q)) * D_ + h * 16 + kq * 4] = ow;
    }
}

// ===================== launch =====================
extern "C" void kernel_launch(void* const* d_in, const int* in_sizes, int n_in,
                              void* d_out, int out_size, void* d_ws, size_t ws_size,
                              hipStream_t stream) {
    const float* node_feature = (const float*)d_in[0];
    const int*   edge_index   = (const int*)d_in[1];
    const int*   traj_x       = (const int*)d_in[2];
    const float* temporal_x   = (const float*)d_in[3];
    const int*   user_id_x    = (const int*)d_in[4];
    const int*   mask         = (const int*)d_in[5];
    const int*   end_idx      = (const int*)d_in[6];
    const float* tmat         = (const float*)d_in[8];
    const float* dmat         = (const float*)d_in[9];
    const int*   highway_x    = (const int*)d_in[10];
    const float* lambda2      = (const float*)d_in[11];
    const float* gnn_w1       = (const float*)d_in[12];
    const float* gnn_b1       = (const float*)d_in[13];
    const float* gnn_w2       = (const float*)d_in[14];
    const float* gnn_b2       = (const float*)d_in[15];
    const float* ue_tab       = (const float*)d_in[16];
    const float* ce_tab       = (const float*)d_in[17];
    const float* fl_w         = (const float*)d_in[18];
    const float* fl_b         = (const float*)d_in[19];
    const float* wqkv         = (const float*)d_in[20];
    const float* bqkv         = (const float*)d_in[21];
    const float* wo           = (const float*)d_in[22];
    const float* bo           = (const float*)d_in[23];
    const float* ln1_g        = (const float*)d_in[24];
    const float* ln1_b        = (const float*)d_in[25];
    const float* ln2_g        = (const float*)d_in[26];
    const float* ln2_b        = (const float*)d_in[27];
    const float* ffn_w1       = (const float*)d_in[28];
    const float* ffn_b1       = (const float*)d_in[29];
    const float* ffn_w2       = (const float*)d_in[30];
    const float* ffn_b2       = (const float*)d_in[31];
    const float* head_w       = (const float*)d_in[32];
    const float* head_b       = (const float*)d_in[33];
    float* out = (float*)d_out;

    // ---- workspace layout (float units) ----
    float* w     = (float*)d_ws;
    int*   cnt   = (int*)w;                  // [0, 40,960)
    float* spe   = w + 40960;                // [40,960, 5,169,152)
    u16*   biasb = (u16*)(w + 5169152);      // [5,169,152, 7,266,304)
    float* wreg  = w + 7266304;              // bf16 weights -> ends 7,999,488
    u16* wqkvT = (u16*)wreg;
    u16* woT   = wqkvT + 4 * 384 * 128;
    u16* w1T   = woT + 4 * 128 * 128;
    u16* w2T   = w1T + 4 * 512 * 128;
    u16* gw1T  = w2T + 4 * 128 * 512;
    u16* gw2T  = gw1T + 128 * 64;
    u16* hwT   = gw2T + 128 * 128;
    float* pool  = w + 8000000;
    // GNN phase
    u16*   h1b   = (u16*)pool;               // [0, 2,564,096) f
    u16*   in1b  = (u16*)(pool + 2564096);   // [2,564,096, 3,846,144)
    u16*   in2b  = (u16*)(pool + 3846144);   // [3,846,144, 6,410,240)
    int*   off   = (int*)(pool + 6410240);
    int*   cursor= (int*)(pool + 6450304);
    int*   ebuf  = (int*)(pool + 6490368);
    int*   part  = (int*)(pool + 6650368);
    // transformer phase
    float* x     = pool;                     // [0, 2,097,152)
    u16*   xb    = (u16*)(pool + 2097152);
    u16*   qkvb  = (u16*)(pool + 3145728);
    u16*   attob = (u16*)(pool + 4718592);

    const int* esrc = edge_index;
    const int* edst = edge_index + E_;

    // ---- uber prep: cnt-zero + all weight cvtT + attn bias ----
    UberArgs ua;
    const float* srcs[7] = {wqkv, wo, ffn_w1, ffn_w2, gnn_w1, gnn_w2, head_w};
    u16* dsts[7]        = {wqkvT, woT, w1T, w2T, gw1T, gw2T, hwT};
    int Ks[7]    = {128, 128, 128, 512, 32, 128, 128};
    int Npads[7] = {384, 128, 512, 128, 128, 128, UP_};
    int Nsrcs[7] = {384, 128, 512, 128, 128, 128, U_};
    int Kps[7]   = {128, 128, 128, 512, 64, 128, 128};
    int Ls[7]    = {4, 4, 4, 4, 1, 1, 1};
    int bb = UB_CNT_END;
    for (int t = 0; t < 7; ++t) {
        ua.csrc[t] = srcs[t]; ua.cdst[t] = dsts[t];
        ua.K[t] = Ks[t]; ua.Npad[t] = Npads[t]; ua.Nsrc[t] = Nsrcs[t]; ua.Kp[t] = Kps[t];
        ua.base[t] = bb;
        bb += (Npads[t] / 32) * (Kps[t] / 32) * Ls[t];
    }
    ua.tm = tmat; ua.dm = dmat; ua.maskp = mask; ua.lambda2 = lambda2;
    ua.bias = biasb; ua.cnt = cnt;
    k_uber<<<UB_TOTAL, 256, 0, stream>>>(ua);

    // ---- GNN: CSR build + gather ----
    k_count<<<(E_ + 255) / 256, 256, 0, stream>>>(edst, cnt);
    k_scanA<<<NSCB, 256, 0, stream>>>(cnt, part);
    k_scanB<<<NSCB, 256, 0, stream>>>(cnt, part, off, cursor);
    k_fill<<<(E_ + 255) / 256, 256, 0, stream>>>(esrc, edst, cursor, ebuf);
    k_gprep1<<<NP_ / 8, 256, 0, stream>>>(node_feature, off, cnt, ebuf, in1b);
    k_mgemm<1, 1, 0, 0, 0><<<dim3(NP_ / 128, 1), 256, 0, stream>>>(in1b, gw1T, gnn_b1, nullptr, h1b,
                                                                   nullptr, nullptr, nullptr, nullptr, NP_, D_, 64);
    k_gprep2<<<NP_ / 4, 256, 0, stream>>>(h1b, off, cnt, ebuf, in2b);
    k_mgemm<1, 0, 0, 0, 0><<<dim3(NP_ / 128, 1), 256, 0, stream>>>(in2b, gw2T, gnn_b2, nullptr, spe,
                                                                   nullptr, nullptr, nullptr, nullptr, NP_, D_, D_);

    // ---- fusion ----
    k_fusion<<<(B_ * S_) / 32, 256, 0, stream>>>(spe, traj_x, ue_tab, user_id_x,
                                                 temporal_x, highway_x, ce_tab, fl_w, fl_b, x, xb);

    // ---- transformer ----
    const int M = B_ * S_;
    for (int l = 0; l < L_; ++l) {
        k_mgemm<0, 1, 0, 0, 0><<<dim3(M / 128, 3), 256, 0, stream>>>(xb, wqkvT + (size_t)l * 384 * 128,
                                                                     bqkv + l * 384, nullptr, qkvb,
                                                                     nullptr, nullptr, nullptr, nullptr, M, 384, D_);
        k_attn<<<B_ * H_, 256, 0, stream>>>(qkvb, biasb, attob);
        k_mgemm<0, 0, 1, 1, 0><<<dim3(M / 128, 1), 256, 0, stream>>>(attob, woT + (size_t)l * 128 * 128,
                                                                     bo + l * D_, x, x,
                                                                     ln1_g + l * D_, ln1_b + l * D_, xb, nullptr, M, D_, D_);
        k_ffn<<<M / 32, 256, 0, stream>>>(xb, w1T + (size_t)l * 512 * 128, ffn_b1 + l * FF_,
                                          w2T + (size_t)l * 128 * 512, ffn_b2 + l * D_,
                                          ln2_g + l * D_, ln2_b + l * D_, x, xb);
    }

    // ---- head (gather fused via GAT) ----
    k_mgemm<0, 0, 0, 0, 1><<<dim3(1, UP_ / 128), 256, 0, stream>>>(xb, hwT, head_b, nullptr, out,
                                                                   nullptr, nullptr, nullptr, end_idx, B_, U_, D_);
}

// Round 9
// 350.344 us; speedup vs baseline: 3.4380x; 1.2065x over previous
//
#include <hip/hip_runtime.h>
#include <hip/hip_fp16.h>
#include <cstdint>
#include <cstddef>

typedef unsigned short u16;
typedef __attribute__((ext_vector_type(8))) short short8;
typedef __attribute__((ext_vector_type(4))) float f32x4;

// ---- problem constants ----
#define B_   64
#define S_   256
#define D_   128
#define H_   8
#define DH_  16
#define FF_  512
#define L_   4
#define U_   5000
#define UP_  5120
#define N_   40000
#define NP_  40064
#define E_   160000
#define FEA_ 32
#define HWY_ 16
#define CED_ 16
#define TD_  6
#define NSCB 157
// uber kernel block ranges
#define UB_CNT_END 160
#define UB_CVT_END 1592
#define UB_TOTAL   5688

static __device__ __forceinline__ u16 f2b(float f) {
    unsigned int u = __float_as_uint(f);
    unsigned int r = (u + 0x7FFFu + ((u >> 16) & 1u)) >> 16;
    return (u16)r;
}
static __device__ __forceinline__ float b2f(u16 u) {
    return __uint_as_float(((unsigned int)u) << 16);
}
static __device__ __forceinline__ u16 f2h(float f) {
    return __half_as_ushort(__float2half(f));
}
static __device__ __forceinline__ float h2f(u16 u) {
    return __half2float(__ushort_as_half(u));
}

static __device__ __forceinline__ void gload16(const void* g, void* l) {
    __builtin_amdgcn_global_load_lds(
        (const __attribute__((address_space(1))) unsigned int*)g,
        (__attribute__((address_space(3))) unsigned int*)l,
        16, 0, 0);
}

// ===================== uber prep: cnt-zero + 7 weight transposes + attn bias =====================
struct UberArgs {
    const float* csrc[7];
    u16* cdst[7];
    int K[7], Npad[7], Nsrc[7], Kp[7], base[7];
    const float* tm; const float* dm; const int* maskp; const float* lambda2;
    u16* bias; int* cnt;
};

__global__ __launch_bounds__(256) void k_uber(UberArgs a) {
    __shared__ float tile[32][33];
    int bid = blockIdx.x, tid = threadIdx.x;
    if (bid < UB_CNT_END) {
        int idx = bid * 256 + tid;
        if (idx < NP_) a.cnt[idx] = 0;
        return;
    }
    if (bid < UB_CVT_END) {
        int t = 0;
#pragma unroll
        for (int i = 1; i < 7; ++i) t += (bid >= a.base[i]);
        int rb = bid - a.base[t];
        int K = a.K[t], Npad = a.Npad[t], Nsrc = a.Nsrc[t], Kp = a.Kp[t];
        int nbn = Npad >> 5, nbk = Kp >> 5;
        int per = nbn * nbk;
        int l = rb / per, rem = rb - l * per;
        int n0 = (rem % nbn) * 32, k0 = (rem / nbn) * 32;
        const float* in = a.csrc[t];
        u16* outp = a.cdst[t];
        int j = tid & 31, i2 = tid >> 5;
#pragma unroll
        for (int r = 0; r < 4; ++r) {
            int k = k0 + i2 + r * 8, n = n0 + j;
            tile[i2 + r * 8][j] = (k < K && n < Nsrc) ? in[(size_t)l * K * Nsrc + (size_t)k * Nsrc + n] : 0.f;
        }
        __syncthreads();
#pragma unroll
        for (int r = 0; r < 4; ++r) {
            int n = n0 + i2 + r * 8, k = k0 + j;
            if (n < Npad && k < Kp)
                outp[(size_t)l * Npad * Kp + (size_t)n * Kp + k] = f2b(tile[j][i2 + r * 8]);
        }
        return;
    }
    int t4 = (bid - UB_CVT_END) * 256 + tid;
    const int total = B_ * S_ * S_ / 4;
    if (t4 >= total) return;
    float l2 = *a.lambda2, l2c = 1.f - l2;
    float4 av = ((const float4*)a.tm)[t4];
    float4 bv = ((const float4*)a.dm)[t4];
    int basei = t4 * 4;
    int bb = basei >> 16;
    int k0 = basei & 255;
    const int* mrow = a.maskp + bb * S_;
    float r0 = (mrow[k0 + 0] > 0 ? 0.f : -30000.f) - (l2 * __logf(1.f + av.x) + l2c * __logf(1.f + bv.x));
    float r1 = (mrow[k0 + 1] > 0 ? 0.f : -30000.f) - (l2 * __logf(1.f + av.y) + l2c * __logf(1.f + bv.y));
    float r2 = (mrow[k0 + 2] > 0 ? 0.f : -30000.f) - (l2 * __logf(1.f + av.z) + l2c * __logf(1.f + bv.z));
    float r3 = (mrow[k0 + 3] > 0 ? 0.f : -30000.f) - (l2 * __logf(1.f + av.w) + l2c * __logf(1.f + bv.w));
    *(ushort4*)&a.bias[(size_t)t4 * 4] = make_ushort4(f2h(r0), f2h(r1), f2h(r2), f2h(r3));
}

// ===================== CSR build =====================
__global__ __launch_bounds__(256) void k_count(const int* __restrict__ dst, int* __restrict__ cnt) {
    int e = blockIdx.x * 256 + threadIdx.x;
    if (e < E_) atomicAdd(&cnt[dst[e]], 1);
}

__global__ __launch_bounds__(256) void k_scanA(const int* __restrict__ cnt, int* __restrict__ part) {
    __shared__ int sh[256];
    int idx = blockIdx.x * 256 + threadIdx.x;
    sh[threadIdx.x] = (idx < NP_) ? cnt[idx] : 0;
    __syncthreads();
    for (int o = 128; o > 0; o >>= 1) {
        if (threadIdx.x < o) sh[threadIdx.x] += sh[threadIdx.x + o];
        __syncthreads();
    }
    if (threadIdx.x == 0) part[blockIdx.x] = sh[0];
}

__global__ __launch_bounds__(256) void k_scanB(const int* __restrict__ cnt, const int* __restrict__ part,
                                               int* __restrict__ off, int* __restrict__ cursor) {
    __shared__ int sh[256];
    __shared__ int bsum;
    int tid = threadIdx.x;
    int pv = (tid < blockIdx.x) ? part[tid] : 0;
    sh[tid] = pv;
    __syncthreads();
    for (int o = 128; o > 0; o >>= 1) {
        if (tid < o) sh[tid] += sh[tid + o];
        __syncthreads();
    }
    if (tid == 0) bsum = sh[0];
    __syncthreads();
    int basev = bsum;
    __syncthreads();
    int idx = blockIdx.x * 256 + tid;
    int v = (idx < NP_) ? cnt[idx] : 0;
    sh[tid] = v;
    __syncthreads();
    for (int o = 1; o < 256; o <<= 1) {
        int t2 = (tid >= o) ? sh[tid - o] : 0;
        __syncthreads();
        sh[tid] += t2;
        __syncthreads();
    }
    if (idx < NP_) {
        int res = sh[tid] - v + basev;
        off[idx] = res;
        cursor[idx] = res;
    }
}

__global__ __launch_bounds__(256) void k_fill(const int* __restrict__ src, const int* __restrict__ dst,
                                              int* __restrict__ cursor, int* __restrict__ ebuf) {
    int e = blockIdx.x * 256 + threadIdx.x;
    if (e >= E_) return;
    int p = atomicAdd(&cursor[dst[e]], 1);
    ebuf[p] = src[e];
}

// ===================== GNN gather+prep =====================
__global__ __launch_bounds__(256) void k_gprep1(const float* __restrict__ nf, const int* __restrict__ off,
                                                const int* __restrict__ cnt, const int* __restrict__ ebuf,
                                                u16* __restrict__ out) {
    int n = blockIdx.x * 8 + (threadIdx.x >> 5);
    int f = threadIdx.x & 31;
    u16 r = 0;
    if (n < N_) {
        int start = off[n], c = cnt[n];
        float acc = 0.f;
        int i = 0;
        for (; i + 4 <= c; i += 4) {
            int s0 = ebuf[start + i], s1 = ebuf[start + i + 1];
            int s2 = ebuf[start + i + 2], s3 = ebuf[start + i + 3];
            float v0 = nf[(size_t)s0 * FEA_ + f];
            float v1 = nf[(size_t)s1 * FEA_ + f];
            float v2 = nf[(size_t)s2 * FEA_ + f];
            float v3 = nf[(size_t)s3 * FEA_ + f];
            acc += (v0 + v1) + (v2 + v3);
        }
        for (; i < c; ++i) {
            int s = ebuf[start + i];
            acc += nf[(size_t)s * FEA_ + f];
        }
        r = f2b(nf[(size_t)n * FEA_ + f] + acc / (float)(c + 1));
    }
    if (n < NP_) {
        out[(size_t)n * 64 + f] = r;
        out[(size_t)n * 64 + 32 + f] = 0;
    }
}

__global__ __launch_bounds__(256) void k_gprep2(const u16* __restrict__ h1b, const int* __restrict__ off,
                                                const int* __restrict__ cnt, const int* __restrict__ ebuf,
                                                u16* __restrict__ out) {
    int n = blockIdx.x * 4 + (threadIdx.x >> 6);
    int d2 = (threadIdx.x & 63) * 2;
    if (n >= NP_) return;
    u16 r0 = 0, r1 = 0;
    if (n < N_) {
        int start = off[n], c = cnt[n];
        float a0 = 0.f, a1 = 0.f;
        int i = 0;
        for (; i + 4 <= c; i += 4) {
            int s0 = ebuf[start + i], s1 = ebuf[start + i + 1];
            int s2 = ebuf[start + i + 2], s3 = ebuf[start + i + 3];
            ushort2 v0 = *(const ushort2*)&h1b[(size_t)s0 * D_ + d2];
            ushort2 v1 = *(const ushort2*)&h1b[(size_t)s1 * D_ + d2];
            ushort2 v2 = *(const ushort2*)&h1b[(size_t)s2 * D_ + d2];
            ushort2 v3 = *(const ushort2*)&h1b[(size_t)s3 * D_ + d2];
            a0 += (b2f(v0.x) + b2f(v1.x)) + (b2f(v2.x) + b2f(v3.x));
            a1 += (b2f(v0.y) + b2f(v1.y)) + (b2f(v2.y) + b2f(v3.y));
        }
        for (; i < c; ++i) {
            int s = ebuf[start + i];
            ushort2 v = *(const ushort2*)&h1b[(size_t)s * D_ + d2];
            a0 += b2f(v.x); a1 += b2f(v.y);
        }
        float rinv = 1.f / (float)(c + 1);
        ushort2 sv = *(const ushort2*)&h1b[(size_t)n * D_ + d2];
        r0 = f2b(b2f(sv.x) + a0 * rinv);
        r1 = f2b(b2f(sv.y) + a1 * rinv);
    }
    *(ushort2*)&out[(size_t)n * D_ + d2] = make_ushort2(r0, r1);
}

// ===================== MFMA GEMM (BM 64/128, opt LN / gathered A) =====================
template<int BM, int ACT, int OUTB, int RES, int LN, int GAT>
__global__ __launch_bounds__(256) void k_mgemm(const u16* __restrict__ A, const u16* __restrict__ BT,
                                               const float* __restrict__ bias, const float* __restrict__ resid,
                                               void* __restrict__ Cout,
                                               const float* __restrict__ g, const float* __restrict__ be,
                                               u16* __restrict__ xbout, const int* __restrict__ endi,
                                               int M, int N, int K) {
    constexpr int SMEMB = (BM == 128) ? (LN ? 128 * 133 * 4 : 32768)
                                      : (LN ? 64 * 133 * 4 : 24576);
    __shared__ __align__(16) char smem[SMEMB];
    u16* Al = (u16*)smem;
    u16* Bl = Al + (BM == 128 ? 128 * 64 : 64 * 64);
    int tid = threadIdx.x;
    int wid = tid >> 6, lane = tid & 63;
    int row0 = blockIdx.x * BM;
    int col0 = blockIdx.y * 128;
    f32x4 acc[4][4] = {};
    int rA = lane & 15, kq = lane >> 4;

    for (int k0 = 0; k0 < K; k0 += 64) {
        if (k0) __syncthreads();
        if (BM == 128) {
            int srow = wid * 32 + (lane >> 3);
            int ks8 = ((lane & 7) ^ (lane >> 3)) * 8;
#pragma unroll
            for (int i = 0; i < 4; ++i) {
                int row = srow + i * 8;
                size_t arow = (size_t)(row0 + row);
                if (GAT) {
                    int bb2 = row0 + row;
                    arow = (bb2 < B_) ? ((size_t)bb2 * S_ + endi[bb2]) : 0;
                }
                gload16(A + arow * K + k0 + ks8, &Al[(wid * 32 + i * 8) * 64]);
                gload16(BT + (size_t)(col0 + row) * K + k0 + ks8, &Bl[(wid * 32 + i * 8) * 64]);
            }
        } else {
#pragma unroll
            for (int i = 0; i < 6; ++i) {
                int c = wid * 6 + i;
                int rr = c * 8 + (lane >> 3);          // 0..191
                int sl = (((lane & 7) ^ (rr & 7)) << 3);
                if (c < 8) {
                    size_t arow = (size_t)(row0 + rr);
                    if (GAT) {
                        int bb2 = row0 + rr;
                        arow = (bb2 < B_) ? ((size_t)bb2 * S_ + endi[bb2]) : 0;
                    }
                    gload16(A + arow * K + k0 + sl, &Al[rr * 64]);
                } else {
                    gload16(BT + (size_t)(col0 + rr - 64) * K + k0 + sl, &Bl[(rr - 64) * 64]);
                }
            }
        }
        __syncthreads();
#pragma unroll
        for (int ks = 0; ks < 2; ++ks) {
            int sw = ((ks * 4 + kq) ^ (rA & 7)) * 8;
            if (BM == 128) {
                int wr = wid >> 1, wc = wid & 1;
                short8 af[4], bfr[4];
#pragma unroll
                for (int m = 0; m < 4; ++m)
                    af[m] = *(const short8*)&Al[(64 * wr + m * 16 + rA) * 64 + sw];
#pragma unroll
                for (int n = 0; n < 4; ++n)
                    bfr[n] = *(const short8*)&Bl[(64 * wc + n * 16 + rA) * 64 + sw];
#pragma unroll
                for (int m = 0; m < 4; ++m)
#pragma unroll
                    for (int n = 0; n < 4; ++n)
                        acc[m][n] = __builtin_amdgcn_mfma_f32_16x16x32_bf16(af[m], bfr[n], acc[m][n], 0, 0, 0);
            } else {
                int wr2 = wid & 1, wc2 = wid >> 1;
                short8 af[2], bfr[4];
#pragma unroll
                for (int m = 0; m < 2; ++m)
                    af[m] = *(const short8*)&Al[(wr2 * 32 + m * 16 + rA) * 64 + sw];
#pragma unroll
                for (int n = 0; n < 4; ++n)
                    bfr[n] = *(const short8*)&Bl[(wc2 * 64 + n * 16 + rA) * 64 + sw];
#pragma unroll
                for (int m = 0; m < 2; ++m)
#pragma unroll
                    for (int n = 0; n < 4; ++n)
                        acc[m][n] = __builtin_amdgcn_mfma_f32_16x16x32_bf16(af[m], bfr[n], acc[m][n], 0, 0, 0);
            }
        }
    }

    if (LN) {
        float* vbuf = (float*)smem;
        __syncthreads();
        constexpr int MR = (BM == 128) ? 4 : 2;
#pragma unroll
        for (int m = 0; m < MR; ++m) {
#pragma unroll
            for (int n = 0; n < 4; ++n) {
                int cc, rl0;
                if (BM == 128) { cc = (wid & 1) * 64 + n * 16 + rA; rl0 = (wid >> 1) * 64 + m * 16 + kq * 4; }
                else           { cc = (wid >> 1) * 64 + n * 16 + rA; rl0 = (wid & 1) * 32 + m * 16 + kq * 4; }
                float bv = bias[cc];
#pragma unroll
                for (int r = 0; r < 4; ++r) {
                    int rl = rl0 + r;
                    float v = acc[m][n][r] + bv + resid[(size_t)(row0 + rl) * 128 + cc];
                    vbuf[rl * 133 + cc] = v;
                }
            }
        }
        __syncthreads();
        if (BM == 128) {
            int rl = tid >> 1, half = tid & 1;
            const float* vrow = vbuf + rl * 133 + half * 64;
            float4 vv[16];
            float s = 0.f, s2 = 0.f;
#pragma unroll
            for (int j = 0; j < 16; ++j) {
                vv[j] = *(const float4*)(vrow + j * 4);
                s += (vv[j].x + vv[j].y) + (vv[j].z + vv[j].w);
                s2 += (vv[j].x * vv[j].x + vv[j].y * vv[j].y) + (vv[j].z * vv[j].z + vv[j].w * vv[j].w);
            }
            s += __shfl_xor(s, 1, 64);
            s2 += __shfl_xor(s2, 1, 64);
            float mean = s * (1.f / 128.f);
            float var = s2 * (1.f / 128.f) - mean * mean;
            float rs = rsqrtf(var + 1e-5f);
            int grow = row0 + rl;
            float* xrow = (float*)Cout + (size_t)grow * 128 + half * 64;
            u16* xbrow = xbout + (size_t)grow * 128 + half * 64;
#pragma unroll
            for (int j = 0; j < 16; ++j) {
                float4 gv = *(const float4*)(g + half * 64 + j * 4);
                float4 bv = *(const float4*)(be + half * 64 + j * 4);
                float o0 = (vv[j].x - mean) * rs * gv.x + bv.x;
                float o1 = (vv[j].y - mean) * rs * gv.y + bv.y;
                float o2 = (vv[j].z - mean) * rs * gv.z + bv.z;
                float o3 = (vv[j].w - mean) * rs * gv.w + bv.w;
                *(float4*)(xrow + j * 4) = make_float4(o0, o1, o2, o3);
                *(ushort4*)(xbrow + j * 4) = make_ushort4(f2b(o0), f2b(o1), f2b(o2), f2b(o3));
            }
        } else {
            int rl = tid >> 2, q4 = tid & 3;
            const float* vrow = vbuf + rl * 133 + q4 * 32;
            float4 vv[8];
            float s = 0.f, s2 = 0.f;
#pragma unroll
            for (int j = 0; j < 8; ++j) {
                vv[j] = *(const float4*)(vrow + j * 4);
                s += (vv[j].x + vv[j].y) + (vv[j].z + vv[j].w);
                s2 += (vv[j].x * vv[j].x + vv[j].y * vv[j].y) + (vv[j].z * vv[j].z + vv[j].w * vv[j].w);
            }
            s += __shfl_xor(s, 1, 64);  s2 += __shfl_xor(s2, 1, 64);
            s += __shfl_xor(s, 2, 64);  s2 += __shfl_xor(s2, 2, 64);
            float mean = s * (1.f / 128.f);
            float var = s2 * (1.f / 128.f) - mean * mean;
            float rs = rsqrtf(var + 1e-5f);
            int grow = row0 + rl;
            float* xrow = (float*)Cout + (size_t)grow * 128 + q4 * 32;
            u16* xbrow = xbout + (size_t)grow * 128 + q4 * 32;
#pragma unroll
            for (int j = 0; j < 8; ++j) {
                float4 gv = *(const float4*)(g + q4 * 32 + j * 4);
                float4 bv = *(const float4*)(be + q4 * 32 + j * 4);
                float o0 = (vv[j].x - mean) * rs * gv.x + bv.x;
                float o1 = (vv[j].y - mean) * rs * gv.y + bv.y;
                float o2 = (vv[j].z - mean) * rs * gv.z + bv.z;
                float o3 = (vv[j].w - mean) * rs * gv.w + bv.w;
                *(float4*)(xrow + j * 4) = make_float4(o0, o1, o2, o3);
                *(ushort4*)(xbrow + j * 4) = make_ushort4(f2b(o0), f2b(o1), f2b(o2), f2b(o3));
            }
        }
    } else {
        constexpr int MR = (BM == 128) ? 4 : 2;
#pragma unroll
        for (int m = 0; m < MR; ++m) {
#pragma unroll
            for (int n = 0; n < 4; ++n) {
                int cc, cr0;
                if (BM == 128) { cc = col0 + (wid & 1) * 64 + n * 16 + rA; cr0 = row0 + (wid >> 1) * 64 + m * 16 + kq * 4; }
                else           { cc = col0 + (wid >> 1) * 64 + n * 16 + rA; cr0 = row0 + (wid & 1) * 32 + m * 16 + kq * 4; }
                if (cc >= N) continue;
                float bv = bias[cc];
#pragma unroll
                for (int r = 0; r < 4; ++r) {
                    int cr = cr0 + r;
                    if (cr >= M) continue;
                    float v = acc[m][n][r] + bv;
                    if (RES) v += resid[(size_t)cr * N + cc];
                    if (ACT) v = fmaxf(v, 0.f);
                    if (OUTB) ((u16*)Cout)[(size_t)cr * N + cc] = f2b(v);
                    else      ((float*)Cout)[(size_t)cr * N + cc] = v;
                }
            }
        }
    }
}

// ===================== fused QKV-proj + flash attention =====================
// block = (b,h). Computes qkv slice (256 rows x 48 cols) into LDS, then attention.
#define KLS 40
#define VTS 272
__global__ __launch_bounds__(256) void k_qkvatt(const u16* __restrict__ xb, const u16* __restrict__ wT,
                                                const float* __restrict__ bq, const u16* __restrict__ bias,
                                                u16* __restrict__ o) {
    __shared__ __align__(16) char smem[73728];
    u16* Kl  = (u16*)smem;              // 256*40*2  = 20480
    u16* Vt  = (u16*)(smem + 20480);    // 16*272*2  =  8704
    u16* Ql  = (u16*)(smem + 29184);    // 256*16*2  =  8192
    u16* Pl  = (u16*)(smem + 37376);    // 4*16*272*2= 34816 (ends 72192)
    u16* Ast = (u16*)smem;              // 256*64*2  = 32768 (phase A)
    u16* Bst = (u16*)(smem + 32768);    // 48*64*2   =  6144 (phase A)
    int idx = blockIdx.x;
    int b = (idx & 7) * 8 + (idx >> 6);
    int h = (idx >> 3) & 7;
    int tid = threadIdx.x, wid = tid >> 6, lane = tid & 63;
    int rA = lane & 15, kq = lane >> 4;

    // ---------- phase A: qkv slice GEMM (256 x 48 x 128) ----------
    f32x4 acc[4][3] = {};
    for (int k0 = 0; k0 < 128; k0 += 64) {
        if (k0) __syncthreads();
#pragma unroll
        for (int i = 0; i < 8; ++i) {
            int row = wid * 64 + i * 8 + (lane >> 3);
            int sl = (((lane & 7) ^ (row & 7)) << 3);
            gload16(xb + ((size_t)(b * S_ + row)) * 128 + k0 + sl, &Ast[(wid * 64 + i * 8) * 64]);
        }
        if (wid < 3) {
#pragma unroll
            for (int i = 0; i < 2; ++i) {
                int c = wid * 2 + i;
                int brow = c * 8 + (lane >> 3);
                int grow = wid * 128 + h * 16 + (brow & 15);
                int sl = (((lane & 7) ^ (brow & 7)) << 3);
                gload16(wT + (size_t)grow * 128 + k0 + sl, &Bst[c * 8 * 64]);
            }
        }
        __syncthreads();
#pragma unroll
        for (int ks = 0; ks < 2; ++ks) {
            int sw = ((ks * 4 + kq) ^ (rA & 7)) * 8;
            short8 af[4], bfr[3];
#pragma unroll
            for (int m = 0; m < 4; ++m)
                af[m] = *(const short8*)&Ast[(wid * 64 + m * 16 + rA) * 64 + sw];
#pragma unroll
            for (int n = 0; n < 3; ++n)
                bfr[n] = *(const short8*)&Bst[(n * 16 + rA) * 64 + sw];
#pragma unroll
            for (int m = 0; m < 4; ++m)
#pragma unroll
                for (int n = 0; n < 3; ++n)
                    acc[m][n] = __builtin_amdgcn_mfma_f32_16x16x32_bf16(af[m], bfr[n], acc[m][n], 0, 0, 0);
        }
    }
    __syncthreads();   // staging reads done; write Q/K/V LDS (overlaps Ast/Bst)
    {
        short8 z = {};
        *(short8*)&Kl[tid * KLS + 16] = z;
        *(short8*)&Kl[tid * KLS + 24] = z;
    }
    {
        float bq0 = bq[h * 16 + rA];
        float bq1 = bq[128 + h * 16 + rA];
        float bq2 = bq[256 + h * 16 + rA];
#pragma unroll
        for (int m = 0; m < 4; ++m) {
            int cr0 = wid * 64 + m * 16 + kq * 4;
#pragma unroll
            for (int r = 0; r < 4; ++r) {
                int row = cr0 + r;
                Ql[row * 16 + rA]  = f2b(acc[m][0][r] + bq0);
                Kl[row * KLS + rA] = f2b(acc[m][1][r] + bq1);
                Vt[rA * VTS + row] = f2b(acc[m][2][r] + bq2);
            }
        }
    }
    __syncthreads();

    // ---------- phase B: attention ----------
    u16* pl = Pl + wid * 16 * VTS;
    int qi = lane & 15;
    for (int qt = 0; qt < 4; ++qt) {
        int q = wid * 64 + qt * 16 + qi;
        ushort4 bb[16];
        const u16* bp = bias + (size_t)b * (S_ * S_) + (size_t)q * S_ + kq * 4;
#pragma unroll
        for (int t = 0; t < 16; ++t) bb[t] = *(const ushort4*)(bp + t * 16);
        short8 qf = {};
        if (lane < 32)
            qf = *(const short8*)&Ql[q * 16 + kq * 8];
        f32x4 sc[16];
#pragma unroll
        for (int t = 0; t < 16; ++t) {
            short8 kf = *(const short8*)&Kl[(t * 16 + qi) * KLS + kq * 8];
            f32x4 zz = {0.f, 0.f, 0.f, 0.f};
            sc[t] = __builtin_amdgcn_mfma_f32_16x16x32_bf16(kf, qf, zz, 0, 0, 0);
        }
        float m = -1e30f;
#pragma unroll
        for (int t = 0; t < 16; ++t) {
            sc[t][0] = sc[t][0] * 0.25f + h2f(bb[t].x);
            sc[t][1] = sc[t][1] * 0.25f + h2f(bb[t].y);
            sc[t][2] = sc[t][2] * 0.25f + h2f(bb[t].z);
            sc[t][3] = sc[t][3] * 0.25f + h2f(bb[t].w);
            m = fmaxf(m, fmaxf(fmaxf(sc[t][0], sc[t][1]), fmaxf(sc[t][2], sc[t][3])));
        }
        m = fmaxf(m, __shfl_xor(m, 16, 64));
        m = fmaxf(m, __shfl_xor(m, 32, 64));
        float l = 0.f;
#pragma unroll
        for (int t = 0; t < 16; ++t) {
            sc[t][0] = __expf(sc[t][0] - m);
            sc[t][1] = __expf(sc[t][1] - m);
            sc[t][2] = __expf(sc[t][2] - m);
            sc[t][3] = __expf(sc[t][3] - m);
            l += (sc[t][0] + sc[t][1]) + (sc[t][2] + sc[t][3]);
        }
        l += __shfl_xor(l, 16, 64);
        l += __shfl_xor(l, 32, 64);
        float inv = 1.f / l;
#pragma unroll
        for (int t = 0; t < 16; ++t) {
            ushort4 pw = make_ushort4(f2b(sc[t][0] * inv), f2b(sc[t][1] * inv),
                                      f2b(sc[t][2] * inv), f2b(sc[t][3] * inv));
            *(ushort4*)&pl[qi * VTS + t * 16 + kq * 4] = pw;
        }
        f32x4 oa = {0.f, 0.f, 0.f, 0.f};
#pragma unroll
        for (int w8 = 0; w8 < 8; ++w8) {
            short8 vf = *(const short8*)&Vt[qi * VTS + w8 * 32 + kq * 8];
            short8 pf = *(const short8*)&pl[qi * VTS + w8 * 32 + kq * 8];
            oa = __builtin_amdgcn_mfma_f32_16x16x32_bf16(vf, pf, oa, 0, 0, 0);
        }
        ushort4 ow = make_ushort4(f2b(oa[0]), f2b(oa[1]), f2b(oa[2]), f2b(oa[3]));
        *(ushort4*)&o[((size_t)(b * S_ + q)) * D_ + h * 16 + kq * 4] = ow;
    }
}

// ===================== fused FFN =====================
__global__ __launch_bounds__(256) void k_ffn(const u16* __restrict__ xbin,
                                             const u16* __restrict__ w1T, const float* __restrict__ b1,
                                             const u16* __restrict__ w2T, const float* __restrict__ b2,
                                             const float* __restrict__ g, const float* __restrict__ be,
                                             float* __restrict__ x, u16* __restrict__ xbout) {
    __shared__ __align__(16) char smem[73728];
    u16* Alds = (u16*)smem;
    u16* Wlds = (u16*)(smem + 8192);
    u16* f1   = (u16*)(smem + 40960);
    float* vbuf = (float*)smem;
    int tid = threadIdx.x, wid = tid >> 6, lane = tid & 63;
    int rows0 = blockIdx.x * 32;
    int rA = lane & 15, kq = lane >> 4;

#pragma unroll
    for (int j = 0; j < 2; ++j) {
        int row = wid * 8 + j * 4 + (lane >> 4);
        int win = (lane >> 3) & 1, slot = lane & 7;
        gload16(xbin + (size_t)(rows0 + row) * 128 + win * 64 + ((slot ^ (row & 7)) << 3),
                Alds + (wid * 8 + j * 4) * 128);
    }

    for (int nh = 0; nh < 2; ++nh) {
        f32x4 acc1[2][4] = {};
        for (int k0 = 0; k0 < 128; k0 += 64) {
            __syncthreads();
#pragma unroll
            for (int i = 0; i < 8; ++i) {
                int rl2 = i * 32 + wid * 8 + (lane >> 3);
                gload16(w1T + (size_t)(nh * 256 + rl2) * 128 + k0 + (((lane & 7) ^ (rl2 & 7)) << 3),
                        Wlds + (i * 32 + wid * 8) * 64);
            }
            __syncthreads();
#pragma unroll
            for (int ks = 0; ks < 2; ++ks) {
                int sw = ((ks * 4 + kq) ^ (rA & 7)) << 3;
                short8 af[2], bf4[4];
                af[0] = *(const short8*)&Alds[rA * 128 + k0 + sw];
                af[1] = *(const short8*)&Alds[(16 + rA) * 128 + k0 + sw];
#pragma unroll
                for (int n = 0; n < 4; ++n)
                    bf4[n] = *(const short8*)&Wlds[(wid * 64 + n * 16 + rA) * 64 + sw];
#pragma unroll
                for (int m = 0; m < 2; ++m)
#pragma unroll
                    for (int n = 0; n < 4; ++n)
                        acc1[m][n] = __builtin_amdgcn_mfma_f32_16x16x32_bf16(af[m], bf4[n], acc1[m][n], 0, 0, 0);
            }
        }
#pragma unroll
        for (int m = 0; m < 2; ++m)
#pragma unroll
            for (int n = 0; n < 4; ++n) {
                int cc = nh * 256 + wid * 64 + n * 16 + rA;
                float bv = b1[cc];
#pragma unroll
                for (int r = 0; r < 4; ++r) {
                    int rl = m * 16 + kq * 4 + r;
                    float v = fmaxf(acc1[m][n][r] + bv, 0.f);
                    int scol = (cc & ~63) | (((((cc >> 3) & 7) ^ (rl & 7)) & 7) << 3) | (cc & 7);
                    f1[rl * 512 + scol] = f2b(v);
                }
            }
    }
    __syncthreads();

    f32x4 acc2[2][2] = {};
    for (int k0 = 0; k0 < 512; k0 += 64) {
        if (k0) __syncthreads();
#pragma unroll
        for (int i = 0; i < 4; ++i) {
            int rl2 = i * 32 + wid * 8 + (lane >> 3);
            gload16(w2T + (size_t)rl2 * 512 + k0 + (((lane & 7) ^ (rl2 & 7)) << 3),
                    Wlds + (i * 32 + wid * 8) * 64);
        }
        __syncthreads();
#pragma unroll
        for (int ks = 0; ks < 2; ++ks) {
            int sw = ((ks * 4 + kq) ^ (rA & 7)) << 3;
            short8 af0 = *(const short8*)&f1[rA * 512 + k0 + sw];
            short8 af1 = *(const short8*)&f1[(16 + rA) * 512 + k0 + sw];
            short8 bf0 = *(const short8*)&Wlds[(wid * 32 + rA) * 64 + sw];
            short8 bf1 = *(const short8*)&Wlds[(wid * 32 + 16 + rA) * 64 + sw];
            acc2[0][0] = __builtin_amdgcn_mfma_f32_16x16x32_bf16(af0, bf0, acc2[0][0], 0, 0, 0);
            acc2[0][1] = __builtin_amdgcn_mfma_f32_16x16x32_bf16(af0, bf1, acc2[0][1], 0, 0, 0);
            acc2[1][0] = __builtin_amdgcn_mfma_f32_16x16x32_bf16(af1, bf0, acc2[1][0], 0, 0, 0);
            acc2[1][1] = __builtin_amdgcn_mfma_f32_16x16x32_bf16(af1, bf1, acc2[1][1], 0, 0, 0);
        }
    }

    __syncthreads();
#pragma unroll
    for (int m = 0; m < 2; ++m)
#pragma unroll
        for (int n = 0; n < 2; ++n) {
            int cc = wid * 32 + n * 16 + rA;
            float bv = b2[cc];
#pragma unroll
            for (int r = 0; r < 4; ++r) {
                int rl = m * 16 + kq * 4 + r;
                float v = acc2[m][n][r] + bv + x[(size_t)(rows0 + rl) * 128 + cc];
                vbuf[rl * 133 + cc] = v;
            }
        }
    __syncthreads();
    int row = tid >> 3, sub = tid & 7;
    const float* vr = vbuf + row * 133 + sub * 16;
    float vv[16];
    float s = 0.f, s2 = 0.f;
#pragma unroll
    for (int j = 0; j < 16; ++j) {
        vv[j] = vr[j];
        s += vv[j];
        s2 += vv[j] * vv[j];
    }
    s += __shfl_xor(s, 1, 64);  s2 += __shfl_xor(s2, 1, 64);
    s += __shfl_xor(s, 2, 64);  s2 += __shfl_xor(s2, 2, 64);
    s += __shfl_xor(s, 4, 64);  s2 += __shfl_xor(s2, 4, 64);
    float mean = s * (1.f / 128.f);
    float var = s2 * (1.f / 128.f) - mean * mean;
    float rs = rsqrtf(var + 1e-5f);
    int grow = rows0 + row;
    float* xrow = x + (size_t)grow * 128 + sub * 16;
    u16* xbrow = xbout + (size_t)grow * 128 + sub * 16;
#pragma unroll
    for (int j = 0; j < 4; ++j) {
        float4 gv = *(const float4*)(g + sub * 16 + j * 4);
        float4 bv = *(const float4*)(be + sub * 16 + j * 4);
        float o0 = (vv[j * 4 + 0] - mean) * rs * gv.x + bv.x;
        float o1 = (vv[j * 4 + 1] - mean) * rs * gv.y + bv.y;
        float o2 = (vv[j * 4 + 2] - mean) * rs * gv.z + bv.z;
        float o3 = (vv[j * 4 + 3] - mean) * rs * gv.w + bv.w;
        *(float4*)(xrow + j * 4) = make_float4(o0, o1, o2, o3);
        *(ushort4*)(xbrow + j * 4) = make_ushort4(f2b(o0), f2b(o1), f2b(o2), f2b(o3));
    }
}

// ===================== fusion + positional encoding =====================
__global__ __launch_bounds__(256) void k_fusion(const float* __restrict__ spe, const int* __restrict__ traj,
                                                const float* __restrict__ ue_tab, const int* __restrict__ uid,
                                                const float* __restrict__ tempx, const int* __restrict__ hwx,
                                                const float* __restrict__ ce_tab, const float* __restrict__ flw,
                                                const float* __restrict__ flb, float* __restrict__ x,
                                                u16* __restrict__ xb) {
    __shared__ float Ws[22 * D_];
    __shared__ float bs[D_];
    __shared__ float ins[2][22];
    int tid = threadIdx.x;
    for (int i = tid; i < 22 * D_; i += 256) Ws[i] = flw[i];
    if (tid < D_) bs[tid] = flb[tid];
    __syncthreads();
    int ro = tid >> 7, d = tid & 127;
    int base = blockIdx.x * 32;
    for (int ir = 0; ir < 16; ++ir) {
        int tok = base + ir * 2 + ro;
        int b = tok >> 8, s = tok & 255;
        if (d < TD_) ins[ro][d] = tempx[(size_t)tok * TD_ + d];
        else if (d < 22) ins[ro][d] = ce_tab[(size_t)hwx[tok] * CED_ + (d - TD_)];
        __syncthreads();
        float acc = bs[d];
#pragma unroll
        for (int k = 0; k < 22; ++k) acc = fmaf(ins[ro][k], Ws[k * D_ + d], acc);
        acc = fmaxf(acc, 0.f);
        int i2 = d & ~1;
        float ang = (float)s * __expf(-(float)i2 * 0.0719557841560639f);
        float pe = (d & 1) ? cosf(ang) : sinf(ang);
        float v = spe[(size_t)traj[tok] * D_ + d] + ue_tab[(size_t)uid[b] * D_ + d] + acc + pe;
        x[(size_t)tok * D_ + d] = v;
        xb[(size_t)tok * D_ + d] = f2b(v);
        __syncthreads();
    }
}

// ===================== launch =====================
extern "C" void kernel_launch(void* const* d_in, const int* in_sizes, int n_in,
                              void* d_out, int out_size, void* d_ws, size_t ws_size,
                              hipStream_t stream) {
    const float* node_feature = (const float*)d_in[0];
    const int*   edge_index   = (const int*)d_in[1];
    const int*   traj_x       = (const int*)d_in[2];
    const float* temporal_x   = (const float*)d_in[3];
    const int*   user_id_x    = (const int*)d_in[4];
    const int*   mask         = (const int*)d_in[5];
    const int*   end_idx      = (const int*)d_in[6];
    const float* tmat         = (const float*)d_in[8];
    const float* dmat         = (const float*)d_in[9];
    const int*   highway_x    = (const int*)d_in[10];
    const float* lambda2      = (const float*)d_in[11];
    const float* gnn_w1       = (const float*)d_in[12];
    const float* gnn_b1       = (const float*)d_in[13];
    const float* gnn_w2       = (const float*)d_in[14];
    const float* gnn_b2       = (const float*)d_in[15];
    const float* ue_tab       = (const float*)d_in[16];
    const float* ce_tab       = (const float*)d_in[17];
    const float* fl_w         = (const float*)d_in[18];
    const float* fl_b         = (const float*)d_in[19];
    const float* wqkv         = (const float*)d_in[20];
    const float* bqkv         = (const float*)d_in[21];
    const float* wo           = (const float*)d_in[22];
    const float* bo           = (const float*)d_in[23];
    const float* ln1_g        = (const float*)d_in[24];
    const float* ln1_b        = (const float*)d_in[25];
    const float* ln2_g        = (const float*)d_in[26];
    const float* ln2_b        = (const float*)d_in[27];
    const float* ffn_w1       = (const float*)d_in[28];
    const float* ffn_b1       = (const float*)d_in[29];
    const float* ffn_w2       = (const float*)d_in[30];
    const float* ffn_b2       = (const float*)d_in[31];
    const float* head_w       = (const float*)d_in[32];
    const float* head_b       = (const float*)d_in[33];
    float* out = (float*)d_out;

    // ---- workspace layout (float units) ----
    float* w     = (float*)d_ws;
    int*   cnt   = (int*)w;                  // [0, 40,960)
    float* spe   = w + 40960;                // [40,960, 5,169,152)
    u16*   biasb = (u16*)(w + 5169152);      // [5,169,152, 7,266,304)
    float* wreg  = w + 7266304;              // bf16 weights -> ends 7,999,488
    u16* wqkvT = (u16*)wreg;
    u16* woT   = wqkvT + 4 * 384 * 128;
    u16* w1T   = woT + 4 * 128 * 128;
    u16* w2T   = w1T + 4 * 512 * 128;
    u16* gw1T  = w2T + 4 * 128 * 512;
    u16* gw2T  = gw1T + 128 * 64;
    u16* hwT   = gw2T + 128 * 128;
    float* pool  = w + 8000000;
    // GNN phase
    u16*   h1b   = (u16*)pool;               // [0, 2,564,096) f
    u16*   in1b  = (u16*)(pool + 2564096);   // [2,564,096, 3,846,144)
    u16*   in2b  = (u16*)(pool + 3846144);   // [3,846,144, 6,410,240)
    int*   off   = (int*)(pool + 6410240);
    int*   cursor= (int*)(pool + 6450304);
    int*   ebuf  = (int*)(pool + 6490368);
    int*   part  = (int*)(pool + 6650368);
    // transformer phase
    float* x     = pool;                     // [0, 2,097,152)
    u16*   xb    = (u16*)(pool + 2097152);   // [2,097,152, 2,621,440)
    u16*   attob = (u16*)(pool + 4718592);   // [4,718,592, 5,242,880)

    const int* esrc = edge_index;
    const int* edst = edge_index + E_;

    // ---- uber prep ----
    UberArgs ua;
    const float* srcs[7] = {wqkv, wo, ffn_w1, ffn_w2, gnn_w1, gnn_w2, head_w};
    u16* dsts[7]        = {wqkvT, woT, w1T, w2T, gw1T, gw2T, hwT};
    int Ks[7]    = {128, 128, 128, 512, 32, 128, 128};
    int Npads[7] = {384, 128, 512, 128, 128, 128, UP_};
    int Nsrcs[7] = {384, 128, 512, 128, 128, 128, U_};
    int Kps[7]   = {128, 128, 128, 512, 64, 128, 128};
    int Ls[7]    = {4, 4, 4, 4, 1, 1, 1};
    int bb = UB_CNT_END;
    for (int t = 0; t < 7; ++t) {
        ua.csrc[t] = srcs[t]; ua.cdst[t] = dsts[t];
        ua.K[t] = Ks[t]; ua.Npad[t] = Npads[t]; ua.Nsrc[t] = Nsrcs[t]; ua.Kp[t] = Kps[t];
        ua.base[t] = bb;
        bb += (Npads[t] / 32) * (Kps[t] / 32) * Ls[t];
    }
    ua.tm = tmat; ua.dm = dmat; ua.maskp = mask; ua.lambda2 = lambda2;
    ua.bias = biasb; ua.cnt = cnt;
    k_uber<<<UB_TOTAL, 256, 0, stream>>>(ua);

    // ---- GNN: CSR build + gather ----
    k_count<<<(E_ + 255) / 256, 256, 0, stream>>>(edst, cnt);
    k_scanA<<<NSCB, 256, 0, stream>>>(cnt, part);
    k_scanB<<<NSCB, 256, 0, stream>>>(cnt, part, off, cursor);
    k_fill<<<(E_ + 255) / 256, 256, 0, stream>>>(esrc, edst, cursor, ebuf);
    k_gprep1<<<NP_ / 8, 256, 0, stream>>>(node_feature, off, cnt, ebuf, in1b);
    k_mgemm<128, 1, 1, 0, 0, 0><<<dim3(NP_ / 128, 1), 256, 0, stream>>>(in1b, gw1T, gnn_b1, nullptr, h1b,
                                                                        nullptr, nullptr, nullptr, nullptr, NP_, D_, 64);
    k_gprep2<<<NP_ / 4, 256, 0, stream>>>(h1b, off, cnt, ebuf, in2b);
    k_mgemm<128, 1, 0, 0, 0, 0><<<dim3(NP_ / 128, 1), 256, 0, stream>>>(in2b, gw2T, gnn_b2, nullptr, spe,
                                                                        nullptr, nullptr, nullptr, nullptr, NP_, D_, D_);

    // ---- fusion ----
    k_fusion<<<(B_ * S_) / 32, 256, 0, stream>>>(spe, traj_x, ue_tab, user_id_x,
                                                 temporal_x, highway_x, ce_tab, fl_w, fl_b, x, xb);

    // ---- transformer ----
    const int M = B_ * S_;
    for (int l = 0; l < L_; ++l) {
        k_qkvatt<<<B_ * H_, 256, 0, stream>>>(xb, wqkvT + (size_t)l * 384 * 128,
                                              bqkv + (size_t)l * 384, biasb, attob);
        k_mgemm<64, 0, 0, 1, 1, 0><<<dim3(M / 64, 1), 256, 0, stream>>>(attob, woT + (size_t)l * 128 * 128,
                                                                        bo + l * D_, x, x,
                                                                        ln1_g + l * D_, ln1_b + l * D_, xb, nullptr, M, D_, D_);
        k_ffn<<<M / 32, 256, 0, stream>>>(xb, w1T + (size_t)l * 512 * 128, ffn_b1 + l * FF_,
                                          w2T + (size_t)l * 128 * 512, ffn_b2 + l * D_,
                                          ln2_g + l * D_, ln2_b + l * D_, x, xb);
    }

    // ---- head (gather fused) ----
    k_mgemm<64, 0, 0, 0, 0, 1><<<dim3(1, UP_ / 128), 256, 0, stream>>>(xb, hwT, head_b, nullptr, out,
                                                                       nullptr, nullptr, nullptr, end_idx, B_, U_, D_);
}

// Round 10
// 303.172 us; speedup vs baseline: 3.9729x; 1.1556x over previous
//
#include <hip/hip_runtime.h>
#include <hip/hip_fp16.h>
#include <cstdint>
#include <cstddef>

typedef unsigned short u16;
typedef __attribute__((ext_vector_type(8))) short short8;
typedef __attribute__((ext_vector_type(4))) float f32x4;

// ---- problem constants ----
#define B_   64
#define S_   256
#define D_   128
#define H_   8
#define DH_  16
#define FF_  512
#define L_   4
#define U_   5000
#define UP_  5120
#define N_   40000
#define NP_  40064
#define E_   160000
#define FEA_ 32
#define HWY_ 16
#define CED_ 16
#define TD_  6
#define NSCB 157
// uber kernel block ranges
#define UB_CNT_END 160
#define UB_CVT_END 1592
#define UB_TOTAL   5688

static __device__ __forceinline__ u16 f2b(float f) {
    unsigned int u = __float_as_uint(f);
    unsigned int r = (u + 0x7FFFu + ((u >> 16) & 1u)) >> 16;
    return (u16)r;
}
static __device__ __forceinline__ float b2f(u16 u) {
    return __uint_as_float(((unsigned int)u) << 16);
}
static __device__ __forceinline__ u16 f2h(float f) {
    return __half_as_ushort(__float2half(f));
}
static __device__ __forceinline__ float h2f(u16 u) {
    return __half2float(__ushort_as_half(u));
}

static __device__ __forceinline__ void gload16(const void* g, void* l) {
    __builtin_amdgcn_global_load_lds(
        (const __attribute__((address_space(1))) unsigned int*)g,
        (__attribute__((address_space(3))) unsigned int*)l,
        16, 0, 0);
}

// ===================== uber prep: cnt-zero + 7 weight transposes + attn bias =====================
struct UberArgs {
    const float* csrc[7];
    u16* cdst[7];
    int K[7], Npad[7], Nsrc[7], Kp[7], base[7];
    const float* tm; const float* dm; const int* maskp; const float* lambda2;
    u16* bias; int* cnt;
};

__global__ __launch_bounds__(256) void k_uber(UberArgs a) {
    __shared__ float tile[32][33];
    int bid = blockIdx.x, tid = threadIdx.x;
    if (bid < UB_CNT_END) {
        int idx = bid * 256 + tid;
        if (idx < NP_) a.cnt[idx] = 0;
        return;
    }
    if (bid < UB_CVT_END) {
        int t = 0;
#pragma unroll
        for (int i = 1; i < 7; ++i) t += (bid >= a.base[i]);
        int rb = bid - a.base[t];
        int K = a.K[t], Npad = a.Npad[t], Nsrc = a.Nsrc[t], Kp = a.Kp[t];
        int nbn = Npad >> 5, nbk = Kp >> 5;
        int per = nbn * nbk;
        int l = rb / per, rem = rb - l * per;
        int n0 = (rem % nbn) * 32, k0 = (rem / nbn) * 32;
        const float* in = a.csrc[t];
        u16* outp = a.cdst[t];
        int j = tid & 31, i2 = tid >> 5;
#pragma unroll
        for (int r = 0; r < 4; ++r) {
            int k = k0 + i2 + r * 8, n = n0 + j;
            tile[i2 + r * 8][j] = (k < K && n < Nsrc) ? in[(size_t)l * K * Nsrc + (size_t)k * Nsrc + n] : 0.f;
        }
        __syncthreads();
#pragma unroll
        for (int r = 0; r < 4; ++r) {
            int n = n0 + i2 + r * 8, k = k0 + j;
            if (n < Npad && k < Kp)
                outp[(size_t)l * Npad * Kp + (size_t)n * Kp + k] = f2b(tile[j][i2 + r * 8]);
        }
        return;
    }
    int t4 = (bid - UB_CVT_END) * 256 + tid;
    const int total = B_ * S_ * S_ / 4;
    if (t4 >= total) return;
    float l2 = *a.lambda2, l2c = 1.f - l2;
    float4 av = ((const float4*)a.tm)[t4];
    float4 bv = ((const float4*)a.dm)[t4];
    int basei = t4 * 4;
    int bb = basei >> 16;
    int k0 = basei & 255;
    const int* mrow = a.maskp + bb * S_;
    float r0 = (mrow[k0 + 0] > 0 ? 0.f : -30000.f) - (l2 * __logf(1.f + av.x) + l2c * __logf(1.f + bv.x));
    float r1 = (mrow[k0 + 1] > 0 ? 0.f : -30000.f) - (l2 * __logf(1.f + av.y) + l2c * __logf(1.f + bv.y));
    float r2 = (mrow[k0 + 2] > 0 ? 0.f : -30000.f) - (l2 * __logf(1.f + av.z) + l2c * __logf(1.f + bv.z));
    float r3 = (mrow[k0 + 3] > 0 ? 0.f : -30000.f) - (l2 * __logf(1.f + av.w) + l2c * __logf(1.f + bv.w));
    *(ushort4*)&a.bias[(size_t)t4 * 4] = make_ushort4(f2h(r0), f2h(r1), f2h(r2), f2h(r3));
}

// ===================== CSR build =====================
__global__ __launch_bounds__(256) void k_count(const int* __restrict__ dst, int* __restrict__ cnt) {
    int e = blockIdx.x * 256 + threadIdx.x;
    if (e < E_) atomicAdd(&cnt[dst[e]], 1);
}

__global__ __launch_bounds__(256) void k_scanA(const int* __restrict__ cnt, int* __restrict__ part) {
    __shared__ int sh[256];
    int idx = blockIdx.x * 256 + threadIdx.x;
    sh[threadIdx.x] = (idx < NP_) ? cnt[idx] : 0;
    __syncthreads();
    for (int o = 128; o > 0; o >>= 1) {
        if (threadIdx.x < o) sh[threadIdx.x] += sh[threadIdx.x + o];
        __syncthreads();
    }
    if (threadIdx.x == 0) part[blockIdx.x] = sh[0];
}

__global__ __launch_bounds__(256) void k_scanB(const int* __restrict__ cnt, const int* __restrict__ part,
                                               int* __restrict__ off, int* __restrict__ cursor) {
    __shared__ int sh[256];
    __shared__ int bsum;
    int tid = threadIdx.x;
    int pv = (tid < blockIdx.x) ? part[tid] : 0;
    sh[tid] = pv;
    __syncthreads();
    for (int o = 128; o > 0; o >>= 1) {
        if (tid < o) sh[tid] += sh[tid + o];
        __syncthreads();
    }
    if (tid == 0) bsum = sh[0];
    __syncthreads();
    int basev = bsum;
    __syncthreads();
    int idx = blockIdx.x * 256 + tid;
    int v = (idx < NP_) ? cnt[idx] : 0;
    sh[tid] = v;
    __syncthreads();
    for (int o = 1; o < 256; o <<= 1) {
        int t2 = (tid >= o) ? sh[tid - o] : 0;
        __syncthreads();
        sh[tid] += t2;
        __syncthreads();
    }
    if (idx < NP_) {
        int res = sh[tid] - v + basev;
        off[idx] = res;
        cursor[idx] = res;
    }
}

__global__ __launch_bounds__(256) void k_fill(const int* __restrict__ src, const int* __restrict__ dst,
                                              int* __restrict__ cursor, int* __restrict__ ebuf) {
    int e = blockIdx.x * 256 + threadIdx.x;
    if (e >= E_) return;
    int p = atomicAdd(&cursor[dst[e]], 1);
    ebuf[p] = src[e];
}

// ===================== GNN gather+prep =====================
__global__ __launch_bounds__(256) void k_gprep1(const float* __restrict__ nf, const int* __restrict__ off,
                                                const int* __restrict__ cnt, const int* __restrict__ ebuf,
                                                u16* __restrict__ out) {
    int n = blockIdx.x * 8 + (threadIdx.x >> 5);
    int f = threadIdx.x & 31;
    u16 r = 0;
    if (n < N_) {
        int start = off[n], c = cnt[n];
        float acc = 0.f;
        int i = 0;
        for (; i + 4 <= c; i += 4) {
            int s0 = ebuf[start + i], s1 = ebuf[start + i + 1];
            int s2 = ebuf[start + i + 2], s3 = ebuf[start + i + 3];
            float v0 = nf[(size_t)s0 * FEA_ + f];
            float v1 = nf[(size_t)s1 * FEA_ + f];
            float v2 = nf[(size_t)s2 * FEA_ + f];
            float v3 = nf[(size_t)s3 * FEA_ + f];
            acc += (v0 + v1) + (v2 + v3);
        }
        for (; i < c; ++i) {
            int s = ebuf[start + i];
            acc += nf[(size_t)s * FEA_ + f];
        }
        r = f2b(nf[(size_t)n * FEA_ + f] + acc / (float)(c + 1));
    }
    if (n < NP_) {
        out[(size_t)n * 64 + f] = r;
        out[(size_t)n * 64 + 32 + f] = 0;
    }
}

__global__ __launch_bounds__(256) void k_gprep2(const u16* __restrict__ h1b, const int* __restrict__ off,
                                                const int* __restrict__ cnt, const int* __restrict__ ebuf,
                                                u16* __restrict__ out) {
    int n = blockIdx.x * 4 + (threadIdx.x >> 6);
    int d2 = (threadIdx.x & 63) * 2;
    if (n >= NP_) return;
    u16 r0 = 0, r1 = 0;
    if (n < N_) {
        int start = off[n], c = cnt[n];
        float a0 = 0.f, a1 = 0.f;
        int i = 0;
        for (; i + 4 <= c; i += 4) {
            int s0 = ebuf[start + i], s1 = ebuf[start + i + 1];
            int s2 = ebuf[start + i + 2], s3 = ebuf[start + i + 3];
            ushort2 v0 = *(const ushort2*)&h1b[(size_t)s0 * D_ + d2];
            ushort2 v1 = *(const ushort2*)&h1b[(size_t)s1 * D_ + d2];
            ushort2 v2 = *(const ushort2*)&h1b[(size_t)s2 * D_ + d2];
            ushort2 v3 = *(const ushort2*)&h1b[(size_t)s3 * D_ + d2];
            a0 += (b2f(v0.x) + b2f(v1.x)) + (b2f(v2.x) + b2f(v3.x));
            a1 += (b2f(v0.y) + b2f(v1.y)) + (b2f(v2.y) + b2f(v3.y));
        }
        for (; i < c; ++i) {
            int s = ebuf[start + i];
            ushort2 v = *(const ushort2*)&h1b[(size_t)s * D_ + d2];
            a0 += b2f(v.x); a1 += b2f(v.y);
        }
        float rinv = 1.f / (float)(c + 1);
        ushort2 sv = *(const ushort2*)&h1b[(size_t)n * D_ + d2];
        r0 = f2b(b2f(sv.x) + a0 * rinv);
        r1 = f2b(b2f(sv.y) + a1 * rinv);
    }
    *(ushort2*)&out[(size_t)n * D_ + d2] = make_ushort2(r0, r1);
}

// ===================== MFMA GEMM (BM 64/128, opt gathered A) =====================
template<int BM, int ACT, int OUTB, int GAT>
__global__ __launch_bounds__(256) void k_mgemm(const u16* __restrict__ A, const u16* __restrict__ BT,
                                               const float* __restrict__ bias, void* __restrict__ Cout,
                                               const int* __restrict__ endi, int M, int N, int K) {
    constexpr int SMEMB = (BM == 128) ? 32768 : 24576;
    __shared__ __align__(16) char smem[SMEMB];
    u16* Al = (u16*)smem;
    u16* Bl = Al + (BM == 128 ? 128 * 64 : 64 * 64);
    int tid = threadIdx.x;
    int wid = tid >> 6, lane = tid & 63;
    int row0 = blockIdx.x * BM;
    int col0 = blockIdx.y * 128;
    f32x4 acc[4][4] = {};
    int rA = lane & 15, kq = lane >> 4;

    for (int k0 = 0; k0 < K; k0 += 64) {
        if (k0) __syncthreads();
        if (BM == 128) {
            int srow = wid * 32 + (lane >> 3);
            int ks8 = ((lane & 7) ^ (lane >> 3)) * 8;
#pragma unroll
            for (int i = 0; i < 4; ++i) {
                int row = srow + i * 8;
                size_t arow = (size_t)(row0 + row);
                if (GAT) {
                    int bb2 = row0 + row;
                    arow = (bb2 < B_) ? ((size_t)bb2 * S_ + endi[bb2]) : 0;
                }
                gload16(A + arow * K + k0 + ks8, &Al[(wid * 32 + i * 8) * 64]);
                gload16(BT + (size_t)(col0 + row) * K + k0 + ks8, &Bl[(wid * 32 + i * 8) * 64]);
            }
        } else {
#pragma unroll
            for (int i = 0; i < 6; ++i) {
                int c = wid * 6 + i;
                int rr = c * 8 + (lane >> 3);
                int sl = (((lane & 7) ^ (rr & 7)) << 3);
                if (c < 8) {
                    size_t arow = (size_t)(row0 + rr);
                    if (GAT) {
                        int bb2 = row0 + rr;
                        arow = (bb2 < B_) ? ((size_t)bb2 * S_ + endi[bb2]) : 0;
                    }
                    gload16(A + arow * K + k0 + sl, &Al[rr * 64]);
                } else {
                    gload16(BT + (size_t)(col0 + rr - 64) * K + k0 + sl, &Bl[(rr - 64) * 64]);
                }
            }
        }
        __syncthreads();
#pragma unroll
        for (int ks = 0; ks < 2; ++ks) {
            int sw = ((ks * 4 + kq) ^ (rA & 7)) * 8;
            if (BM == 128) {
                int wr = wid >> 1, wc = wid & 1;
                short8 af[4], bfr[4];
#pragma unroll
                for (int m = 0; m < 4; ++m)
                    af[m] = *(const short8*)&Al[(64 * wr + m * 16 + rA) * 64 + sw];
#pragma unroll
                for (int n = 0; n < 4; ++n)
                    bfr[n] = *(const short8*)&Bl[(64 * wc + n * 16 + rA) * 64 + sw];
#pragma unroll
                for (int m = 0; m < 4; ++m)
#pragma unroll
                    for (int n = 0; n < 4; ++n)
                        acc[m][n] = __builtin_amdgcn_mfma_f32_16x16x32_bf16(af[m], bfr[n], acc[m][n], 0, 0, 0);
            } else {
                int wr2 = wid & 1, wc2 = wid >> 1;
                short8 af[2], bfr[4];
#pragma unroll
                for (int m = 0; m < 2; ++m)
                    af[m] = *(const short8*)&Al[(wr2 * 32 + m * 16 + rA) * 64 + sw];
#pragma unroll
                for (int n = 0; n < 4; ++n)
                    bfr[n] = *(const short8*)&Bl[(wc2 * 64 + n * 16 + rA) * 64 + sw];
#pragma unroll
                for (int m = 0; m < 2; ++m)
#pragma unroll
                    for (int n = 0; n < 4; ++n)
                        acc[m][n] = __builtin_amdgcn_mfma_f32_16x16x32_bf16(af[m], bfr[n], acc[m][n], 0, 0, 0);
            }
        }
    }

    constexpr int MR = (BM == 128) ? 4 : 2;
#pragma unroll
    for (int m = 0; m < MR; ++m) {
#pragma unroll
        for (int n = 0; n < 4; ++n) {
            int cc, cr0;
            if (BM == 128) { cc = col0 + (wid & 1) * 64 + n * 16 + rA; cr0 = row0 + (wid >> 1) * 64 + m * 16 + kq * 4; }
            else           { cc = col0 + (wid >> 1) * 64 + n * 16 + rA; cr0 = row0 + (wid & 1) * 32 + m * 16 + kq * 4; }
            if (cc >= N) continue;
            float bv = bias[cc];
#pragma unroll
            for (int r = 0; r < 4; ++r) {
                int cr = cr0 + r;
                if (cr >= M) continue;
                float v = acc[m][n][r] + bv;
                if (ACT) v = fmaxf(v, 0.f);
                if (OUTB) ((u16*)Cout)[(size_t)cr * N + cc] = f2b(v);
                else      ((float*)Cout)[(size_t)cr * N + cc] = v;
            }
        }
    }
}

// ===================== fused QKV-proj + flash attention =====================
#define KLS 40
#define VTS 272
__global__ __launch_bounds__(256) void k_qkvatt(const u16* __restrict__ xb, const u16* __restrict__ wT,
                                                const float* __restrict__ bq, const u16* __restrict__ bias,
                                                u16* __restrict__ o) {
    __shared__ __align__(16) char smem[73728];
    u16* Kl  = (u16*)smem;
    u16* Vt  = (u16*)(smem + 20480);
    u16* Ql  = (u16*)(smem + 29184);
    u16* Pl  = (u16*)(smem + 37376);
    u16* Ast = (u16*)smem;
    u16* Bst = (u16*)(smem + 32768);
    int idx = blockIdx.x;
    int b = (idx & 7) * 8 + (idx >> 6);
    int h = (idx >> 3) & 7;
    int tid = threadIdx.x, wid = tid >> 6, lane = tid & 63;
    int rA = lane & 15, kq = lane >> 4;

    f32x4 acc[4][3] = {};
    for (int k0 = 0; k0 < 128; k0 += 64) {
        if (k0) __syncthreads();
#pragma unroll
        for (int i = 0; i < 8; ++i) {
            int row = wid * 64 + i * 8 + (lane >> 3);
            int sl = (((lane & 7) ^ (row & 7)) << 3);
            gload16(xb + ((size_t)(b * S_ + row)) * 128 + k0 + sl, &Ast[(wid * 64 + i * 8) * 64]);
        }
        if (wid < 3) {
#pragma unroll
            for (int i = 0; i < 2; ++i) {
                int c = wid * 2 + i;
                int brow = c * 8 + (lane >> 3);
                int grow = wid * 128 + h * 16 + (brow & 15);
                int sl = (((lane & 7) ^ (brow & 7)) << 3);
                gload16(wT + (size_t)grow * 128 + k0 + sl, &Bst[c * 8 * 64]);
            }
        }
        __syncthreads();
#pragma unroll
        for (int ks = 0; ks < 2; ++ks) {
            int sw = ((ks * 4 + kq) ^ (rA & 7)) * 8;
            short8 af[4], bfr[3];
#pragma unroll
            for (int m = 0; m < 4; ++m)
                af[m] = *(const short8*)&Ast[(wid * 64 + m * 16 + rA) * 64 + sw];
#pragma unroll
            for (int n = 0; n < 3; ++n)
                bfr[n] = *(const short8*)&Bst[(n * 16 + rA) * 64 + sw];
#pragma unroll
            for (int m = 0; m < 4; ++m)
#pragma unroll
                for (int n = 0; n < 3; ++n)
                    acc[m][n] = __builtin_amdgcn_mfma_f32_16x16x32_bf16(af[m], bfr[n], acc[m][n], 0, 0, 0);
        }
    }
    __syncthreads();
    {
        short8 z = {};
        *(short8*)&Kl[tid * KLS + 16] = z;
        *(short8*)&Kl[tid * KLS + 24] = z;
    }
    {
        float bq0 = bq[h * 16 + rA];
        float bq1 = bq[128 + h * 16 + rA];
        float bq2 = bq[256 + h * 16 + rA];
#pragma unroll
        for (int m = 0; m < 4; ++m) {
            int cr0 = wid * 64 + m * 16 + kq * 4;
#pragma unroll
            for (int r = 0; r < 4; ++r) {
                int row = cr0 + r;
                Ql[row * 16 + rA]  = f2b(acc[m][0][r] + bq0);
                Kl[row * KLS + rA] = f2b(acc[m][1][r] + bq1);
                Vt[rA * VTS + row] = f2b(acc[m][2][r] + bq2);
            }
        }
    }
    __syncthreads();

    u16* pl = Pl + wid * 16 * VTS;
    int qi = lane & 15;
    for (int qt = 0; qt < 4; ++qt) {
        int q = wid * 64 + qt * 16 + qi;
        ushort4 bb[16];
        const u16* bp = bias + (size_t)b * (S_ * S_) + (size_t)q * S_ + kq * 4;
#pragma unroll
        for (int t = 0; t < 16; ++t) bb[t] = *(const ushort4*)(bp + t * 16);
        short8 qf = {};
        if (lane < 32)
            qf = *(const short8*)&Ql[q * 16 + kq * 8];
        f32x4 sc[16];
#pragma unroll
        for (int t = 0; t < 16; ++t) {
            short8 kf = *(const short8*)&Kl[(t * 16 + qi) * KLS + kq * 8];
            f32x4 zz = {0.f, 0.f, 0.f, 0.f};
            sc[t] = __builtin_amdgcn_mfma_f32_16x16x32_bf16(kf, qf, zz, 0, 0, 0);
        }
        float m = -1e30f;
#pragma unroll
        for (int t = 0; t < 16; ++t) {
            sc[t][0] = sc[t][0] * 0.25f + h2f(bb[t].x);
            sc[t][1] = sc[t][1] * 0.25f + h2f(bb[t].y);
            sc[t][2] = sc[t][2] * 0.25f + h2f(bb[t].z);
            sc[t][3] = sc[t][3] * 0.25f + h2f(bb[t].w);
            m = fmaxf(m, fmaxf(fmaxf(sc[t][0], sc[t][1]), fmaxf(sc[t][2], sc[t][3])));
        }
        m = fmaxf(m, __shfl_xor(m, 16, 64));
        m = fmaxf(m, __shfl_xor(m, 32, 64));
        float l = 0.f;
#pragma unroll
        for (int t = 0; t < 16; ++t) {
            sc[t][0] = __expf(sc[t][0] - m);
            sc[t][1] = __expf(sc[t][1] - m);
            sc[t][2] = __expf(sc[t][2] - m);
            sc[t][3] = __expf(sc[t][3] - m);
            l += (sc[t][0] + sc[t][1]) + (sc[t][2] + sc[t][3]);
        }
        l += __shfl_xor(l, 16, 64);
        l += __shfl_xor(l, 32, 64);
        float inv = 1.f / l;
#pragma unroll
        for (int t = 0; t < 16; ++t) {
            ushort4 pw = make_ushort4(f2b(sc[t][0] * inv), f2b(sc[t][1] * inv),
                                      f2b(sc[t][2] * inv), f2b(sc[t][3] * inv));
            *(ushort4*)&pl[qi * VTS + t * 16 + kq * 4] = pw;
        }
        f32x4 oa = {0.f, 0.f, 0.f, 0.f};
#pragma unroll
        for (int w8 = 0; w8 < 8; ++w8) {
            short8 vf = *(const short8*)&Vt[qi * VTS + w8 * 32 + kq * 8];
            short8 pf = *(const short8*)&pl[qi * VTS + w8 * 32 + kq * 8];
            oa = __builtin_amdgcn_mfma_f32_16x16x32_bf16(vf, pf, oa, 0, 0, 0);
        }
        ushort4 ow = make_ushort4(f2b(oa[0]), f2b(oa[1]), f2b(oa[2]), f2b(oa[3]));
        *(ushort4*)&o[((size_t)(b * S_ + q)) * D_ + h * 16 + kq * 4] = ow;
    }
}

// ===================== fused layer-tail: LN1(x + atto@wo + bo) -> FFN -> LN2 =====================
// block = 32 rows, 256 threads / 4 waves; grid = M/32 = 256
__global__ __launch_bounds__(256) void k_layer(const u16* __restrict__ atto,
                                               const u16* __restrict__ woT, const float* __restrict__ bo,
                                               const float* __restrict__ ln1g, const float* __restrict__ ln1b,
                                               const u16* __restrict__ w1T, const float* __restrict__ b1,
                                               const u16* __restrict__ w2T, const float* __restrict__ b2,
                                               const float* __restrict__ ln2g, const float* __restrict__ ln2b,
                                               float* __restrict__ x, u16* __restrict__ xbout) {
    __shared__ __align__(16) char smem[73728];
    u16* Alds = (u16*)smem;                 // [32][128]  8KB (atto staging, then LN1 bf16)
    u16* Wlds = (u16*)(smem + 8192);        // [<=256][64] 32KB (streamed weights)
    u16* f1   = (u16*)(smem + 40960);       // [32][512] 32KB (swizzled)
    float* vbuf = (float*)smem;             // 17KB overlay (epilogues)
    int tid = threadIdx.x, wid = tid >> 6, lane = tid & 63;
    int rows0 = blockIdx.x * 32;
    int rA = lane & 15, kq = lane >> 4;
    int row = tid >> 3, sub = tid & 7;      // LN ownership: 8 threads/row, 16 cols each

    // stage atto rows [32][128] (pre-swizzled source, linear dest)
#pragma unroll
    for (int j = 0; j < 2; ++j) {
        int srow = wid * 8 + j * 4 + (lane >> 4);
        int win = (lane >> 3) & 1, slot = lane & 7;
        gload16(atto + (size_t)(rows0 + srow) * 128 + win * 64 + ((slot ^ (srow & 7)) << 3),
                Alds + (wid * 8 + j * 4) * 128);
    }

    // ---------- phase WO: accw = A @ woT^T (32 x 128 x 128) ----------
    f32x4 accw[2][2] = {};
    for (int k0 = 0; k0 < 128; k0 += 64) {
        __syncthreads();
#pragma unroll
        for (int i = 0; i < 4; ++i) {
            int rl2 = i * 32 + wid * 8 + (lane >> 3);
            gload16(woT + (size_t)rl2 * 128 + k0 + (((lane & 7) ^ (rl2 & 7)) << 3),
                    Wlds + (i * 32 + wid * 8) * 64);
        }
        __syncthreads();
#pragma unroll
        for (int ks = 0; ks < 2; ++ks) {
            int sw = ((ks * 4 + kq) ^ (rA & 7)) << 3;
            short8 af0 = *(const short8*)&Alds[rA * 128 + k0 + sw];
            short8 af1 = *(const short8*)&Alds[(16 + rA) * 128 + k0 + sw];
            short8 bf0 = *(const short8*)&Wlds[(wid * 32 + rA) * 64 + sw];
            short8 bf1 = *(const short8*)&Wlds[(wid * 32 + 16 + rA) * 64 + sw];
            accw[0][0] = __builtin_amdgcn_mfma_f32_16x16x32_bf16(af0, bf0, accw[0][0], 0, 0, 0);
            accw[0][1] = __builtin_amdgcn_mfma_f32_16x16x32_bf16(af0, bf1, accw[0][1], 0, 0, 0);
            accw[1][0] = __builtin_amdgcn_mfma_f32_16x16x32_bf16(af1, bf0, accw[1][0], 0, 0, 0);
            accw[1][1] = __builtin_amdgcn_mfma_f32_16x16x32_bf16(af1, bf1, accw[1][1], 0, 0, 0);
        }
    }

    // ---------- LN1 epilogue: x1 = LN(accw + bo + x_resid), keep x1 in regs, bf16->Alds ----------
    __syncthreads();
#pragma unroll
    for (int m = 0; m < 2; ++m)
#pragma unroll
        for (int n = 0; n < 2; ++n) {
            int cc = wid * 32 + n * 16 + rA;
            float bv = bo[cc];
#pragma unroll
            for (int r = 0; r < 4; ++r) {
                int rl = m * 16 + kq * 4 + r;
                vbuf[rl * 133 + cc] = accw[m][n][r] + bv + x[(size_t)(rows0 + rl) * 128 + cc];
            }
        }
    __syncthreads();
    float x1[16];
    {
        const float* vr = vbuf + row * 133 + sub * 16;
        float s = 0.f, s2 = 0.f;
#pragma unroll
        for (int j = 0; j < 16; ++j) {
            x1[j] = vr[j];
            s += x1[j];
            s2 += x1[j] * x1[j];
        }
        s += __shfl_xor(s, 1, 64);  s2 += __shfl_xor(s2, 1, 64);
        s += __shfl_xor(s, 2, 64);  s2 += __shfl_xor(s2, 2, 64);
        s += __shfl_xor(s, 4, 64);  s2 += __shfl_xor(s2, 4, 64);
        float mean = s * (1.f / 128.f);
        float var = s2 * (1.f / 128.f) - mean * mean;
        float rs = rsqrtf(var + 1e-5f);
#pragma unroll
        for (int j = 0; j < 4; ++j) {
            float4 gv = *(const float4*)(ln1g + sub * 16 + j * 4);
            float4 bv = *(const float4*)(ln1b + sub * 16 + j * 4);
            x1[j * 4 + 0] = (x1[j * 4 + 0] - mean) * rs * gv.x + bv.x;
            x1[j * 4 + 1] = (x1[j * 4 + 1] - mean) * rs * gv.y + bv.y;
            x1[j * 4 + 2] = (x1[j * 4 + 2] - mean) * rs * gv.z + bv.z;
            x1[j * 4 + 3] = (x1[j * 4 + 3] - mean) * rs * gv.w + bv.w;
        }
    }
    __syncthreads();   // vbuf reads done; safe to overwrite Alds
#pragma unroll
    for (int j = 0; j < 16; ++j) {
        int c = sub * 16 + j;
        int sc = (c & ~63) | ((((c >> 3) & 7) ^ (row & 7)) << 3) | (c & 7);
        Alds[row * 128 + sc] = f2b(x1[j]);
    }

    // ---------- phase FFN1: f1 = relu(x1 @ W1 + b1) ----------
    for (int nh = 0; nh < 2; ++nh) {
        f32x4 acc1[2][4] = {};
        for (int k0 = 0; k0 < 128; k0 += 64) {
            __syncthreads();
#pragma unroll
            for (int i = 0; i < 8; ++i) {
                int rl2 = i * 32 + wid * 8 + (lane >> 3);
                gload16(w1T + (size_t)(nh * 256 + rl2) * 128 + k0 + (((lane & 7) ^ (rl2 & 7)) << 3),
                        Wlds + (i * 32 + wid * 8) * 64);
            }
            __syncthreads();
#pragma unroll
            for (int ks = 0; ks < 2; ++ks) {
                int sw = ((ks * 4 + kq) ^ (rA & 7)) << 3;
                short8 af[2], bf4[4];
                af[0] = *(const short8*)&Alds[rA * 128 + k0 + sw];
                af[1] = *(const short8*)&Alds[(16 + rA) * 128 + k0 + sw];
#pragma unroll
                for (int n = 0; n < 4; ++n)
                    bf4[n] = *(const short8*)&Wlds[(wid * 64 + n * 16 + rA) * 64 + sw];
#pragma unroll
                for (int m = 0; m < 2; ++m)
#pragma unroll
                    for (int n = 0; n < 4; ++n)
                        acc1[m][n] = __builtin_amdgcn_mfma_f32_16x16x32_bf16(af[m], bf4[n], acc1[m][n], 0, 0, 0);
            }
        }
#pragma unroll
        for (int m = 0; m < 2; ++m)
#pragma unroll
            for (int n = 0; n < 4; ++n) {
                int cc = nh * 256 + wid * 64 + n * 16 + rA;
                float bv = b1[cc];
#pragma unroll
                for (int r = 0; r < 4; ++r) {
                    int rl = m * 16 + kq * 4 + r;
                    float v = fmaxf(acc1[m][n][r] + bv, 0.f);
                    int scol = (cc & ~63) | (((((cc >> 3) & 7) ^ (rl & 7)) & 7) << 3) | (cc & 7);
                    f1[rl * 512 + scol] = f2b(v);
                }
            }
    }
    __syncthreads();

    // ---------- phase FFN2: acc2 = f1 @ W2 ----------
    f32x4 acc2[2][2] = {};
    for (int k0 = 0; k0 < 512; k0 += 64) {
        if (k0) __syncthreads();
#pragma unroll
        for (int i = 0; i < 4; ++i) {
            int rl2 = i * 32 + wid * 8 + (lane >> 3);
            gload16(w2T + (size_t)rl2 * 512 + k0 + (((lane & 7) ^ (rl2 & 7)) << 3),
                    Wlds + (i * 32 + wid * 8) * 64);
        }
        __syncthreads();
#pragma unroll
        for (int ks = 0; ks < 2; ++ks) {
            int sw = ((ks * 4 + kq) ^ (rA & 7)) << 3;
            short8 af0 = *(const short8*)&f1[rA * 512 + k0 + sw];
            short8 af1 = *(const short8*)&f1[(16 + rA) * 512 + k0 + sw];
            short8 bf0 = *(const short8*)&Wlds[(wid * 32 + rA) * 64 + sw];
            short8 bf1 = *(const short8*)&Wlds[(wid * 32 + 16 + rA) * 64 + sw];
            acc2[0][0] = __builtin_amdgcn_mfma_f32_16x16x32_bf16(af0, bf0, acc2[0][0], 0, 0, 0);
            acc2[0][1] = __builtin_amdgcn_mfma_f32_16x16x32_bf16(af0, bf1, acc2[0][1], 0, 0, 0);
            acc2[1][0] = __builtin_amdgcn_mfma_f32_16x16x32_bf16(af1, bf0, acc2[1][0], 0, 0, 0);
            acc2[1][1] = __builtin_amdgcn_mfma_f32_16x16x32_bf16(af1, bf1, acc2[1][1], 0, 0, 0);
        }
    }

    // ---------- LN2 epilogue ----------
    __syncthreads();
#pragma unroll
    for (int m = 0; m < 2; ++m)
#pragma unroll
        for (int n = 0; n < 2; ++n) {
            int cc = wid * 32 + n * 16 + rA;
            float bv = b2[cc];
#pragma unroll
            for (int r = 0; r < 4; ++r) {
                int rl = m * 16 + kq * 4 + r;
                vbuf[rl * 133 + cc] = acc2[m][n][r] + bv;
            }
        }
    __syncthreads();
    {
        const float* vr = vbuf + row * 133 + sub * 16;
        float vv[16];
        float s = 0.f, s2 = 0.f;
#pragma unroll
        for (int j = 0; j < 16; ++j) {
            vv[j] = vr[j] + x1[j];   // residual from registers
            s += vv[j];
            s2 += vv[j] * vv[j];
        }
        s += __shfl_xor(s, 1, 64);  s2 += __shfl_xor(s2, 1, 64);
        s += __shfl_xor(s, 2, 64);  s2 += __shfl_xor(s2, 2, 64);
        s += __shfl_xor(s, 4, 64);  s2 += __shfl_xor(s2, 4, 64);
        float mean = s * (1.f / 128.f);
        float var = s2 * (1.f / 128.f) - mean * mean;
        float rs = rsqrtf(var + 1e-5f);
        int grow = rows0 + row;
        float* xrow = x + (size_t)grow * 128 + sub * 16;
        u16* xbrow = xbout + (size_t)grow * 128 + sub * 16;
#pragma unroll
        for (int j = 0; j < 4; ++j) {
            float4 gv = *(const float4*)(ln2g + sub * 16 + j * 4);
            float4 bv = *(const float4*)(ln2b + sub * 16 + j * 4);
            float o0 = (vv[j * 4 + 0] - mean) * rs * gv.x + bv.x;
            float o1 = (vv[j * 4 + 1] - mean) * rs * gv.y + bv.y;
            float o2 = (vv[j * 4 + 2] - mean) * rs * gv.z + bv.z;
            float o3 = (vv[j * 4 + 3] - mean) * rs * gv.w + bv.w;
            *(float4*)(xrow + j * 4) = make_float4(o0, o1, o2, o3);
            *(ushort4*)(xbrow + j * 4) = make_ushort4(f2b(o0), f2b(o1), f2b(o2), f2b(o3));
        }
    }
}

// ===================== fusion + positional encoding =====================
__global__ __launch_bounds__(256) void k_fusion(const float* __restrict__ spe, const int* __restrict__ traj,
                                                const float* __restrict__ ue_tab, const int* __restrict__ uid,
                                                const float* __restrict__ tempx, const int* __restrict__ hwx,
                                                const float* __restrict__ ce_tab, const float* __restrict__ flw,
                                                const float* __restrict__ flb, float* __restrict__ x,
                                                u16* __restrict__ xb) {
    __shared__ float Ws[22 * D_];
    __shared__ float bs[D_];
    __shared__ float ins[2][22];
    int tid = threadIdx.x;
    for (int i = tid; i < 22 * D_; i += 256) Ws[i] = flw[i];
    if (tid < D_) bs[tid] = flb[tid];
    __syncthreads();
    int ro = tid >> 7, d = tid & 127;
    int base = blockIdx.x * 32;
    for (int ir = 0; ir < 16; ++ir) {
        int tok = base + ir * 2 + ro;
        int b = tok >> 8, s = tok & 255;
        if (d < TD_) ins[ro][d] = tempx[(size_t)tok * TD_ + d];
        else if (d < 22) ins[ro][d] = ce_tab[(size_t)hwx[tok] * CED_ + (d - TD_)];
        __syncthreads();
        float acc = bs[d];
#pragma unroll
        for (int k = 0; k < 22; ++k) acc = fmaf(ins[ro][k], Ws[k * D_ + d], acc);
        acc = fmaxf(acc, 0.f);
        int i2 = d & ~1;
        float ang = (float)s * __expf(-(float)i2 * 0.0719557841560639f);
        float pe = (d & 1) ? cosf(ang) : sinf(ang);
        float v = spe[(size_t)traj[tok] * D_ + d] + ue_tab[(size_t)uid[b] * D_ + d] + acc + pe;
        x[(size_t)tok * D_ + d] = v;
        xb[(size_t)tok * D_ + d] = f2b(v);
        __syncthreads();
    }
}

// ===================== launch =====================
extern "C" void kernel_launch(void* const* d_in, const int* in_sizes, int n_in,
                              void* d_out, int out_size, void* d_ws, size_t ws_size,
                              hipStream_t stream) {
    const float* node_feature = (const float*)d_in[0];
    const int*   edge_index   = (const int*)d_in[1];
    const int*   traj_x       = (const int*)d_in[2];
    const float* temporal_x   = (const float*)d_in[3];
    const int*   user_id_x    = (const int*)d_in[4];
    const int*   mask         = (const int*)d_in[5];
    const int*   end_idx      = (const int*)d_in[6];
    const float* tmat         = (const float*)d_in[8];
    const float* dmat         = (const float*)d_in[9];
    const int*   highway_x    = (const int*)d_in[10];
    const float* lambda2      = (const float*)d_in[11];
    const float* gnn_w1       = (const float*)d_in[12];
    const float* gnn_b1       = (const float*)d_in[13];
    const float* gnn_w2       = (const float*)d_in[14];
    const float* gnn_b2       = (const float*)d_in[15];
    const float* ue_tab       = (const float*)d_in[16];
    const float* ce_tab       = (const float*)d_in[17];
    const float* fl_w         = (const float*)d_in[18];
    const float* fl_b         = (const float*)d_in[19];
    const float* wqkv         = (const float*)d_in[20];
    const float* bqkv         = (const float*)d_in[21];
    const float* wo           = (const float*)d_in[22];
    const float* bo           = (const float*)d_in[23];
    const float* ln1_g        = (const float*)d_in[24];
    const float* ln1_b        = (const float*)d_in[25];
    const float* ln2_g        = (const float*)d_in[26];
    const float* ln2_b        = (const float*)d_in[27];
    const float* ffn_w1       = (const float*)d_in[28];
    const float* ffn_b1       = (const float*)d_in[29];
    const float* ffn_w2       = (const float*)d_in[30];
    const float* ffn_b2       = (const float*)d_in[31];
    const float* head_w       = (const float*)d_in[32];
    const float* head_b       = (const float*)d_in[33];
    float* out = (float*)d_out;

    // ---- workspace layout (float units) ----
    float* w     = (float*)d_ws;
    int*   cnt   = (int*)w;                  // [0, 40,960)
    float* spe   = w + 40960;                // [40,960, 5,169,152)
    u16*   biasb = (u16*)(w + 5169152);      // [5,169,152, 7,266,304)
    float* wreg  = w + 7266304;              // bf16 weights -> ends 7,999,488
    u16* wqkvT = (u16*)wreg;
    u16* woT   = wqkvT + 4 * 384 * 128;
    u16* w1T   = woT + 4 * 128 * 128;
    u16* w2T   = w1T + 4 * 512 * 128;
    u16* gw1T  = w2T + 4 * 128 * 512;
    u16* gw2T  = gw1T + 128 * 64;
    u16* hwT   = gw2T + 128 * 128;
    float* pool  = w + 8000000;
    // GNN phase
    u16*   h1b   = (u16*)pool;               // [0, 2,564,096) f
    u16*   in1b  = (u16*)(pool + 2564096);   // [2,564,096, 3,846,144)
    u16*   in2b  = (u16*)(pool + 3846144);   // [3,846,144, 6,410,240)
    int*   off   = (int*)(pool + 6410240);
    int*   cursor= (int*)(pool + 6450304);
    int*   ebuf  = (int*)(pool + 6490368);
    int*   part  = (int*)(pool + 6650368);
    // transformer phase
    float* x     = pool;                     // [0, 2,097,152)
    u16*   xb    = (u16*)(pool + 2097152);   // [2,097,152, 2,621,440)
    u16*   attob = (u16*)(pool + 4718592);   // [4,718,592, 5,242,880)

    const int* esrc = edge_index;
    const int* edst = edge_index + E_;

    // ---- uber prep ----
    UberArgs ua;
    const float* srcs[7] = {wqkv, wo, ffn_w1, ffn_w2, gnn_w1, gnn_w2, head_w};
    u16* dsts[7]        = {wqkvT, woT, w1T, w2T, gw1T, gw2T, hwT};
    int Ks[7]    = {128, 128, 128, 512, 32, 128, 128};
    int Npads[7] = {384, 128, 512, 128, 128, 128, UP_};
    int Nsrcs[7] = {384, 128, 512, 128, 128, 128, U_};
    int Kps[7]   = {128, 128, 128, 512, 64, 128, 128};
    int Ls[7]    = {4, 4, 4, 4, 1, 1, 1};
    int bb = UB_CNT_END;
    for (int t = 0; t < 7; ++t) {
        ua.csrc[t] = srcs[t]; ua.cdst[t] = dsts[t];
        ua.K[t] = Ks[t]; ua.Npad[t] = Npads[t]; ua.Nsrc[t] = Nsrcs[t]; ua.Kp[t] = Kps[t];
        ua.base[t] = bb;
        bb += (Npads[t] / 32) * (Kps[t] / 32) * Ls[t];
    }
    ua.tm = tmat; ua.dm = dmat; ua.maskp = mask; ua.lambda2 = lambda2;
    ua.bias = biasb; ua.cnt = cnt;
    k_uber<<<UB_TOTAL, 256, 0, stream>>>(ua);

    // ---- GNN: CSR build + gather ----
    k_count<<<(E_ + 255) / 256, 256, 0, stream>>>(edst, cnt);
    k_scanA<<<NSCB, 256, 0, stream>>>(cnt, part);
    k_scanB<<<NSCB, 256, 0, stream>>>(cnt, part, off, cursor);
    k_fill<<<(E_ + 255) / 256, 256, 0, stream>>>(esrc, edst, cursor, ebuf);
    k_gprep1<<<NP_ / 8, 256, 0, stream>>>(node_feature, off, cnt, ebuf, in1b);
    k_mgemm<128, 1, 1, 0><<<dim3(NP_ / 128, 1), 256, 0, stream>>>(in1b, gw1T, gnn_b1, h1b, nullptr, NP_, D_, 64);
    k_gprep2<<<NP_ / 4, 256, 0, stream>>>(h1b, off, cnt, ebuf, in2b);
    k_mgemm<128, 1, 0, 0><<<dim3(NP_ / 128, 1), 256, 0, stream>>>(in2b, gw2T, gnn_b2, spe, nullptr, NP_, D_, D_);

    // ---- fusion ----
    k_fusion<<<(B_ * S_) / 32, 256, 0, stream>>>(spe, traj_x, ue_tab, user_id_x,
                                                 temporal_x, highway_x, ce_tab, fl_w, fl_b, x, xb);

    // ---- transformer: 2 kernels per layer ----
    const int M = B_ * S_;
    for (int l = 0; l < L_; ++l) {
        k_qkvatt<<<B_ * H_, 256, 0, stream>>>(xb, wqkvT + (size_t)l * 384 * 128,
                                              bqkv + (size_t)l * 384, biasb, attob);
        k_layer<<<M / 32, 256, 0, stream>>>(attob, woT + (size_t)l * 128 * 128, bo + l * D_,
                                            ln1_g + l * D_, ln1_b + l * D_,
                                            w1T + (size_t)l * 512 * 128, ffn_b1 + l * FF_,
                                            w2T + (size_t)l * 128 * 512, ffn_b2 + l * D_,
                                            ln2_g + l * D_, ln2_b + l * D_, x, xb);
    }

    // ---- head (gather fused) ----
    k_mgemm<64, 0, 0, 1><<<dim3(1, UP_ / 128), 256, 0, stream>>>(xb, hwT, head_b, out, end_idx, B_, U_, D_);
}